// Round 2
// baseline (928.949 us; speedup 1.0000x reference)
//
#include <hip/hip_runtime.h>

typedef unsigned short u16;

#define ICNST 128
#define C2 256   // OC*WIDTH
#define NPB 64

__device__ __forceinline__ float bf2f(u16 u){
  return __uint_as_float(((unsigned int)u) << 16);
}
__device__ __forceinline__ float2 bf2x2(unsigned int u){
  float2 r;
  r.x = __uint_as_float(u << 16);
  r.y = __uint_as_float(u & 0xffff0000u);
  return r;
}
__device__ __forceinline__ u16 f2bf(float f){
  unsigned int u = __float_as_uint(f);
  unsigned int r = (u + 0x7fffu + ((u >> 16) & 1u)) >> 16;
  return (u16)r;
}

// ---- degree count ----
__global__ void k_deg(const int* __restrict__ dst, int* __restrict__ deg, int E){
  int e = blockIdx.x * blockDim.x + threadIdx.x;
  if (e < E) atomicAdd(&deg[dst[e]], 1);
}

// ---- exclusive scan of deg -> row_start, cursor; also norm ----
__global__ __launch_bounds__(1024) void k_scan(const int* __restrict__ deg,
    int* __restrict__ row_start, int* __restrict__ cursor,
    float* __restrict__ norm, int n){
  __shared__ int sums[1024];
  int t = threadIdx.x;
  int ch = (n + 1023) >> 10;
  int b = t * ch;
  int e = min(b + ch, n);
  int s = 0;
  for (int i = b; i < e; ++i) s += deg[i];
  sums[t] = s;
  __syncthreads();
  for (int off = 1; off < 1024; off <<= 1){
    int v = (t >= off) ? sums[t - off] : 0;
    __syncthreads();
    sums[t] += v;
    __syncthreads();
  }
  int run = sums[t] - s; // exclusive prefix of this chunk
  for (int i = b; i < e; ++i){
    int d = deg[i];
    row_start[i] = run;
    cursor[i] = run;
    norm[i] = (d > 0) ? rsqrtf((float)d) : 0.f;
    run += d;
  }
  if (t == 1023) row_start[n] = run;
}

// ---- scatter edges into CSR slots ----
__global__ void k_scatter(const int* __restrict__ src, const int* __restrict__ dstA,
    int* __restrict__ cursor, int* __restrict__ csr_src, int E){
  int e = blockIdx.x * blockDim.x + threadIdx.x;
  if (e < E){
    int d = dstA[e];
    int pos = atomicAdd(&cursor[d], 1);
    csr_src[pos] = src[e];
  }
}

// ---- init: merge = X@Wm + bm (stored bf16), out0 = relu(X@Wp + bp + merge) ----
__global__ __launch_bounds__(512) void k_init(const float* __restrict__ node,
    const float* __restrict__ Wpre, const float* __restrict__ bpre,
    const float* __restrict__ Wmrg, const float* __restrict__ bmrg,
    u16* __restrict__ merge, u16* __restrict__ outA, int n){
  __shared__ u16 WpT[128 * 256]; // transposed [j][i], bf16, XOR-swizzled, 64KB
  __shared__ u16 WmT[128 * 256];
  __shared__ float xl[2][128];
  __shared__ float bP[256], bM[256];
  int t = threadIdx.x;
  if (t < 256){ bP[t] = bpre[t]; bM[t] = bmrg[t]; }
  // stage + transpose weights: global f32 layout [i][j] (j fastest, 256 wide)
  for (int c = t; c < 8192; c += 512){
    int i = c >> 6;              // 64 float4 per row of 256
    int j0 = (c & 63) * 4;
    float4 up = ((const float4*)Wpre)[c];
    float4 um = ((const float4*)Wmrg)[c];
    float pe[4] = {up.x, up.y, up.z, up.w};
    float me[4] = {um.x, um.y, um.z, um.w};
    #pragma unroll
    for (int k = 0; k < 4; ++k){
      int j = j0 + k;
      int byte = (j * 256 + i * 2) ^ ((j & 7) << 4);
      WpT[byte >> 1] = f2bf(pe[k]);
      WmT[byte >> 1] = f2bf(me[k]);
    }
  }
  __syncthreads();

  int n0 = blockIdx.x * NPB;
  int j = t & 255;
  int which = t >> 8;
  for (int p = 0; p < NPB / 2; ++p){
    __syncthreads();
    if (t < 256){
      int w2 = t >> 7, i = t & 127;
      int nn = n0 + p * 2 + w2;
      xl[w2][i] = (nn < n) ? node[(size_t)nn * ICNST + i] : 0.f;
    }
    __syncthreads();
    int nn = n0 + p * 2 + which;
    if (nn < n){
      float accP = 0.f, accM = 0.f;
      #pragma unroll
      for (int k = 0; k < 16; ++k){
        int byte = (j * 256 + k * 16) ^ ((j & 7) << 4);
        uint4 wp = *(const uint4*)((const char*)WpT + byte);
        uint4 wm = *(const uint4*)((const char*)WmT + byte);
        const float* xs = &xl[which][k * 8];
        float2 c;
        c = bf2x2(wp.x); accP = fmaf(c.x, xs[0], accP); accP = fmaf(c.y, xs[1], accP);
        c = bf2x2(wp.y); accP = fmaf(c.x, xs[2], accP); accP = fmaf(c.y, xs[3], accP);
        c = bf2x2(wp.z); accP = fmaf(c.x, xs[4], accP); accP = fmaf(c.y, xs[5], accP);
        c = bf2x2(wp.w); accP = fmaf(c.x, xs[6], accP); accP = fmaf(c.y, xs[7], accP);
        c = bf2x2(wm.x); accM = fmaf(c.x, xs[0], accM); accM = fmaf(c.y, xs[1], accM);
        c = bf2x2(wm.y); accM = fmaf(c.x, xs[2], accM); accM = fmaf(c.y, xs[3], accM);
        c = bf2x2(wm.z); accM = fmaf(c.x, xs[4], accM); accM = fmaf(c.y, xs[5], accM);
        c = bf2x2(wm.w); accM = fmaf(c.x, xs[6], accM); accM = fmaf(c.y, xs[7], accM);
      }
      float mg = accM + bM[j];
      merge[(size_t)nn * C2 + j] = f2bf(mg);
      float o = accP + bP[j] + mg;
      outA[(size_t)nn * C2 + j] = f2bf(o > 0.f ? o : 0.f);
    }
  }
}

// ---- propagation: B[d] = norm[d] * sum_{e in in(d)} norm[s]*A[s] ----
__global__ __launch_bounds__(256) void k_prop(const u16* __restrict__ A, u16* __restrict__ B,
    const int* __restrict__ row_start, const int* __restrict__ csr,
    const float* __restrict__ norm, int n){
  int gw = (blockIdx.x * blockDim.x + threadIdx.x) >> 6;
  int lane = threadIdx.x & 63;
  if (gw >= n) return;
  int b = row_start[gw], e = row_start[gw + 1];
  float a0 = 0.f, a1 = 0.f, a2 = 0.f, a3 = 0.f;
  for (int j2 = b; j2 < e; ++j2){
    int s = csr[j2];
    float w = norm[s];
    uint2 rv = *(const uint2*)(A + (size_t)s * C2 + lane * 4);
    float2 p0 = bf2x2(rv.x), p1 = bf2x2(rv.y);
    a0 = fmaf(w, p0.x, a0); a1 = fmaf(w, p0.y, a1);
    a2 = fmaf(w, p1.x, a2); a3 = fmaf(w, p1.y, a3);
  }
  float nd = norm[gw];
  ushort4 ov;
  ov.x = f2bf(nd * a0); ov.y = f2bf(nd * a1);
  ov.z = f2bf(nd * a2); ov.w = f2bf(nd * a3);
  *(ushort4*)(B + (size_t)gw * C2 + lane * 4) = ov;
}

// ---- per-node block-diag conv, in place: buf = relu(conv(buf) + b_conv + merge) ----
__global__ __launch_bounds__(512) void k_conv(u16* __restrict__ buf,
    const float* __restrict__ Wc, const float* __restrict__ bc,
    const u16* __restrict__ merge, int n){
  __shared__ u16 WT[128 * 256]; // row j = w*128+o, 128 i's, bf16, swizzled, 64KB
  __shared__ float inl[2][256];
  __shared__ float bC[256];
  int t = threadIdx.x;
  if (t < 256) bC[t] = bc[t];
  // stage: global f32 layout [j][i], i fastest (128 wide)
  for (int c = t; c < 8192; c += 512){
    int jj = c >> 5;             // 32 float4 per row of 128
    int i0 = (c & 31) * 4;
    float4 u = ((const float4*)Wc)[c];
    float e4[4] = {u.x, u.y, u.z, u.w};
    #pragma unroll
    for (int k = 0; k < 4; ++k){
      int byte = (jj * 256 + (i0 + k) * 2) ^ ((jj & 7) << 4);
      WT[byte >> 1] = f2bf(e4[k]);
    }
  }
  __syncthreads();

  int n0 = blockIdx.x * NPB;
  int j = t & 255;
  int which = t >> 8;
  int wslice = (j >> 7) * 128;
  for (int p = 0; p < NPB / 2; ++p){
    __syncthreads();
    {
      int w2 = t >> 8, i = t & 255;
      int nn = n0 + p * 2 + w2;
      inl[w2][i] = (nn < n) ? bf2f(buf[(size_t)nn * C2 + i]) : 0.f;
    }
    __syncthreads();
    int nn = n0 + p * 2 + which;
    if (nn < n){
      float acc = 0.f;
      #pragma unroll
      for (int k = 0; k < 16; ++k){
        int byte = (j * 256 + k * 16) ^ ((j & 7) << 4);
        uint4 wv = *(const uint4*)((const char*)WT + byte);
        const float* xs = &inl[which][wslice + k * 8];
        float2 c;
        c = bf2x2(wv.x); acc = fmaf(c.x, xs[0], acc); acc = fmaf(c.y, xs[1], acc);
        c = bf2x2(wv.y); acc = fmaf(c.x, xs[2], acc); acc = fmaf(c.y, xs[3], acc);
        c = bf2x2(wv.z); acc = fmaf(c.x, xs[4], acc); acc = fmaf(c.y, xs[5], acc);
        c = bf2x2(wv.w); acc = fmaf(c.x, xs[6], acc); acc = fmaf(c.y, xs[7], acc);
      }
      float o = acc + bC[j] + bf2f(merge[(size_t)nn * C2 + j]);
      buf[(size_t)nn * C2 + j] = f2bf(o > 0.f ? o : 0.f);
    }
  }
}

// ---- final: out[n][o] = mean(buf[n][2o], buf[n][2o+1]), f32 output ----
__global__ void k_final(const u16* __restrict__ buf, float* __restrict__ out, int total){
  int idx = blockIdx.x * blockDim.x + threadIdx.x;
  if (idx < total){
    int nn = idx >> 7, o = idx & 127;
    unsigned int pr = *(const unsigned int*)(buf + (size_t)nn * C2 + 2 * o);
    float2 v = bf2x2(pr);
    out[idx] = 0.5f * (v.x + v.y);
  }
}

extern "C" void kernel_launch(void* const* d_in, const int* in_sizes, int n_in,
                              void* d_out, int out_size, void* d_ws, size_t ws_size,
                              hipStream_t stream){
  const float* node = (const float*)d_in[0];
  const int*   eidx = (const int*)d_in[1];
  const float* Wpre = (const float*)d_in[2];
  const float* bpre = (const float*)d_in[3];
  const float* Wmrg = (const float*)d_in[4];
  const float* bmrg = (const float*)d_in[5];
  const float* Wcv  = (const float*)d_in[6];
  const float* bcv  = (const float*)d_in[7];
  float* out = (float*)d_out;

  const int n = in_sizes[0] / ICNST;
  const int E = in_sizes[1] / 2;
  const int* srcp = eidx;
  const int* dstp = eidx + E;

  char* ws = (char*)d_ws;
  size_t off = 0;
  auto alloc = [&](size_t bytes) -> char* {
    char* p = ws + off;
    off += bytes;
    off = (off + 255) & ~(size_t)255;
    return p;
  };
  int*   deg       = (int*)  alloc((size_t)n * 4);
  float* norm      = (float*)alloc((size_t)n * 4);
  int*   row_start = (int*)  alloc((size_t)(n + 1) * 4);
  int*   cursor    = (int*)  alloc((size_t)n * 4);
  int*   csr       = (int*)  alloc((size_t)E * 4);
  u16*   merge     = (u16*)  alloc((size_t)n * C2 * 2);
  u16*   bufA      = (u16*)  alloc((size_t)n * C2 * 2);
  u16*   bufB      = (u16*)  alloc((size_t)n * C2 * 2);
  (void)ws_size; (void)n_in; (void)out_size;

  hipMemsetAsync(deg, 0, (size_t)n * 4, stream);
  k_deg<<<(E + 255) / 256, 256, 0, stream>>>(dstp, deg, E);
  k_scan<<<1, 1024, 0, stream>>>(deg, row_start, cursor, norm, n);
  k_scatter<<<(E + 255) / 256, 256, 0, stream>>>(srcp, dstp, cursor, csr, E);

  int gb = (n + NPB - 1) / NPB;
  k_init<<<gb, 512, 0, stream>>>(node, Wpre, bpre, Wmrg, bmrg, merge, bufA, n);

  // iteration 1: prop A->B, conv in-place B
  k_prop<<<(n + 3) / 4, 256, 0, stream>>>(bufA, bufB, row_start, csr, norm, n);
  k_conv<<<gb, 512, 0, stream>>>(bufB, Wcv, bcv, merge, n);
  // iteration 2: prop B->A, conv in-place A
  k_prop<<<(n + 3) / 4, 256, 0, stream>>>(bufB, bufA, row_start, csr, norm, n);
  k_conv<<<gb, 512, 0, stream>>>(bufA, Wcv, bcv, merge, n);

  k_final<<<((n * 128) + 255) / 256, 256, 0, stream>>>(bufA, out, n * 128);
}

// Round 3
// 408.606 us; speedup vs baseline: 2.2735x; 2.2735x over previous
//
#include <hip/hip_runtime.h>

typedef unsigned short u16;
typedef __attribute__((ext_vector_type(8))) short bf16x8;
typedef __attribute__((ext_vector_type(4))) float f32x4;

#define ICNST 128
#define C2 256   // OC*WIDTH

__device__ __forceinline__ float bf2f(u16 u){
  return __uint_as_float(((unsigned int)u) << 16);
}
__device__ __forceinline__ float2 bf2x2(unsigned int u){
  float2 r;
  r.x = __uint_as_float(u << 16);
  r.y = __uint_as_float(u & 0xffff0000u);
  return r;
}
__device__ __forceinline__ u16 f2bf(float f){
  unsigned int u = __float_as_uint(f);
  unsigned int r = (u + 0x7fffu + ((u >> 16) & 1u)) >> 16;
  return (u16)r;
}
__device__ __forceinline__ unsigned int pk2(float a, float b){
  return (unsigned int)f2bf(a) | ((unsigned int)f2bf(b) << 16);
}

// ---- degree count ----
__global__ void k_deg(const int* __restrict__ dst, int* __restrict__ deg, int E){
  int e = blockIdx.x * blockDim.x + threadIdx.x;
  if (e < E) atomicAdd(&deg[dst[e]], 1);
}

// ---- exclusive scan of deg -> row_start, cursor; also norm ----
__global__ __launch_bounds__(1024) void k_scan(const int* __restrict__ deg,
    int* __restrict__ row_start, int* __restrict__ cursor,
    float* __restrict__ norm, int n){
  __shared__ int sums[1024];
  int t = threadIdx.x;
  int ch = (n + 1023) >> 10;
  int b = t * ch;
  int e = min(b + ch, n);
  int s = 0;
  for (int i = b; i < e; ++i) s += deg[i];
  sums[t] = s;
  __syncthreads();
  for (int off = 1; off < 1024; off <<= 1){
    int v = (t >= off) ? sums[t - off] : 0;
    __syncthreads();
    sums[t] += v;
    __syncthreads();
  }
  int run = sums[t] - s;
  for (int i = b; i < e; ++i){
    int d = deg[i];
    row_start[i] = run;
    cursor[i] = run;
    norm[i] = (d > 0) ? rsqrtf((float)d) : 0.f;
    run += d;
  }
  if (t == 1023) row_start[n] = run;
}

// ---- scatter edges into CSR slots ----
__global__ void k_scatter(const int* __restrict__ src, const int* __restrict__ dstA,
    int* __restrict__ cursor, int* __restrict__ csr_src, int E){
  int e = blockIdx.x * blockDim.x + threadIdx.x;
  if (e < E){
    int d = dstA[e];
    int pos = atomicAdd(&cursor[d], 1);
    csr_src[pos] = src[e];
  }
}

// ---- convert weights to bf16: WT[j][k] = (j<256?Wpre:Wmrg)[k][j'], Wc_bf = Wcv ----
__global__ void k_cvtW(const float* __restrict__ Wpre, const float* __restrict__ Wmrg,
    const float* __restrict__ Wcv, u16* __restrict__ WT, u16* __restrict__ Wc){
  int idx = blockIdx.x * blockDim.x + threadIdx.x;
  if (idx < 65536){
    int j = idx & 511, k = idx >> 9;
    float v = (j < 256) ? Wpre[k * 256 + j] : Wmrg[k * 256 + (j - 256)];
    WT[j * 128 + k] = f2bf(v);
  } else if (idx < 65536 + 32768){
    int x = idx - 65536;
    Wc[x] = f2bf(Wcv[x]);
  }
}

// ---- init (MFMA): merge = X@Wm + bm; out0 = relu(X@Wp + bp + merge) ----
// grid (ceil(n/64), 2), 256 threads (4 waves). Tile: 64 rows x 128 paired cols.
__global__ __launch_bounds__(256) void k_initM(const float* __restrict__ node,
    const u16* __restrict__ WT, const float* __restrict__ bpre,
    const float* __restrict__ bmrg, u16* __restrict__ merge,
    u16* __restrict__ outA, int n){
  __shared__ u16 Al[64 * 128]; // bf16, XOR-swizzled, 16KB
  int t = threadIdx.x;
  int w = t >> 6, l = t & 63;
  int n0 = blockIdx.x * 64;
  int cbase = blockIdx.y * 128 + w * 32; // paired-col base for this wave

  // stage A: 64 rows x 128 f32 -> bf16 swizzled LDS. thread: row=t>>2, 32 cols.
  {
    int row = t >> 2, c0 = (t & 3) * 32;
    const float* src = node + (size_t)(n0 + row) * ICNST + c0;
    bool ok = (n0 + row) < n;
    #pragma unroll
    for (int q = 0; q < 8; ++q){
      float4 v = ok ? *(const float4*)(src + q * 4) : float4{0.f, 0.f, 0.f, 0.f};
      int byte = (row * 256 + c0 * 2 + q * 8) ^ ((row & 7) << 4);
      uint2 pv; pv.x = pk2(v.x, v.y); pv.y = pk2(v.z, v.w);
      *(uint2*)((char*)Al + byte) = pv;
    }
  }
  __syncthreads();

  f32x4 acc[4][4] = {}; // [row frag][col frag: 0,1=pre 2,3=merge]
  int lk = (l >> 4) * 8;
  #pragma unroll
  for (int ks = 0; ks < 4; ++ks){
    bf16x8 bf[4];
    #pragma unroll
    for (int fc = 0; fc < 4; ++fc){
      int j = (fc < 2) ? (cbase + fc * 16 + (l & 15))
                       : (256 + cbase + (fc - 2) * 16 + (l & 15));
      bf[fc] = *(const bf16x8*)(WT + (size_t)j * 128 + ks * 32 + lk);
    }
    bf16x8 af[4];
    #pragma unroll
    for (int fr = 0; fr < 4; ++fr){
      int row = fr * 16 + (l & 15);
      int byte = (row * 256 + ks * 64 + (l >> 4) * 16) ^ ((l & 7) << 4);
      af[fr] = *(const bf16x8*)((const char*)Al + byte);
    }
    #pragma unroll
    for (int fr = 0; fr < 4; ++fr)
      #pragma unroll
      for (int fc = 0; fc < 4; ++fc)
        acc[fr][fc] = __builtin_amdgcn_mfma_f32_16x16x32_bf16(af[fr], bf[fc], acc[fr][fc], 0, 0, 0);
  }

  #pragma unroll
  for (int fr = 0; fr < 4; ++fr){
    int rbase = n0 + fr * 16 + (l >> 4) * 4;
    #pragma unroll
    for (int fc = 0; fc < 2; ++fc){
      int j = cbase + fc * 16 + (l & 15);
      float bP = bpre[j], bM = bmrg[j];
      #pragma unroll
      for (int r = 0; r < 4; ++r){
        int rn = rbase + r;
        if (rn < n){
          float mg = acc[fr][fc + 2][r] + bM;
          float o  = acc[fr][fc][r] + bP + mg;
          merge[(size_t)rn * C2 + j] = f2bf(mg);
          outA [(size_t)rn * C2 + j] = f2bf(o > 0.f ? o : 0.f);
        }
      }
    }
  }
}

// ---- conv (MFMA), in place: buf = relu(blockdiag_conv(buf) + b_conv + merge) ----
// grid ceil(n/64), 512 threads (8 waves). Tile: 64 rows x 256 cols.
__global__ __launch_bounds__(512) void k_convM(u16* __restrict__ buf,
    const u16* __restrict__ Wc, const float* __restrict__ bc,
    const u16* __restrict__ merge, int n){
  __shared__ u16 Al[64 * 256]; // bf16, XOR-swizzled, 32KB
  int t = threadIdx.x;
  int w = t >> 6, l = t & 63;
  int n0 = blockIdx.x * 64;
  int wh = w >> 2;              // which 128-col half (selects A cols + W block)

  // stage A: 64 rows x 256 bf16. thread: row=t>>3, 32 cols.
  {
    int row = t >> 3, c0 = (t & 7) * 32;
    const u16* src = buf + (size_t)(n0 + row) * C2 + c0;
    bool ok = (n0 + row) < n;
    #pragma unroll
    for (int q = 0; q < 4; ++q){
      uint4 v = ok ? *(const uint4*)(src + q * 8) : uint4{0u, 0u, 0u, 0u};
      int byte = (row * 512 + c0 * 2 + q * 16) ^ ((row & 7) << 4);
      *(uint4*)((char*)Al + byte) = v;
    }
  }
  __syncthreads();

  f32x4 acc[4][2] = {};
  int lk = (l >> 4) * 8;
  #pragma unroll
  for (int ks = 0; ks < 4; ++ks){
    bf16x8 bf[2];
    #pragma unroll
    for (int fc = 0; fc < 2; ++fc){
      int rw = w * 32 + fc * 16 + (l & 15);   // = wh*128 + col
      bf[fc] = *(const bf16x8*)(Wc + (size_t)rw * 128 + ks * 32 + lk);
    }
    bf16x8 af[4];
    #pragma unroll
    for (int fr = 0; fr < 4; ++fr){
      int row = fr * 16 + (l & 15);
      int byte = (row * 512 + wh * 256 + ks * 64 + (l >> 4) * 16) ^ ((l & 7) << 4);
      af[fr] = *(const bf16x8*)((const char*)Al + byte);
    }
    #pragma unroll
    for (int fr = 0; fr < 4; ++fr)
      #pragma unroll
      for (int fc = 0; fc < 2; ++fc)
        acc[fr][fc] = __builtin_amdgcn_mfma_f32_16x16x32_bf16(af[fr], bf[fc], acc[fr][fc], 0, 0, 0);
  }

  #pragma unroll
  for (int fr = 0; fr < 4; ++fr){
    int rbase = n0 + fr * 16 + (l >> 4) * 4;
    #pragma unroll
    for (int fc = 0; fc < 2; ++fc){
      int j = w * 32 + fc * 16 + (l & 15);
      float bC = bc[j];
      #pragma unroll
      for (int r = 0; r < 4; ++r){
        int rn = rbase + r;
        if (rn < n){
          float o = acc[fr][fc][r] + bC + bf2f(merge[(size_t)rn * C2 + j]);
          buf[(size_t)rn * C2 + j] = f2bf(o > 0.f ? o : 0.f);
        }
      }
    }
  }
}

// ---- propagation: B[d] = norm[d] * sum_{e in in(d)} norm[s]*A[s] ----
__global__ __launch_bounds__(256) void k_prop(const u16* __restrict__ A, u16* __restrict__ B,
    const int* __restrict__ row_start, const int* __restrict__ csr,
    const float* __restrict__ norm, int n){
  int gw = (blockIdx.x * blockDim.x + threadIdx.x) >> 6;
  int lane = threadIdx.x & 63;
  if (gw >= n) return;
  int b = row_start[gw], e = row_start[gw + 1];
  float a0 = 0.f, a1 = 0.f, a2 = 0.f, a3 = 0.f;
  for (int j2 = b; j2 < e; ++j2){
    int s = csr[j2];
    float w = norm[s];
    uint2 rv = *(const uint2*)(A + (size_t)s * C2 + lane * 4);
    float2 p0 = bf2x2(rv.x), p1 = bf2x2(rv.y);
    a0 = fmaf(w, p0.x, a0); a1 = fmaf(w, p0.y, a1);
    a2 = fmaf(w, p1.x, a2); a3 = fmaf(w, p1.y, a3);
  }
  float nd = norm[gw];
  ushort4 ov;
  ov.x = f2bf(nd * a0); ov.y = f2bf(nd * a1);
  ov.z = f2bf(nd * a2); ov.w = f2bf(nd * a3);
  *(ushort4*)(B + (size_t)gw * C2 + lane * 4) = ov;
}

// ---- final: out[n][o] = mean(buf[n][2o], buf[n][2o+1]), f32 output ----
__global__ void k_final(const u16* __restrict__ buf, float* __restrict__ out, int total){
  int idx = blockIdx.x * blockDim.x + threadIdx.x;
  if (idx < total){
    int nn = idx >> 7, o = idx & 127;
    unsigned int pr = *(const unsigned int*)(buf + (size_t)nn * C2 + 2 * o);
    float2 v = bf2x2(pr);
    out[idx] = 0.5f * (v.x + v.y);
  }
}

extern "C" void kernel_launch(void* const* d_in, const int* in_sizes, int n_in,
                              void* d_out, int out_size, void* d_ws, size_t ws_size,
                              hipStream_t stream){
  const float* node = (const float*)d_in[0];
  const int*   eidx = (const int*)d_in[1];
  const float* Wpre = (const float*)d_in[2];
  const float* bpre = (const float*)d_in[3];
  const float* Wmrg = (const float*)d_in[4];
  const float* bmrg = (const float*)d_in[5];
  const float* Wcv  = (const float*)d_in[6];
  const float* bcv  = (const float*)d_in[7];
  float* out = (float*)d_out;

  const int n = in_sizes[0] / ICNST;
  const int E = in_sizes[1] / 2;
  const int* srcp = eidx;
  const int* dstp = eidx + E;

  char* ws = (char*)d_ws;
  size_t off = 0;
  auto alloc = [&](size_t bytes) -> char* {
    char* p = ws + off;
    off += bytes;
    off = (off + 255) & ~(size_t)255;
    return p;
  };
  int*   deg       = (int*)  alloc((size_t)n * 4);
  float* norm      = (float*)alloc((size_t)n * 4);
  int*   row_start = (int*)  alloc((size_t)(n + 1) * 4);
  int*   cursor    = (int*)  alloc((size_t)n * 4);
  int*   csr       = (int*)  alloc((size_t)E * 4);
  u16*   merge     = (u16*)  alloc((size_t)n * C2 * 2);
  u16*   bufA      = (u16*)  alloc((size_t)n * C2 * 2);
  u16*   bufB      = (u16*)  alloc((size_t)n * C2 * 2);
  u16*   WT        = (u16*)  alloc((size_t)512 * 128 * 2);
  u16*   Wcbf      = (u16*)  alloc((size_t)2 * 128 * 128 * 2);
  (void)ws_size; (void)n_in; (void)out_size;

  hipMemsetAsync(deg, 0, (size_t)n * 4, stream);
  k_cvtW<<<384, 256, 0, stream>>>(Wpre, Wmrg, Wcv, WT, Wcbf);
  k_deg<<<(E + 255) / 256, 256, 0, stream>>>(dstp, deg, E);
  k_scan<<<1, 1024, 0, stream>>>(deg, row_start, cursor, norm, n);
  k_scatter<<<(E + 255) / 256, 256, 0, stream>>>(srcp, dstp, cursor, csr, E);

  int gb = (n + 63) / 64;
  k_initM<<<dim3(gb, 2), 256, 0, stream>>>(node, WT, bpre, bmrg, merge, bufA, n);

  // iteration 1: prop A->B, conv in-place B
  k_prop<<<(n + 3) / 4, 256, 0, stream>>>(bufA, bufB, row_start, csr, norm, n);
  k_convM<<<gb, 512, 0, stream>>>(bufB, Wcbf, bcv, merge, n);
  // iteration 2: prop B->A, conv in-place A
  k_prop<<<(n + 3) / 4, 256, 0, stream>>>(bufB, bufA, row_start, csr, norm, n);
  k_convM<<<gb, 512, 0, stream>>>(bufA, Wcbf, bcv, merge, n);

  k_final<<<((n * 128) + 255) / 256, 256, 0, stream>>>(bufA, out, n * 128);
}

// Round 4
// 284.358 us; speedup vs baseline: 3.2668x; 1.4369x over previous
//
#include <hip/hip_runtime.h>

typedef unsigned short u16;
typedef __attribute__((ext_vector_type(8))) short bf16x8;
typedef __attribute__((ext_vector_type(4))) float f32x4;

#define ICNST 128
#define C2 256   // OC*WIDTH

__device__ __forceinline__ float bf2f(u16 u){
  return __uint_as_float(((unsigned int)u) << 16);
}
__device__ __forceinline__ float2 bf2x2(unsigned int u){
  float2 r;
  r.x = __uint_as_float(u << 16);
  r.y = __uint_as_float(u & 0xffff0000u);
  return r;
}
__device__ __forceinline__ u16 f2bf(float f){
  unsigned int u = __float_as_uint(f);
  unsigned int r = (u + 0x7fffu + ((u >> 16) & 1u)) >> 16;
  return (u16)r;
}
__device__ __forceinline__ unsigned int pk2(float a, float b){
  return (unsigned int)f2bf(a) | ((unsigned int)f2bf(b) << 16);
}

// ---- degree count ----
__global__ void k_deg(const int* __restrict__ dst, int* __restrict__ deg, int E){
  int e = blockIdx.x * blockDim.x + threadIdx.x;
  if (e < E) atomicAdd(&deg[dst[e]], 1);
}

// ---- hierarchical scan: 1) per-block sums ----
__global__ __launch_bounds__(256) void k_scan1(const int* __restrict__ deg,
    int* __restrict__ bsum, int n){
  __shared__ int red[256];
  int t = threadIdx.x;
  int i = blockIdx.x * 256 + t;
  red[t] = (i < n) ? deg[i] : 0;
  __syncthreads();
  for (int off = 128; off > 0; off >>= 1){
    if (t < off) red[t] += red[t + off];
    __syncthreads();
  }
  if (t == 0) bsum[blockIdx.x] = red[0];
}

// ---- 2) single-block exclusive scan of block sums (nb <= 256) ----
__global__ __launch_bounds__(256) void k_scan2(int* __restrict__ bsum, int nb){
  __shared__ int s[256];
  int t = threadIdx.x;
  int v = (t < nb) ? bsum[t] : 0;
  s[t] = v;
  __syncthreads();
  for (int off = 1; off < 256; off <<= 1){
    int u = (t >= off) ? s[t - off] : 0;
    __syncthreads();
    s[t] += u;
    __syncthreads();
  }
  if (t < nb) bsum[t] = s[t] - v; // exclusive
}

// ---- 3) block-local exclusive scan + offset -> row_start, cursor, norm ----
__global__ __launch_bounds__(256) void k_scan3(const int* __restrict__ deg,
    const int* __restrict__ bsum, int* __restrict__ row_start,
    int* __restrict__ cursor, float* __restrict__ norm, int n){
  __shared__ int s[256];
  int t = threadIdx.x;
  int i = blockIdx.x * 256 + t;
  int v = (i < n) ? deg[i] : 0;
  s[t] = v;
  __syncthreads();
  for (int off = 1; off < 256; off <<= 1){
    int u = (t >= off) ? s[t - off] : 0;
    __syncthreads();
    s[t] += u;
    __syncthreads();
  }
  int ex = s[t] - v + bsum[blockIdx.x];
  if (i < n){
    row_start[i] = ex;
    cursor[i] = ex;
    norm[i] = (v > 0) ? rsqrtf((float)v) : 0.f;
    if (i == n - 1) row_start[n] = ex + v;
  }
}

// ---- scatter edges into CSR slots ----
__global__ void k_scatter(const int* __restrict__ src, const int* __restrict__ dstA,
    int* __restrict__ cursor, int* __restrict__ csr_src, int E){
  int e = blockIdx.x * blockDim.x + threadIdx.x;
  if (e < E){
    int d = dstA[e];
    int pos = atomicAdd(&cursor[d], 1);
    csr_src[pos] = src[e];
  }
}

// ---- convert weights to bf16: WT[j][k] = (j<256?Wpre:Wmrg)[k][j'], Wc_bf = Wcv ----
__global__ void k_cvtW(const float* __restrict__ Wpre, const float* __restrict__ Wmrg,
    const float* __restrict__ Wcv, u16* __restrict__ WT, u16* __restrict__ Wc){
  int idx = blockIdx.x * blockDim.x + threadIdx.x;
  if (idx < 65536){
    int j = idx & 511, k = idx >> 9;
    float v = (j < 256) ? Wpre[k * 256 + j] : Wmrg[k * 256 + (j - 256)];
    WT[j * 128 + k] = f2bf(v);
  } else if (idx < 65536 + 32768){
    int x = idx - 65536;
    Wc[x] = f2bf(Wcv[x]);
  }
}

// ---- init (MFMA): merge = X@Wm + bm; out0 = relu(X@Wp + bp + merge) ----
// grid (ceil(n/64), 2), 256 threads (4 waves). Tile: 64 rows x 128 paired cols.
__global__ __launch_bounds__(256) void k_initM(const float* __restrict__ node,
    const u16* __restrict__ WT, const float* __restrict__ bpre,
    const float* __restrict__ bmrg, u16* __restrict__ merge,
    u16* __restrict__ outA, int n){
  __shared__ u16 Al[64 * 128]; // bf16, XOR-swizzled, 16KB
  int t = threadIdx.x;
  int w = t >> 6, l = t & 63;
  int n0 = blockIdx.x * 64;
  int cbase = blockIdx.y * 128 + w * 32; // paired-col base for this wave

  // stage A: 64 rows x 128 f32 -> bf16 swizzled LDS. thread: row=t>>2, 32 cols.
  {
    int row = t >> 2, c0 = (t & 3) * 32;
    const float* src = node + (size_t)(n0 + row) * ICNST + c0;
    bool ok = (n0 + row) < n;
    #pragma unroll
    for (int q = 0; q < 8; ++q){
      float4 v = ok ? *(const float4*)(src + q * 4) : float4{0.f, 0.f, 0.f, 0.f};
      int byte = (row * 256 + c0 * 2 + q * 8) ^ ((row & 7) << 4);
      uint2 pv; pv.x = pk2(v.x, v.y); pv.y = pk2(v.z, v.w);
      *(uint2*)((char*)Al + byte) = pv;
    }
  }
  __syncthreads();

  f32x4 acc[4][4] = {}; // [row frag][col frag: 0,1=pre 2,3=merge]
  int lk = (l >> 4) * 8;
  #pragma unroll
  for (int ks = 0; ks < 4; ++ks){
    bf16x8 bf[4];
    #pragma unroll
    for (int fc = 0; fc < 4; ++fc){
      int j = (fc < 2) ? (cbase + fc * 16 + (l & 15))
                       : (256 + cbase + (fc - 2) * 16 + (l & 15));
      bf[fc] = *(const bf16x8*)(WT + (size_t)j * 128 + ks * 32 + lk);
    }
    bf16x8 af[4];
    #pragma unroll
    for (int fr = 0; fr < 4; ++fr){
      int row = fr * 16 + (l & 15);
      int byte = (row * 256 + ks * 64 + (l >> 4) * 16) ^ ((l & 7) << 4);
      af[fr] = *(const bf16x8*)((const char*)Al + byte);
    }
    #pragma unroll
    for (int fr = 0; fr < 4; ++fr)
      #pragma unroll
      for (int fc = 0; fc < 4; ++fc)
        acc[fr][fc] = __builtin_amdgcn_mfma_f32_16x16x32_bf16(af[fr], bf[fc], acc[fr][fc], 0, 0, 0);
  }

  #pragma unroll
  for (int fr = 0; fr < 4; ++fr){
    int rbase = n0 + fr * 16 + (l >> 4) * 4;
    #pragma unroll
    for (int fc = 0; fc < 2; ++fc){
      int j = cbase + fc * 16 + (l & 15);
      float bP = bpre[j], bM = bmrg[j];
      #pragma unroll
      for (int r = 0; r < 4; ++r){
        int rn = rbase + r;
        if (rn < n){
          float mg = acc[fr][fc + 2][r] + bM;
          float o  = acc[fr][fc][r] + bP + mg;
          merge[(size_t)rn * C2 + j] = f2bf(mg);
          outA [(size_t)rn * C2 + j] = f2bf(o > 0.f ? o : 0.f);
        }
      }
    }
  }
}

// ---- conv (MFMA), in place: buf = relu(blockdiag_conv(buf) + b_conv + merge) ----
// grid ceil(n/64), 512 threads (8 waves). Tile: 64 rows x 256 cols.
__global__ __launch_bounds__(512) void k_convM(u16* __restrict__ buf,
    const u16* __restrict__ Wc, const float* __restrict__ bc,
    const u16* __restrict__ merge, int n){
  __shared__ u16 Al[64 * 256]; // bf16, XOR-swizzled, 32KB
  int t = threadIdx.x;
  int w = t >> 6, l = t & 63;
  int n0 = blockIdx.x * 64;
  int wh = w >> 2;              // which 128-col half (selects A cols + W block)

  // stage A: 64 rows x 256 bf16. thread: row=t>>3, 32 cols.
  {
    int row = t >> 3, c0 = (t & 7) * 32;
    const u16* src = buf + (size_t)(n0 + row) * C2 + c0;
    bool ok = (n0 + row) < n;
    #pragma unroll
    for (int q = 0; q < 4; ++q){
      uint4 v = ok ? *(const uint4*)(src + q * 8) : uint4{0u, 0u, 0u, 0u};
      int byte = (row * 512 + c0 * 2 + q * 16) ^ ((row & 7) << 4);
      *(uint4*)((char*)Al + byte) = v;
    }
  }
  __syncthreads();

  f32x4 acc[4][2] = {};
  int lk = (l >> 4) * 8;
  #pragma unroll
  for (int ks = 0; ks < 4; ++ks){
    bf16x8 bf[2];
    #pragma unroll
    for (int fc = 0; fc < 2; ++fc){
      int rw = w * 32 + fc * 16 + (l & 15);   // = wh*128 + col
      bf[fc] = *(const bf16x8*)(Wc + (size_t)rw * 128 + ks * 32 + lk);
    }
    bf16x8 af[4];
    #pragma unroll
    for (int fr = 0; fr < 4; ++fr){
      int row = fr * 16 + (l & 15);
      int byte = (row * 512 + wh * 256 + ks * 64 + (l >> 4) * 16) ^ ((l & 7) << 4);
      af[fr] = *(const bf16x8*)((const char*)Al + byte);
    }
    #pragma unroll
    for (int fr = 0; fr < 4; ++fr)
      #pragma unroll
      for (int fc = 0; fc < 2; ++fc)
        acc[fr][fc] = __builtin_amdgcn_mfma_f32_16x16x32_bf16(af[fr], bf[fc], acc[fr][fc], 0, 0, 0);
  }

  #pragma unroll
  for (int fr = 0; fr < 4; ++fr){
    int rbase = n0 + fr * 16 + (l >> 4) * 4;
    #pragma unroll
    for (int fc = 0; fc < 2; ++fc){
      int j = w * 32 + fc * 16 + (l & 15);
      float bC = bc[j];
      #pragma unroll
      for (int r = 0; r < 4; ++r){
        int rn = rbase + r;
        if (rn < n){
          float o = acc[fr][fc][r] + bC + bf2f(merge[(size_t)rn * C2 + j]);
          buf[(size_t)rn * C2 + j] = f2bf(o > 0.f ? o : 0.f);
        }
      }
    }
  }
}

// ---- propagation: B[d] = norm[d] * sum_{e in in(d)} norm[s]*A[s] ----
__global__ __launch_bounds__(256) void k_prop(const u16* __restrict__ A, u16* __restrict__ B,
    const int* __restrict__ row_start, const int* __restrict__ csr,
    const float* __restrict__ norm, int n){
  int gw = (blockIdx.x * blockDim.x + threadIdx.x) >> 6;
  int lane = threadIdx.x & 63;
  if (gw >= n) return;
  int b = row_start[gw], e = row_start[gw + 1];
  float a0 = 0.f, a1 = 0.f, a2 = 0.f, a3 = 0.f;
  for (int j2 = b; j2 < e; ++j2){
    int s = csr[j2];
    float w = norm[s];
    uint2 rv = *(const uint2*)(A + (size_t)s * C2 + lane * 4);
    float2 p0 = bf2x2(rv.x), p1 = bf2x2(rv.y);
    a0 = fmaf(w, p0.x, a0); a1 = fmaf(w, p0.y, a1);
    a2 = fmaf(w, p1.x, a2); a3 = fmaf(w, p1.y, a3);
  }
  float nd = norm[gw];
  ushort4 ov;
  ov.x = f2bf(nd * a0); ov.y = f2bf(nd * a1);
  ov.z = f2bf(nd * a2); ov.w = f2bf(nd * a3);
  *(ushort4*)(B + (size_t)gw * C2 + lane * 4) = ov;
}

// ---- final: out[n][o] = mean(buf[n][2o], buf[n][2o+1]), f32 output ----
__global__ void k_final(const u16* __restrict__ buf, float* __restrict__ out, int total){
  int idx = blockIdx.x * blockDim.x + threadIdx.x;
  if (idx < total){
    int nn = idx >> 7, o = idx & 127;
    unsigned int pr = *(const unsigned int*)(buf + (size_t)nn * C2 + 2 * o);
    float2 v = bf2x2(pr);
    out[idx] = 0.5f * (v.x + v.y);
  }
}

extern "C" void kernel_launch(void* const* d_in, const int* in_sizes, int n_in,
                              void* d_out, int out_size, void* d_ws, size_t ws_size,
                              hipStream_t stream){
  const float* node = (const float*)d_in[0];
  const int*   eidx = (const int*)d_in[1];
  const float* Wpre = (const float*)d_in[2];
  const float* bpre = (const float*)d_in[3];
  const float* Wmrg = (const float*)d_in[4];
  const float* bmrg = (const float*)d_in[5];
  const float* Wcv  = (const float*)d_in[6];
  const float* bcv  = (const float*)d_in[7];
  float* out = (float*)d_out;

  const int n = in_sizes[0] / ICNST;
  const int E = in_sizes[1] / 2;
  const int* srcp = eidx;
  const int* dstp = eidx + E;

  char* ws = (char*)d_ws;
  size_t off = 0;
  auto alloc = [&](size_t bytes) -> char* {
    char* p = ws + off;
    off += bytes;
    off = (off + 255) & ~(size_t)255;
    return p;
  };
  int*   deg       = (int*)  alloc((size_t)n * 4);
  float* norm      = (float*)alloc((size_t)n * 4);
  int*   row_start = (int*)  alloc((size_t)(n + 1) * 4);
  int*   cursor    = (int*)  alloc((size_t)n * 4);
  int*   csr       = (int*)  alloc((size_t)E * 4);
  u16*   merge     = (u16*)  alloc((size_t)n * C2 * 2);
  u16*   bufA      = (u16*)  alloc((size_t)n * C2 * 2);
  u16*   bufB      = (u16*)  alloc((size_t)n * C2 * 2);
  u16*   WT        = (u16*)  alloc((size_t)512 * 128 * 2);
  u16*   Wcbf      = (u16*)  alloc((size_t)2 * 128 * 128 * 2);
  int*   bsum      = (int*)  alloc((size_t)256 * 4);
  (void)ws_size; (void)n_in; (void)out_size;

  const int nb = (n + 255) / 256;

  hipMemsetAsync(deg, 0, (size_t)n * 4, stream);
  k_cvtW<<<384, 256, 0, stream>>>(Wpre, Wmrg, Wcv, WT, Wcbf);
  k_deg<<<(E + 255) / 256, 256, 0, stream>>>(dstp, deg, E);
  k_scan1<<<nb, 256, 0, stream>>>(deg, bsum, n);
  k_scan2<<<1, 256, 0, stream>>>(bsum, nb);
  k_scan3<<<nb, 256, 0, stream>>>(deg, bsum, row_start, cursor, norm, n);
  k_scatter<<<(E + 255) / 256, 256, 0, stream>>>(srcp, dstp, cursor, csr, E);

  int gb = (n + 63) / 64;
  k_initM<<<dim3(gb, 2), 256, 0, stream>>>(node, WT, bpre, bmrg, merge, bufA, n);

  // iteration 1: prop A->B, conv in-place B
  k_prop<<<(n + 3) / 4, 256, 0, stream>>>(bufA, bufB, row_start, csr, norm, n);
  k_convM<<<gb, 512, 0, stream>>>(bufB, Wcbf, bcv, merge, n);
  // iteration 2: prop B->A, conv in-place A
  k_prop<<<(n + 3) / 4, 256, 0, stream>>>(bufB, bufA, row_start, csr, norm, n);
  k_convM<<<gb, 512, 0, stream>>>(bufA, Wcbf, bcv, merge, n);

  k_final<<<((n * 128) + 255) / 256, 256, 0, stream>>>(bufA, out, n * 128);
}

// Round 5
// 240.829 us; speedup vs baseline: 3.8573x; 1.1807x over previous
//
#include <hip/hip_runtime.h>

typedef unsigned short u16;
typedef __attribute__((ext_vector_type(8))) short bf16x8;
typedef __attribute__((ext_vector_type(4))) float f32x4;

#define ICNST 128
#define C2 256   // OC*WIDTH

__device__ __forceinline__ float bf2f(u16 u){
  return __uint_as_float(((unsigned int)u) << 16);
}
__device__ __forceinline__ float2 bf2x2(unsigned int u){
  float2 r;
  r.x = __uint_as_float(u << 16);
  r.y = __uint_as_float(u & 0xffff0000u);
  return r;
}
__device__ __forceinline__ u16 f2bf(float f){
  unsigned int u = __float_as_uint(f);
  unsigned int r = (u + 0x7fffu + ((u >> 16) & 1u)) >> 16;
  return (u16)r;
}
__device__ __forceinline__ unsigned int pk2(float a, float b){
  return (unsigned int)f2bf(a) | ((unsigned int)f2bf(b) << 16);
}

// ---- degree count ----
__global__ void k_deg(const int* __restrict__ dst, int* __restrict__ deg, int E){
  int e = blockIdx.x * blockDim.x + threadIdx.x;
  if (e < E) atomicAdd(&deg[dst[e]], 1);
}

// ---- hierarchical scan: 1) per-block sums ----
__global__ __launch_bounds__(256) void k_scan1(const int* __restrict__ deg,
    int* __restrict__ bsum, int n){
  __shared__ int red[256];
  int t = threadIdx.x;
  int i = blockIdx.x * 256 + t;
  red[t] = (i < n) ? deg[i] : 0;
  __syncthreads();
  for (int off = 128; off > 0; off >>= 1){
    if (t < off) red[t] += red[t + off];
    __syncthreads();
  }
  if (t == 0) bsum[blockIdx.x] = red[0];
}

// ---- 2) single-block exclusive scan of block sums (nb <= 256) ----
__global__ __launch_bounds__(256) void k_scan2(int* __restrict__ bsum, int nb){
  __shared__ int s[256];
  int t = threadIdx.x;
  int v = (t < nb) ? bsum[t] : 0;
  s[t] = v;
  __syncthreads();
  for (int off = 1; off < 256; off <<= 1){
    int u = (t >= off) ? s[t - off] : 0;
    __syncthreads();
    s[t] += u;
    __syncthreads();
  }
  if (t < nb) bsum[t] = s[t] - v; // exclusive
}

// ---- 3) block-local exclusive scan + offset -> row_start, cursor, norm ----
__global__ __launch_bounds__(256) void k_scan3(const int* __restrict__ deg,
    const int* __restrict__ bsum, int* __restrict__ row_start,
    int* __restrict__ cursor, float* __restrict__ norm, int n){
  __shared__ int s[256];
  int t = threadIdx.x;
  int i = blockIdx.x * 256 + t;
  int v = (i < n) ? deg[i] : 0;
  s[t] = v;
  __syncthreads();
  for (int off = 1; off < 256; off <<= 1){
    int u = (t >= off) ? s[t - off] : 0;
    __syncthreads();
    s[t] += u;
    __syncthreads();
  }
  int ex = s[t] - v + bsum[blockIdx.x];
  if (i < n){
    row_start[i] = ex;
    cursor[i] = ex;
    norm[i] = (v > 0) ? rsqrtf((float)v) : 0.f;
    if (i == n - 1) row_start[n] = ex + v;
  }
}

// ---- scatter edges into CSR slots ----
__global__ void k_scatter(const int* __restrict__ src, const int* __restrict__ dstA,
    int* __restrict__ cursor, int* __restrict__ csr_src, int E){
  int e = blockIdx.x * blockDim.x + threadIdx.x;
  if (e < E){
    int d = dstA[e];
    int pos = atomicAdd(&cursor[d], 1);
    csr_src[pos] = src[e];
  }
}

// ---- convert weights to bf16: WT[j][k] = (j<256?Wpre:Wmrg)[k][j'], Wc_bf = Wcv ----
__global__ void k_cvtW(const float* __restrict__ Wpre, const float* __restrict__ Wmrg,
    const float* __restrict__ Wcv, u16* __restrict__ WT, u16* __restrict__ Wc){
  int idx = blockIdx.x * blockDim.x + threadIdx.x;
  if (idx < 65536){
    int j = idx & 511, k = idx >> 9;
    float v = (j < 256) ? Wpre[k * 256 + j] : Wmrg[k * 256 + (j - 256)];
    WT[j * 128 + k] = f2bf(v);
  } else if (idx < 65536 + 32768){
    int x = idx - 65536;
    Wc[x] = f2bf(Wcv[x]);
  }
}

// ---- init (MFMA): merge = X@Wm + bm; bufA = norm .* relu(X@Wp + bp + merge) ----
// grid (ceil(n/64), 2), 256 threads (4 waves). Tile: 64 rows x 128 paired cols.
__global__ __launch_bounds__(256) void k_initM(const float* __restrict__ node,
    const u16* __restrict__ WT, const float* __restrict__ bpre,
    const float* __restrict__ bmrg, const float* __restrict__ norm,
    u16* __restrict__ merge, u16* __restrict__ outA, int n){
  __shared__ u16 Al[64 * 128]; // bf16, XOR-swizzled, 16KB
  int t = threadIdx.x;
  int w = t >> 6, l = t & 63;
  int n0 = blockIdx.x * 64;
  int cbase = blockIdx.y * 128 + w * 32; // paired-col base for this wave

  // stage A: 64 rows x 128 f32 -> bf16 swizzled LDS. thread: row=t>>2, 32 cols.
  {
    int row = t >> 2, c0 = (t & 3) * 32;
    const float* src = node + (size_t)(n0 + row) * ICNST + c0;
    bool ok = (n0 + row) < n;
    #pragma unroll
    for (int q = 0; q < 8; ++q){
      float4 v = ok ? *(const float4*)(src + q * 4) : float4{0.f, 0.f, 0.f, 0.f};
      int byte = (row * 256 + c0 * 2 + q * 8) ^ ((row & 7) << 4);
      uint2 pv; pv.x = pk2(v.x, v.y); pv.y = pk2(v.z, v.w);
      *(uint2*)((char*)Al + byte) = pv;
    }
  }
  __syncthreads();

  f32x4 acc[4][4] = {}; // [row frag][col frag: 0,1=pre 2,3=merge]
  int lk = (l >> 4) * 8;
  #pragma unroll
  for (int ks = 0; ks < 4; ++ks){
    bf16x8 bf[4];
    #pragma unroll
    for (int fc = 0; fc < 4; ++fc){
      int j = (fc < 2) ? (cbase + fc * 16 + (l & 15))
                       : (256 + cbase + (fc - 2) * 16 + (l & 15));
      bf[fc] = *(const bf16x8*)(WT + (size_t)j * 128 + ks * 32 + lk);
    }
    bf16x8 af[4];
    #pragma unroll
    for (int fr = 0; fr < 4; ++fr){
      int row = fr * 16 + (l & 15);
      int byte = (row * 256 + ks * 64 + (l >> 4) * 16) ^ ((l & 7) << 4);
      af[fr] = *(const bf16x8*)((const char*)Al + byte);
    }
    #pragma unroll
    for (int fr = 0; fr < 4; ++fr)
      #pragma unroll
      for (int fc = 0; fc < 4; ++fc)
        acc[fr][fc] = __builtin_amdgcn_mfma_f32_16x16x32_bf16(af[fr], bf[fc], acc[fr][fc], 0, 0, 0);
  }

  #pragma unroll
  for (int fr = 0; fr < 4; ++fr){
    int rbase = n0 + fr * 16 + (l >> 4) * 4;
    float nrm[4];
    #pragma unroll
    for (int r = 0; r < 4; ++r)
      nrm[r] = (rbase + r < n) ? norm[rbase + r] : 0.f;
    #pragma unroll
    for (int fc = 0; fc < 2; ++fc){
      int j = cbase + fc * 16 + (l & 15);
      float bP = bpre[j], bM = bmrg[j];
      #pragma unroll
      for (int r = 0; r < 4; ++r){
        int rn = rbase + r;
        if (rn < n){
          float mg = acc[fr][fc + 2][r] + bM;
          float o  = acc[fr][fc][r] + bP + mg;
          o = (o > 0.f) ? o : 0.f;
          merge[(size_t)rn * C2 + j] = f2bf(mg);
          outA [(size_t)rn * C2 + j] = f2bf(nrm[r] * o);
        }
      }
    }
  }
}

// ---- conv (MFMA), in place. FINAL=0: buf = norm .* relu(conv(buf)+bc+merge)
//      FINAL=1: out[n][o] = mean of pairs of relu(conv(buf)+bc+merge), f32 ----
template<int FINAL>
__global__ __launch_bounds__(512) void k_convM(u16* __restrict__ buf,
    const u16* __restrict__ Wc, const float* __restrict__ bc,
    const u16* __restrict__ merge, const float* __restrict__ norm,
    float* __restrict__ out, int n){
  __shared__ u16 Al[64 * 256]; // bf16, XOR-swizzled, 32KB
  int t = threadIdx.x;
  int w = t >> 6, l = t & 63;
  int n0 = blockIdx.x * 64;
  int wh = w >> 2;              // which 128-col half (selects A cols + W block)

  // stage A: 64 rows x 256 bf16. thread: row=t>>3, 32 cols.
  {
    int row = t >> 3, c0 = (t & 7) * 32;
    const u16* src = buf + (size_t)(n0 + row) * C2 + c0;
    bool ok = (n0 + row) < n;
    #pragma unroll
    for (int q = 0; q < 4; ++q){
      uint4 v = ok ? *(const uint4*)(src + q * 8) : uint4{0u, 0u, 0u, 0u};
      int byte = (row * 512 + c0 * 2 + q * 16) ^ ((row & 7) << 4);
      *(uint4*)((char*)Al + byte) = v;
    }
  }
  __syncthreads();

  f32x4 acc[4][2] = {};
  int lk = (l >> 4) * 8;
  #pragma unroll
  for (int ks = 0; ks < 4; ++ks){
    bf16x8 bf[2];
    #pragma unroll
    for (int fc = 0; fc < 2; ++fc){
      int rw = w * 32 + fc * 16 + (l & 15);   // = wh*128 + col
      bf[fc] = *(const bf16x8*)(Wc + (size_t)rw * 128 + ks * 32 + lk);
    }
    bf16x8 af[4];
    #pragma unroll
    for (int fr = 0; fr < 4; ++fr){
      int row = fr * 16 + (l & 15);
      int byte = (row * 512 + wh * 256 + ks * 64 + (l >> 4) * 16) ^ ((l & 7) << 4);
      af[fr] = *(const bf16x8*)((const char*)Al + byte);
    }
    #pragma unroll
    for (int fr = 0; fr < 4; ++fr)
      #pragma unroll
      for (int fc = 0; fc < 2; ++fc)
        acc[fr][fc] = __builtin_amdgcn_mfma_f32_16x16x32_bf16(af[fr], bf[fc], acc[fr][fc], 0, 0, 0);
  }

  #pragma unroll
  for (int fr = 0; fr < 4; ++fr){
    int rbase = n0 + fr * 16 + (l >> 4) * 4;
    float nrm[4];
    if (!FINAL){
      #pragma unroll
      for (int r = 0; r < 4; ++r)
        nrm[r] = (rbase + r < n) ? norm[rbase + r] : 0.f;
    }
    #pragma unroll
    for (int fc = 0; fc < 2; ++fc){
      int j = w * 32 + fc * 16 + (l & 15);
      float bC = bc[j];
      #pragma unroll
      for (int r = 0; r < 4; ++r){
        int rn = rbase + r;
        float mg = (rn < n) ? bf2f(merge[(size_t)rn * C2 + j]) : 0.f;
        float o = acc[fr][fc][r] + bC + mg;
        float v = (o > 0.f) ? o : 0.f;
        if (!FINAL){
          if (rn < n) buf[(size_t)rn * C2 + j] = f2bf(nrm[r] * v);
        } else {
          float vx = __shfl_xor(v, 1, 64);
          if (!(l & 1) && rn < n)
            out[(size_t)rn * 128 + (j >> 1)] = 0.5f * (v + vx);
        }
      }
    }
  }
}

// ---- propagation: B[d] = norm[d] * sum_{e in in(d)} A[s]  (A pre-scaled) ----
__global__ __launch_bounds__(256) void k_prop(const u16* __restrict__ A, u16* __restrict__ B,
    const int* __restrict__ row_start, const int* __restrict__ csr,
    const float* __restrict__ norm, int n){
  int gw = (blockIdx.x * blockDim.x + threadIdx.x) >> 6;
  int lane = threadIdx.x & 63;
  if (gw >= n) return;
  int b = row_start[gw], e = row_start[gw + 1];
  float a0 = 0.f, a1 = 0.f, a2 = 0.f, a3 = 0.f;
  int j = b;
  for (; j + 4 <= e; j += 4){
    int i0 = csr[j], i1 = csr[j + 1], i2 = csr[j + 2], i3 = csr[j + 3];
    uint2 r0 = *(const uint2*)(A + (size_t)i0 * C2 + lane * 4);
    uint2 r1 = *(const uint2*)(A + (size_t)i1 * C2 + lane * 4);
    uint2 r2 = *(const uint2*)(A + (size_t)i2 * C2 + lane * 4);
    uint2 r3 = *(const uint2*)(A + (size_t)i3 * C2 + lane * 4);
    float2 p;
    p = bf2x2(r0.x); a0 += p.x; a1 += p.y; p = bf2x2(r0.y); a2 += p.x; a3 += p.y;
    p = bf2x2(r1.x); a0 += p.x; a1 += p.y; p = bf2x2(r1.y); a2 += p.x; a3 += p.y;
    p = bf2x2(r2.x); a0 += p.x; a1 += p.y; p = bf2x2(r2.y); a2 += p.x; a3 += p.y;
    p = bf2x2(r3.x); a0 += p.x; a1 += p.y; p = bf2x2(r3.y); a2 += p.x; a3 += p.y;
  }
  for (; j < e; ++j){
    int i0 = csr[j];
    uint2 r0 = *(const uint2*)(A + (size_t)i0 * C2 + lane * 4);
    float2 p;
    p = bf2x2(r0.x); a0 += p.x; a1 += p.y; p = bf2x2(r0.y); a2 += p.x; a3 += p.y;
  }
  float nd = norm[gw];
  ushort4 ov;
  ov.x = f2bf(nd * a0); ov.y = f2bf(nd * a1);
  ov.z = f2bf(nd * a2); ov.w = f2bf(nd * a3);
  *(ushort4*)(B + (size_t)gw * C2 + lane * 4) = ov;
}

extern "C" void kernel_launch(void* const* d_in, const int* in_sizes, int n_in,
                              void* d_out, int out_size, void* d_ws, size_t ws_size,
                              hipStream_t stream){
  const float* node = (const float*)d_in[0];
  const int*   eidx = (const int*)d_in[1];
  const float* Wpre = (const float*)d_in[2];
  const float* bpre = (const float*)d_in[3];
  const float* Wmrg = (const float*)d_in[4];
  const float* bmrg = (const float*)d_in[5];
  const float* Wcv  = (const float*)d_in[6];
  const float* bcv  = (const float*)d_in[7];
  float* out = (float*)d_out;

  const int n = in_sizes[0] / ICNST;
  const int E = in_sizes[1] / 2;
  const int* srcp = eidx;
  const int* dstp = eidx + E;

  char* ws = (char*)d_ws;
  size_t off = 0;
  auto alloc = [&](size_t bytes) -> char* {
    char* p = ws + off;
    off += bytes;
    off = (off + 255) & ~(size_t)255;
    return p;
  };
  int*   deg       = (int*)  alloc((size_t)n * 4);
  float* norm      = (float*)alloc((size_t)n * 4);
  int*   row_start = (int*)  alloc((size_t)(n + 1) * 4);
  int*   cursor    = (int*)  alloc((size_t)n * 4);
  int*   csr       = (int*)  alloc((size_t)E * 4);
  u16*   merge     = (u16*)  alloc((size_t)n * C2 * 2);
  u16*   bufA      = (u16*)  alloc((size_t)n * C2 * 2);
  u16*   bufB      = (u16*)  alloc((size_t)n * C2 * 2);
  u16*   WT        = (u16*)  alloc((size_t)512 * 128 * 2);
  u16*   Wcbf      = (u16*)  alloc((size_t)2 * 128 * 128 * 2);
  int*   bsum      = (int*)  alloc((size_t)256 * 4);
  (void)ws_size; (void)n_in; (void)out_size;

  const int nb = (n + 255) / 256;

  hipMemsetAsync(deg, 0, (size_t)n * 4, stream);
  k_cvtW<<<384, 256, 0, stream>>>(Wpre, Wmrg, Wcv, WT, Wcbf);
  k_deg<<<(E + 255) / 256, 256, 0, stream>>>(dstp, deg, E);
  k_scan1<<<nb, 256, 0, stream>>>(deg, bsum, n);
  k_scan2<<<1, 256, 0, stream>>>(bsum, nb);
  k_scan3<<<nb, 256, 0, stream>>>(deg, bsum, row_start, cursor, norm, n);
  k_scatter<<<(E + 255) / 256, 256, 0, stream>>>(srcp, dstp, cursor, csr, E);

  int gb = (n + 63) / 64;
  k_initM<<<dim3(gb, 2), 256, 0, stream>>>(node, WT, bpre, bmrg, norm, merge, bufA, n);

  // iteration 1: prop A->B (pre-scaled rows), conv in-place B (writes scaled)
  k_prop<<<(n + 3) / 4, 256, 0, stream>>>(bufA, bufB, row_start, csr, norm, n);
  k_convM<0><<<gb, 512, 0, stream>>>(bufB, Wcbf, bcv, merge, norm, nullptr, n);
  // iteration 2: prop B->A, conv fused with final mean -> out
  k_prop<<<(n + 3) / 4, 256, 0, stream>>>(bufB, bufA, row_start, csr, norm, n);
  k_convM<1><<<gb, 512, 0, stream>>>(bufA, Wcbf, bcv, merge, norm, out, n);
}

// Round 7
// 232.557 us; speedup vs baseline: 3.9945x; 1.0356x over previous
//
#include <hip/hip_runtime.h>

typedef unsigned short u16;
typedef __attribute__((ext_vector_type(8))) short bf16x8;
typedef __attribute__((ext_vector_type(4))) float f32x4;

#define ICNST 128
#define C2 256   // OC*WIDTH

__device__ __forceinline__ float bf2f(u16 u){
  return __uint_as_float(((unsigned int)u) << 16);
}
__device__ __forceinline__ float2 bf2x2(unsigned int u){
  float2 r;
  r.x = __uint_as_float(u << 16);
  r.y = __uint_as_float(u & 0xffff0000u);
  return r;
}
__device__ __forceinline__ u16 f2bf(float f){
  unsigned int u = __float_as_uint(f);
  unsigned int r = (u + 0x7fffu + ((u >> 16) & 1u)) >> 16;
  return (u16)r;
}
__device__ __forceinline__ unsigned int pk2(float a, float b){
  return (unsigned int)f2bf(a) | ((unsigned int)f2bf(b) << 16);
}

// ---- degree count ----
__global__ void k_deg(const int* __restrict__ dst, int* __restrict__ deg, int E){
  int e = blockIdx.x * blockDim.x + threadIdx.x;
  if (e < E) atomicAdd(&deg[dst[e]], 1);
}

// ---- hierarchical scan: 1) per-block sums ----
__global__ __launch_bounds__(256) void k_scan1(const int* __restrict__ deg,
    int* __restrict__ bsum, int n){
  __shared__ int red[256];
  int t = threadIdx.x;
  int i = blockIdx.x * 256 + t;
  red[t] = (i < n) ? deg[i] : 0;
  __syncthreads();
  for (int off = 128; off > 0; off >>= 1){
    if (t < off) red[t] += red[t + off];
    __syncthreads();
  }
  if (t == 0) bsum[blockIdx.x] = red[0];
}

// ---- 2) single-block exclusive scan of block sums (nb <= 256) ----
__global__ __launch_bounds__(256) void k_scan2(int* __restrict__ bsum, int nb){
  __shared__ int s[256];
  int t = threadIdx.x;
  int v = (t < nb) ? bsum[t] : 0;
  s[t] = v;
  __syncthreads();
  for (int off = 1; off < 256; off <<= 1){
    int u = (t >= off) ? s[t - off] : 0;
    __syncthreads();
    s[t] += u;
    __syncthreads();
  }
  if (t < nb) bsum[t] = s[t] - v; // exclusive
}

// ---- 3) block-local exclusive scan + offset -> row_start, cursor, norm ----
__global__ __launch_bounds__(256) void k_scan3(const int* __restrict__ deg,
    const int* __restrict__ bsum, int* __restrict__ row_start,
    int* __restrict__ cursor, float* __restrict__ norm, int n){
  __shared__ int s[256];
  int t = threadIdx.x;
  int i = blockIdx.x * 256 + t;
  int v = (i < n) ? deg[i] : 0;
  s[t] = v;
  __syncthreads();
  for (int off = 1; off < 256; off <<= 1){
    int u = (t >= off) ? s[t - off] : 0;
    __syncthreads();
    s[t] += u;
    __syncthreads();
  }
  int ex = s[t] - v + bsum[blockIdx.x];
  if (i < n){
    row_start[i] = ex;
    cursor[i] = ex;
    norm[i] = (v > 0) ? rsqrtf((float)v) : 0.f;
    if (i == n - 1) row_start[n] = ex + v;
  }
}

// ---- scatter edges into CSR slots ----
__global__ void k_scatter(const int* __restrict__ src, const int* __restrict__ dstA,
    int* __restrict__ cursor, int* __restrict__ csr_src, int E){
  int e = blockIdx.x * blockDim.x + threadIdx.x;
  if (e < E){
    int d = dstA[e];
    int pos = atomicAdd(&cursor[d], 1);
    csr_src[pos] = src[e];
  }
}

// ---- convert weights to bf16: WT[j][k] = (j<256?Wpre:Wmrg)[k][j'], Wc_bf = Wcv ----
__global__ void k_cvtW(const float* __restrict__ Wpre, const float* __restrict__ Wmrg,
    const float* __restrict__ Wcv, u16* __restrict__ WT, u16* __restrict__ Wc){
  int idx = blockIdx.x * blockDim.x + threadIdx.x;
  if (idx < 65536){
    int j = idx & 511, k = idx >> 9;
    float v = (j < 256) ? Wpre[k * 256 + j] : Wmrg[k * 256 + (j - 256)];
    WT[j * 128 + k] = f2bf(v);
  } else if (idx < 65536 + 32768){
    int x = idx - 65536;
    Wc[x] = f2bf(Wcv[x]);
  }
}

// ---- init (MFMA, swapped-D): merge = X@Wm + bm; bufA = norm .* relu(X@Wp + bp + merge)
// grid (ceil(n/128), 2), 512 threads (8 waves = 2 row groups x 4 col groups).
// blockIdx.y selects which 128 of the 256 paired columns.
__global__ __launch_bounds__(512) void k_initM(const float* __restrict__ node,
    const u16* __restrict__ WT, const float* __restrict__ bpre,
    const float* __restrict__ bmrg, const float* __restrict__ norm,
    u16* __restrict__ merge, u16* __restrict__ outA, int n){
  __shared__ u16 Al[128 * 128]; // bf16, XOR-swizzled, 32KB
  int t = threadIdx.x;
  int w = t >> 6, l = t & 63;
  int n0 = blockIdx.x * 128;
  int rg = (w >> 2) * 64;                       // row group for this wave
  int cb = blockIdx.y * 128 + (w & 3) * 32;     // paired-col base for this wave

  // stage A: 128 rows x 128 f32 -> bf16 swizzled LDS. thread: row=t>>2, 32 cols.
  {
    int row = t >> 2, c0 = (t & 3) * 32;
    const float* src = node + (size_t)(n0 + row) * ICNST + c0;
    bool ok = (n0 + row) < n;
    #pragma unroll
    for (int q = 0; q < 8; ++q){
      float4 v = ok ? *(const float4*)(src + q * 4) : float4{0.f, 0.f, 0.f, 0.f};
      int byte = (row * 256 + c0 * 2 + q * 8) ^ ((row & 7) << 4);
      uint2 pv; pv.x = pk2(v.x, v.y); pv.y = pk2(v.z, v.w);
      *(uint2*)((char*)Al + byte) = pv;
    }
  }
  __syncthreads();

  f32x4 acc[4][4] = {}; // [row frag][col frag: 0,1=pre 2,3=merge], D transposed
  int lk = (l >> 4) * 8;
  #pragma unroll
  for (int ks = 0; ks < 4; ++ks){
    bf16x8 bf[4];
    #pragma unroll
    for (int fc = 0; fc < 4; ++fc){
      int j = (fc < 2) ? (cb + fc * 16 + (l & 15))
                       : (256 + cb + (fc - 2) * 16 + (l & 15));
      bf[fc] = *(const bf16x8*)(WT + (size_t)j * 128 + ks * 32 + lk);
    }
    bf16x8 af[4];
    #pragma unroll
    for (int fr = 0; fr < 4; ++fr){
      int row = rg + fr * 16 + (l & 15);
      int byte = (row * 256 + ks * 64 + (l >> 4) * 16) ^ ((l & 7) << 4);
      af[fr] = *(const bf16x8*)((const char*)Al + byte);
    }
    #pragma unroll
    for (int fr = 0; fr < 4; ++fr)
      #pragma unroll
      for (int fc = 0; fc < 4; ++fc)
        acc[fr][fc] = __builtin_amdgcn_mfma_f32_16x16x32_bf16(bf[fc], af[fr], acc[fr][fc], 0, 0, 0);
  }

  // epilogue: lane holds 4 consecutive j's (reg r -> j0+r); node row = l&15 slot
  #pragma unroll
  for (int fr = 0; fr < 4; ++fr){
    int row = n0 + rg + fr * 16 + (l & 15);
    bool ok = row < n;
    float nr = ok ? norm[row] : 0.f;
    #pragma unroll
    for (int fcp = 0; fcp < 2; ++fcp){
      int j0 = cb + fcp * 16 + (l >> 4) * 4;
      float4 bP = *(const float4*)(bpre + j0);
      float4 bM = *(const float4*)(bmrg + j0);
      f32x4 aP = acc[fr][fcp], aM = acc[fr][fcp + 2];
      float bPe[4] = {bP.x, bP.y, bP.z, bP.w};
      float bMe[4] = {bM.x, bM.y, bM.z, bM.w};
      ushort4 mgv, outv;
      u16* mgp = (u16*)&mgv; u16* otp = (u16*)&outv;
      #pragma unroll
      for (int r = 0; r < 4; ++r){
        float mg = aM[r] + bMe[r];
        float o  = aP[r] + bPe[r] + mg;
        o = (o > 0.f) ? o : 0.f;
        mgp[r] = f2bf(mg);
        otp[r] = f2bf(nr * o);
      }
      if (ok){
        *(ushort4*)(merge + (size_t)row * C2 + j0) = mgv;
        *(ushort4*)(outA  + (size_t)row * C2 + j0) = outv;
      }
    }
  }
}

// ---- conv (MFMA, swapped-D), in place. FINAL=0: buf = norm .* relu(conv+bc+merge)
//      FINAL=1: out[row][j/2] = pair-mean of relu(conv+bc+merge), f32 ----
template<int FINAL>
__global__ __launch_bounds__(512) void k_convM(u16* __restrict__ buf,
    const u16* __restrict__ Wc, const float* __restrict__ bc,
    const u16* __restrict__ merge, const float* __restrict__ norm,
    float* __restrict__ out, int n){
  __shared__ u16 Al[64 * 256]; // bf16, XOR-swizzled, 32KB
  int t = threadIdx.x;
  int w = t >> 6, l = t & 63;
  int n0 = blockIdx.x * 64;
  int wh = w >> 2;              // which 128-col half (selects A cols + W block)

  // stage A: 64 rows x 256 bf16. thread: row=t>>3, 32 cols.
  {
    int row = t >> 3, c0 = (t & 7) * 32;
    const u16* src = buf + (size_t)(n0 + row) * C2 + c0;
    bool ok = (n0 + row) < n;
    #pragma unroll
    for (int q = 0; q < 4; ++q){
      uint4 v = ok ? *(const uint4*)(src + q * 8) : uint4{0u, 0u, 0u, 0u};
      int byte = (row * 512 + c0 * 2 + q * 16) ^ ((row & 7) << 4);
      *(uint4*)((char*)Al + byte) = v;
    }
  }
  __syncthreads();

  f32x4 acc[4][2] = {}; // D transposed: reg r -> output col j0+r
  int lk = (l >> 4) * 8;
  #pragma unroll
  for (int ks = 0; ks < 4; ++ks){
    bf16x8 bf[2];
    #pragma unroll
    for (int fc = 0; fc < 2; ++fc){
      int rw = w * 32 + fc * 16 + (l & 15);   // = wh*128 + col
      bf[fc] = *(const bf16x8*)(Wc + (size_t)rw * 128 + ks * 32 + lk);
    }
    bf16x8 af[4];
    #pragma unroll
    for (int fr = 0; fr < 4; ++fr){
      int row = fr * 16 + (l & 15);
      int byte = (row * 512 + wh * 256 + ks * 64 + (l >> 4) * 16) ^ ((l & 7) << 4);
      af[fr] = *(const bf16x8*)((const char*)Al + byte);
    }
    #pragma unroll
    for (int fr = 0; fr < 4; ++fr)
      #pragma unroll
      for (int fc = 0; fc < 2; ++fc)
        acc[fr][fc] = __builtin_amdgcn_mfma_f32_16x16x32_bf16(bf[fc], af[fr], acc[fr][fc], 0, 0, 0);
  }

  #pragma unroll
  for (int fr = 0; fr < 4; ++fr){
    int row = n0 + fr * 16 + (l & 15);
    bool ok = row < n;
    float nr = 0.f;
    if (!FINAL) nr = ok ? norm[row] : 0.f;
    #pragma unroll
    for (int fc = 0; fc < 2; ++fc){
      int j0 = w * 32 + fc * 16 + (l >> 4) * 4;
      float4 bC = *(const float4*)(bc + j0);
      float bCe[4] = {bC.x, bC.y, bC.z, bC.w};
      ushort4 mg4 = ok ? *(const ushort4*)(merge + (size_t)row * C2 + j0)
                       : ushort4{0, 0, 0, 0};
      const u16* mge = (const u16*)&mg4;
      float v[4];
      #pragma unroll
      for (int r = 0; r < 4; ++r){
        float o = acc[fr][fc][r] + bCe[r] + bf2f(mge[r]);
        v[r] = (o > 0.f) ? o : 0.f;
      }
      if (!FINAL){
        ushort4 ov;
        u16* ovp = (u16*)&ov;
        #pragma unroll
        for (int r = 0; r < 4; ++r) ovp[r] = f2bf(nr * v[r]);
        if (ok) *(ushort4*)(buf + (size_t)row * C2 + j0) = ov;
      } else {
        float2 om;
        om.x = 0.5f * (v[0] + v[1]);
        om.y = 0.5f * (v[2] + v[3]);
        if (ok) *(float2*)(out + (size_t)row * 128 + (j0 >> 1)) = om;
      }
    }
  }
}

// ---- propagation: B[d] = norm[d] * sum_{e in in(d)} A[s]  (A pre-scaled) ----
__global__ __launch_bounds__(256) void k_prop(const u16* __restrict__ A, u16* __restrict__ B,
    const int* __restrict__ row_start, const int* __restrict__ csr,
    const float* __restrict__ norm, int n){
  int gw = (blockIdx.x * blockDim.x + threadIdx.x) >> 6;
  int lane = threadIdx.x & 63;
  if (gw >= n) return;
  int b = row_start[gw], e = row_start[gw + 1];
  float a0 = 0.f, a1 = 0.f, a2 = 0.f, a3 = 0.f;
  int j = b;
  for (; j + 4 <= e; j += 4){
    int i0 = csr[j], i1 = csr[j + 1], i2 = csr[j + 2], i3 = csr[j + 3];
    uint2 r0 = *(const uint2*)(A + (size_t)i0 * C2 + lane * 4);
    uint2 r1 = *(const uint2*)(A + (size_t)i1 * C2 + lane * 4);
    uint2 r2 = *(const uint2*)(A + (size_t)i2 * C2 + lane * 4);
    uint2 r3 = *(const uint2*)(A + (size_t)i3 * C2 + lane * 4);
    float2 p;
    p = bf2x2(r0.x); a0 += p.x; a1 += p.y; p = bf2x2(r0.y); a2 += p.x; a3 += p.y;
    p = bf2x2(r1.x); a0 += p.x; a1 += p.y; p = bf2x2(r1.y); a2 += p.x; a3 += p.y;
    p = bf2x2(r2.x); a0 += p.x; a1 += p.y; p = bf2x2(r2.y); a2 += p.x; a3 += p.y;
    p = bf2x2(r3.x); a0 += p.x; a1 += p.y; p = bf2x2(r3.y); a2 += p.x; a3 += p.y;
  }
  for (; j < e; ++j){
    int i0 = csr[j];
    uint2 r0 = *(const uint2*)(A + (size_t)i0 * C2 + lane * 4);
    float2 p;
    p = bf2x2(r0.x); a0 += p.x; a1 += p.y; p = bf2x2(r0.y); a2 += p.x; a3 += p.y;
  }
  float nd = norm[gw];
  ushort4 ov;
  ov.x = f2bf(nd * a0); ov.y = f2bf(nd * a1);
  ov.z = f2bf(nd * a2); ov.w = f2bf(nd * a3);
  *(ushort4*)(B + (size_t)gw * C2 + lane * 4) = ov;
}

extern "C" void kernel_launch(void* const* d_in, const int* in_sizes, int n_in,
                              void* d_out, int out_size, void* d_ws, size_t ws_size,
                              hipStream_t stream){
  const float* node = (const float*)d_in[0];
  const int*   eidx = (const int*)d_in[1];
  const float* Wpre = (const float*)d_in[2];
  const float* bpre = (const float*)d_in[3];
  const float* Wmrg = (const float*)d_in[4];
  const float* bmrg = (const float*)d_in[5];
  const float* Wcv  = (const float*)d_in[6];
  const float* bcv  = (const float*)d_in[7];
  float* out = (float*)d_out;

  const int n = in_sizes[0] / ICNST;
  const int E = in_sizes[1] / 2;
  const int* srcp = eidx;
  const int* dstp = eidx + E;

  char* ws = (char*)d_ws;
  size_t off = 0;
  auto alloc = [&](size_t bytes) -> char* {
    char* p = ws + off;
    off += bytes;
    off = (off + 255) & ~(size_t)255;
    return p;
  };
  int*   deg       = (int*)  alloc((size_t)n * 4);
  float* norm      = (float*)alloc((size_t)n * 4);
  int*   row_start = (int*)  alloc((size_t)(n + 1) * 4);
  int*   cursor    = (int*)  alloc((size_t)n * 4);
  int*   csr       = (int*)  alloc((size_t)E * 4);
  u16*   merge     = (u16*)  alloc((size_t)n * C2 * 2);
  u16*   bufA      = (u16*)  alloc((size_t)n * C2 * 2);
  u16*   bufB      = (u16*)  alloc((size_t)n * C2 * 2);
  u16*   WT        = (u16*)  alloc((size_t)512 * 128 * 2);
  u16*   Wcbf      = (u16*)  alloc((size_t)2 * 128 * 128 * 2);
  int*   bsum      = (int*)  alloc((size_t)256 * 4);
  (void)ws_size; (void)n_in; (void)out_size;

  const int nb = (n + 255) / 256;

  hipMemsetAsync(deg, 0, (size_t)n * 4, stream);
  k_cvtW<<<384, 256, 0, stream>>>(Wpre, Wmrg, Wcv, WT, Wcbf);
  k_deg<<<(E + 255) / 256, 256, 0, stream>>>(dstp, deg, E);
  k_scan1<<<nb, 256, 0, stream>>>(deg, bsum, n);
  k_scan2<<<1, 256, 0, stream>>>(bsum, nb);
  k_scan3<<<nb, 256, 0, stream>>>(deg, bsum, row_start, cursor, norm, n);
  k_scatter<<<(E + 255) / 256, 256, 0, stream>>>(srcp, dstp, cursor, csr, E);

  int gb128 = (n + 127) / 128;
  int gb64  = (n + 63) / 64;
  k_initM<<<dim3(gb128, 2), 512, 0, stream>>>(node, WT, bpre, bmrg, norm, merge, bufA, n);

  // iteration 1: prop A->B (pre-scaled rows), conv in-place B (writes scaled)
  k_prop<<<(n + 3) / 4, 256, 0, stream>>>(bufA, bufB, row_start, csr, norm, n);
  k_convM<0><<<gb64, 512, 0, stream>>>(bufB, Wcbf, bcv, merge, norm, nullptr, n);
  // iteration 2: prop B->A, conv fused with final mean -> out (f32)
  k_prop<<<(n + 3) / 4, 256, 0, stream>>>(bufB, bufA, row_start, csr, norm, n);
  k_convM<1><<<gb64, 512, 0, stream>>>(bufA, Wcbf, bcv, merge, norm, out, n);
}

// Round 8
// 215.416 us; speedup vs baseline: 4.3124x; 1.0796x over previous
//
#include <hip/hip_runtime.h>

typedef unsigned short u16;
typedef __attribute__((ext_vector_type(8))) short bf16x8;
typedef __attribute__((ext_vector_type(4))) float f32x4;

#define ICNST 128
#define C2 256   // OC*WIDTH

__device__ __forceinline__ float bf2f(u16 u){
  return __uint_as_float(((unsigned int)u) << 16);
}
__device__ __forceinline__ float2 bf2x2(unsigned int u){
  float2 r;
  r.x = __uint_as_float(u << 16);
  r.y = __uint_as_float(u & 0xffff0000u);
  return r;
}
__device__ __forceinline__ u16 f2bf(float f){
  unsigned int u = __float_as_uint(f);
  unsigned int r = (u + 0x7fffu + ((u >> 16) & 1u)) >> 16;
  return (u16)r;
}
__device__ __forceinline__ unsigned int pk2(float a, float b){
  return (unsigned int)f2bf(a) | ((unsigned int)f2bf(b) << 16);
}

// ---- degree count ----
__global__ void k_deg(const int* __restrict__ dst, int* __restrict__ deg, int E){
  int e = blockIdx.x * blockDim.x + threadIdx.x;
  if (e < E) atomicAdd(&deg[dst[e]], 1);
}

// ---- hierarchical scan: 1) per-block sums ----
__global__ __launch_bounds__(256) void k_scan1(const int* __restrict__ deg,
    int* __restrict__ bsum, int n){
  __shared__ int red[256];
  int t = threadIdx.x;
  int i = blockIdx.x * 256 + t;
  red[t] = (i < n) ? deg[i] : 0;
  __syncthreads();
  for (int off = 128; off > 0; off >>= 1){
    if (t < off) red[t] += red[t + off];
    __syncthreads();
  }
  if (t == 0) bsum[blockIdx.x] = red[0];
}

// ---- 2) single-block exclusive scan of block sums (nb <= 256) ----
__global__ __launch_bounds__(256) void k_scan2(int* __restrict__ bsum, int nb){
  __shared__ int s[256];
  int t = threadIdx.x;
  int v = (t < nb) ? bsum[t] : 0;
  s[t] = v;
  __syncthreads();
  for (int off = 1; off < 256; off <<= 1){
    int u = (t >= off) ? s[t - off] : 0;
    __syncthreads();
    s[t] += u;
    __syncthreads();
  }
  if (t < nb) bsum[t] = s[t] - v; // exclusive
}

// ---- 3) block-local exclusive scan + offset -> row_start, cursor, norm ----
__global__ __launch_bounds__(256) void k_scan3(const int* __restrict__ deg,
    const int* __restrict__ bsum, int* __restrict__ row_start,
    int* __restrict__ cursor, float* __restrict__ norm, int n){
  __shared__ int s[256];
  int t = threadIdx.x;
  int i = blockIdx.x * 256 + t;
  int v = (i < n) ? deg[i] : 0;
  s[t] = v;
  __syncthreads();
  for (int off = 1; off < 256; off <<= 1){
    int u = (t >= off) ? s[t - off] : 0;
    __syncthreads();
    s[t] += u;
    __syncthreads();
  }
  int ex = s[t] - v + bsum[blockIdx.x];
  if (i < n){
    row_start[i] = ex;
    cursor[i] = ex;
    norm[i] = (v > 0) ? rsqrtf((float)v) : 0.f;
    if (i == n - 1) row_start[n] = ex + v;
  }
}

// ---- scatter edges into CSR slots ----
__global__ void k_scatter(const int* __restrict__ src, const int* __restrict__ dstA,
    int* __restrict__ cursor, int* __restrict__ csr_src, int E){
  int e = blockIdx.x * blockDim.x + threadIdx.x;
  if (e < E){
    int d = dstA[e];
    int pos = atomicAdd(&cursor[d], 1);
    csr_src[pos] = src[e];
  }
}

// ---- convert weights to bf16: WT[j][k] = (j<256?Wpre:Wmrg)[k][j'], Wc_bf = Wcv ----
__global__ void k_cvtW(const float* __restrict__ Wpre, const float* __restrict__ Wmrg,
    const float* __restrict__ Wcv, u16* __restrict__ WT, u16* __restrict__ Wc){
  int idx = blockIdx.x * blockDim.x + threadIdx.x;
  if (idx < 65536){
    int j = idx & 511, k = idx >> 9;
    float v = (j < 256) ? Wpre[k * 256 + j] : Wmrg[k * 256 + (j - 256)];
    WT[j * 128 + k] = f2bf(v);
  } else if (idx < 65536 + 32768){
    int x = idx - 65536;
    Wc[x] = f2bf(Wcv[x]);
  }
}

// ---- init (MFMA, swapped-D): merge = X@Wm + bm; bufA = norm .* relu(X@Wp + bp + merge)
// grid ceil(n/64), 512 threads = 8 waves; wave w owns paired-cols [w*32, w*32+32).
// Node tile staged exactly ONCE per 64 rows (no y duplication).
__global__ __launch_bounds__(512) void k_initM(const float* __restrict__ node,
    const u16* __restrict__ WT, const float* __restrict__ bpre,
    const float* __restrict__ bmrg, const float* __restrict__ norm,
    u16* __restrict__ merge, u16* __restrict__ outA, int n){
  __shared__ u16 Al[64 * 128]; // bf16, XOR-swizzled, 16KB
  int t = threadIdx.x;
  int w = t >> 6, l = t & 63;
  int n0 = blockIdx.x * 64;
  int cb = w * 32;             // paired-col base for this wave (0..224)

  // stage A: 64 rows x 128 f32 -> bf16 swizzled LDS. thread: row=t>>3, 16 cols.
  {
    int row = t >> 3, c0 = (t & 7) * 16;
    const float* src = node + (size_t)(n0 + row) * ICNST + c0;
    bool ok = (n0 + row) < n;
    #pragma unroll
    for (int q = 0; q < 4; ++q){
      float4 v = ok ? *(const float4*)(src + q * 4) : float4{0.f, 0.f, 0.f, 0.f};
      int byte = (row * 256 + c0 * 2 + q * 8) ^ ((row & 7) << 4);
      unsigned int pv = pk2(v.x, v.y);
      unsigned int pw = pk2(v.z, v.w);
      uint2 pp; pp.x = pv; pp.y = pw;
      *(uint2*)((char*)Al + byte) = pp;
    }
  }
  __syncthreads();

  f32x4 acc[4][4] = {}; // [row frag][col frag: 0,1=pre 2,3=merge], D transposed
  int lk = (l >> 4) * 8;
  #pragma unroll
  for (int ks = 0; ks < 4; ++ks){
    bf16x8 bf[4];
    #pragma unroll
    for (int fc = 0; fc < 4; ++fc){
      int j = (fc < 2) ? (cb + fc * 16 + (l & 15))
                       : (256 + cb + (fc - 2) * 16 + (l & 15));
      bf[fc] = *(const bf16x8*)(WT + (size_t)j * 128 + ks * 32 + lk);
    }
    bf16x8 af[4];
    #pragma unroll
    for (int fr = 0; fr < 4; ++fr){
      int row = fr * 16 + (l & 15);
      int byte = (row * 256 + ks * 64 + (l >> 4) * 16) ^ ((l & 7) << 4);
      af[fr] = *(const bf16x8*)((const char*)Al + byte);
    }
    #pragma unroll
    for (int fr = 0; fr < 4; ++fr)
      #pragma unroll
      for (int fc = 0; fc < 4; ++fc)
        acc[fr][fc] = __builtin_amdgcn_mfma_f32_16x16x32_bf16(bf[fc], af[fr], acc[fr][fc], 0, 0, 0);
  }

  // epilogue: lane holds 4 consecutive j's (reg r -> j0+r)
  #pragma unroll
  for (int fr = 0; fr < 4; ++fr){
    int row = n0 + fr * 16 + (l & 15);
    bool ok = row < n;
    float nr = ok ? norm[row] : 0.f;
    #pragma unroll
    for (int fcp = 0; fcp < 2; ++fcp){
      int j0 = cb + fcp * 16 + (l >> 4) * 4;
      float4 bP = *(const float4*)(bpre + j0);
      float4 bM = *(const float4*)(bmrg + j0);
      f32x4 aP = acc[fr][fcp], aM = acc[fr][fcp + 2];
      float bPe[4] = {bP.x, bP.y, bP.z, bP.w};
      float bMe[4] = {bM.x, bM.y, bM.z, bM.w};
      ushort4 mgv, outv;
      u16* mgp = (u16*)&mgv; u16* otp = (u16*)&outv;
      #pragma unroll
      for (int r = 0; r < 4; ++r){
        float mg = aM[r] + bMe[r];
        float o  = aP[r] + bPe[r] + mg;
        o = (o > 0.f) ? o : 0.f;
        mgp[r] = f2bf(mg);
        otp[r] = f2bf(nr * o);
      }
      if (ok){
        *(ushort4*)(merge + (size_t)row * C2 + j0) = mgv;
        *(ushort4*)(outA  + (size_t)row * C2 + j0) = outv;
      }
    }
  }
}

// ---- conv (MFMA, swapped-D), in place. FINAL=0: buf = norm .* relu(conv+bc+merge)
//      FINAL=1: out[row][j/2] = pair-mean of relu(conv+bc+merge), f32 ----
template<int FINAL>
__global__ __launch_bounds__(512) void k_convM(u16* __restrict__ buf,
    const u16* __restrict__ Wc, const float* __restrict__ bc,
    const u16* __restrict__ merge, const float* __restrict__ norm,
    float* __restrict__ out, int n){
  __shared__ u16 Al[64 * 256]; // bf16, XOR-swizzled, 32KB
  int t = threadIdx.x;
  int w = t >> 6, l = t & 63;
  int n0 = blockIdx.x * 64;
  int wh = w >> 2;              // which 128-col half (selects A cols + W block)

  // stage A: 64 rows x 256 bf16. thread: row=t>>3, 32 cols.
  {
    int row = t >> 3, c0 = (t & 7) * 32;
    const u16* src = buf + (size_t)(n0 + row) * C2 + c0;
    bool ok = (n0 + row) < n;
    #pragma unroll
    for (int q = 0; q < 4; ++q){
      uint4 v = ok ? *(const uint4*)(src + q * 8) : uint4{0u, 0u, 0u, 0u};
      int byte = (row * 512 + c0 * 2 + q * 16) ^ ((row & 7) << 4);
      *(uint4*)((char*)Al + byte) = v;
    }
  }
  __syncthreads();

  f32x4 acc[4][2] = {}; // D transposed: reg r -> output col j0+r
  int lk = (l >> 4) * 8;
  #pragma unroll
  for (int ks = 0; ks < 4; ++ks){
    bf16x8 bf[2];
    #pragma unroll
    for (int fc = 0; fc < 2; ++fc){
      int rw = w * 32 + fc * 16 + (l & 15);   // = wh*128 + col
      bf[fc] = *(const bf16x8*)(Wc + (size_t)rw * 128 + ks * 32 + lk);
    }
    bf16x8 af[4];
    #pragma unroll
    for (int fr = 0; fr < 4; ++fr){
      int row = fr * 16 + (l & 15);
      int byte = (row * 512 + wh * 256 + ks * 64 + (l >> 4) * 16) ^ ((l & 7) << 4);
      af[fr] = *(const bf16x8*)((const char*)Al + byte);
    }
    #pragma unroll
    for (int fr = 0; fr < 4; ++fr)
      #pragma unroll
      for (int fc = 0; fc < 2; ++fc)
        acc[fr][fc] = __builtin_amdgcn_mfma_f32_16x16x32_bf16(bf[fc], af[fr], acc[fr][fc], 0, 0, 0);
  }

  #pragma unroll
  for (int fr = 0; fr < 4; ++fr){
    int row = n0 + fr * 16 + (l & 15);
    bool ok = row < n;
    float nr = 0.f;
    if (!FINAL) nr = ok ? norm[row] : 0.f;
    #pragma unroll
    for (int fc = 0; fc < 2; ++fc){
      int j0 = w * 32 + fc * 16 + (l >> 4) * 4;
      float4 bC = *(const float4*)(bc + j0);
      float bCe[4] = {bC.x, bC.y, bC.z, bC.w};
      ushort4 mg4 = ok ? *(const ushort4*)(merge + (size_t)row * C2 + j0)
                       : ushort4{0, 0, 0, 0};
      const u16* mge = (const u16*)&mg4;
      float v[4];
      #pragma unroll
      for (int r = 0; r < 4; ++r){
        float o = acc[fr][fc][r] + bCe[r] + bf2f(mge[r]);
        v[r] = (o > 0.f) ? o : 0.f;
      }
      if (!FINAL){
        ushort4 ov;
        u16* ovp = (u16*)&ov;
        #pragma unroll
        for (int r = 0; r < 4; ++r) ovp[r] = f2bf(nr * v[r]);
        if (ok) *(ushort4*)(buf + (size_t)row * C2 + j0) = ov;
      } else {
        float2 om;
        om.x = 0.5f * (v[0] + v[1]);
        om.y = 0.5f * (v[2] + v[3]);
        if (ok) *(float2*)(out + (size_t)row * 128 + (j0 >> 1)) = om;
      }
    }
  }
}

// ---- propagation: B[d] = norm[d] * sum_{e in in(d)} A[s]  (A pre-scaled) ----
__global__ __launch_bounds__(256) void k_prop(const u16* __restrict__ A, u16* __restrict__ B,
    const int* __restrict__ row_start, const int* __restrict__ csr,
    const float* __restrict__ norm, int n){
  int gw = (blockIdx.x * blockDim.x + threadIdx.x) >> 6;
  int lane = threadIdx.x & 63;
  if (gw >= n) return;
  int b = row_start[gw], e = row_start[gw + 1];
  float a0 = 0.f, a1 = 0.f, a2 = 0.f, a3 = 0.f;
  int j = b;
  for (; j + 4 <= e; j += 4){
    int i0 = csr[j], i1 = csr[j + 1], i2 = csr[j + 2], i3 = csr[j + 3];
    uint2 r0 = *(const uint2*)(A + (size_t)i0 * C2 + lane * 4);
    uint2 r1 = *(const uint2*)(A + (size_t)i1 * C2 + lane * 4);
    uint2 r2 = *(const uint2*)(A + (size_t)i2 * C2 + lane * 4);
    uint2 r3 = *(const uint2*)(A + (size_t)i3 * C2 + lane * 4);
    float2 p;
    p = bf2x2(r0.x); a0 += p.x; a1 += p.y; p = bf2x2(r0.y); a2 += p.x; a3 += p.y;
    p = bf2x2(r1.x); a0 += p.x; a1 += p.y; p = bf2x2(r1.y); a2 += p.x; a3 += p.y;
    p = bf2x2(r2.x); a0 += p.x; a1 += p.y; p = bf2x2(r2.y); a2 += p.x; a3 += p.y;
    p = bf2x2(r3.x); a0 += p.x; a1 += p.y; p = bf2x2(r3.y); a2 += p.x; a3 += p.y;
  }
  for (; j < e; ++j){
    int i0 = csr[j];
    uint2 r0 = *(const uint2*)(A + (size_t)i0 * C2 + lane * 4);
    float2 p;
    p = bf2x2(r0.x); a0 += p.x; a1 += p.y; p = bf2x2(r0.y); a2 += p.x; a3 += p.y;
  }
  float nd = norm[gw];
  ushort4 ov;
  ov.x = f2bf(nd * a0); ov.y = f2bf(nd * a1);
  ov.z = f2bf(nd * a2); ov.w = f2bf(nd * a3);
  *(ushort4*)(B + (size_t)gw * C2 + lane * 4) = ov;
}

extern "C" void kernel_launch(void* const* d_in, const int* in_sizes, int n_in,
                              void* d_out, int out_size, void* d_ws, size_t ws_size,
                              hipStream_t stream){
  const float* node = (const float*)d_in[0];
  const int*   eidx = (const int*)d_in[1];
  const float* Wpre = (const float*)d_in[2];
  const float* bpre = (const float*)d_in[3];
  const float* Wmrg = (const float*)d_in[4];
  const float* bmrg = (const float*)d_in[5];
  const float* Wcv  = (const float*)d_in[6];
  const float* bcv  = (const float*)d_in[7];
  float* out = (float*)d_out;

  const int n = in_sizes[0] / ICNST;
  const int E = in_sizes[1] / 2;
  const int* srcp = eidx;
  const int* dstp = eidx + E;

  char* ws = (char*)d_ws;
  size_t off = 0;
  auto alloc = [&](size_t bytes) -> char* {
    char* p = ws + off;
    off += bytes;
    off = (off + 255) & ~(size_t)255;
    return p;
  };
  int*   deg       = (int*)  alloc((size_t)n * 4);
  float* norm      = (float*)alloc((size_t)n * 4);
  int*   row_start = (int*)  alloc((size_t)(n + 1) * 4);
  int*   cursor    = (int*)  alloc((size_t)n * 4);
  int*   csr       = (int*)  alloc((size_t)E * 4);
  u16*   merge     = (u16*)  alloc((size_t)n * C2 * 2);
  u16*   bufA      = (u16*)  alloc((size_t)n * C2 * 2);
  u16*   bufB      = (u16*)  alloc((size_t)n * C2 * 2);
  u16*   WT        = (u16*)  alloc((size_t)512 * 128 * 2);
  u16*   Wcbf      = (u16*)  alloc((size_t)2 * 128 * 128 * 2);
  int*   bsum      = (int*)  alloc((size_t)256 * 4);
  (void)ws_size; (void)n_in; (void)out_size;

  const int nb = (n + 255) / 256;

  hipMemsetAsync(deg, 0, (size_t)n * 4, stream);
  k_cvtW<<<384, 256, 0, stream>>>(Wpre, Wmrg, Wcv, WT, Wcbf);
  k_deg<<<(E + 255) / 256, 256, 0, stream>>>(dstp, deg, E);
  k_scan1<<<nb, 256, 0, stream>>>(deg, bsum, n);
  k_scan2<<<1, 256, 0, stream>>>(bsum, nb);
  k_scan3<<<nb, 256, 0, stream>>>(deg, bsum, row_start, cursor, norm, n);
  k_scatter<<<(E + 255) / 256, 256, 0, stream>>>(srcp, dstp, cursor, csr, E);

  int gb64 = (n + 63) / 64;
  k_initM<<<gb64, 512, 0, stream>>>(node, WT, bpre, bmrg, norm, merge, bufA, n);

  // iteration 1: prop A->B (pre-scaled rows), conv in-place B (writes scaled)
  k_prop<<<(n + 3) / 4, 256, 0, stream>>>(bufA, bufB, row_start, csr, norm, n);
  k_convM<0><<<gb64, 512, 0, stream>>>(bufB, Wcbf, bcv, merge, norm, nullptr, n);
  // iteration 2: prop B->A, conv fused with final mean -> out (f32)
  k_prop<<<(n + 3) / 4, 256, 0, stream>>>(bufB, bufA, row_start, csr, norm, n);
  k_convM<1><<<gb64, 512, 0, stream>>>(bufA, Wcbf, bcv, merge, norm, out, n);
}

// Round 10
// 214.899 us; speedup vs baseline: 4.3227x; 1.0024x over previous
//
#include <hip/hip_runtime.h>

typedef unsigned short u16;
typedef __attribute__((ext_vector_type(8))) short bf16x8;
typedef __attribute__((ext_vector_type(4))) float f32x4;

#define ICNST 128
#define C2 256   // OC*WIDTH

__device__ __forceinline__ float bf2f(u16 u){
  return __uint_as_float(((unsigned int)u) << 16);
}
__device__ __forceinline__ float2 bf2x2(unsigned int u){
  float2 r;
  r.x = __uint_as_float(u << 16);
  r.y = __uint_as_float(u & 0xffff0000u);
  return r;
}
__device__ __forceinline__ u16 f2bf(float f){
  unsigned int u = __float_as_uint(f);
  unsigned int r = (u + 0x7fffu + ((u >> 16) & 1u)) >> 16;
  return (u16)r;
}
__device__ __forceinline__ unsigned int pk2(float a, float b){
  return (unsigned int)f2bf(a) | ((unsigned int)f2bf(b) << 16);
}

// ---- fused: weight bf16 conversion (blocks 0..383) + degree count ----
__global__ __launch_bounds__(256) void k_pre(const int* __restrict__ dst,
    int* __restrict__ deg, const float* __restrict__ Wpre,
    const float* __restrict__ Wmrg, const float* __restrict__ Wcv,
    u16* __restrict__ WT, u16* __restrict__ Wc, int E){
  int bid = blockIdx.x;
  if (bid < 384){
    int idx = bid * 256 + threadIdx.x;
    if (idx < 65536){
      int j = idx & 511, k = idx >> 9;
      float v = (j < 256) ? Wpre[k * 256 + j] : Wmrg[k * 256 + (j - 256)];
      WT[j * 128 + k] = f2bf(v);
    } else if (idx < 65536 + 32768){
      int x = idx - 65536;
      Wc[x] = f2bf(Wcv[x]);
    }
  } else {
    int e = (bid - 384) * 256 + threadIdx.x;
    if (e < E) atomicAdd(&deg[dst[e]], 1);
  }
}

// ---- hierarchical scan: 1) per-block sums ----
__global__ __launch_bounds__(256) void k_scan1(const int* __restrict__ deg,
    int* __restrict__ bsum, int n){
  __shared__ int red[256];
  int t = threadIdx.x;
  int i = blockIdx.x * 256 + t;
  red[t] = (i < n) ? deg[i] : 0;
  __syncthreads();
  for (int off = 128; off > 0; off >>= 1){
    if (t < off) red[t] += red[t + off];
    __syncthreads();
  }
  if (t == 0) bsum[blockIdx.x] = red[0];
}

// ---- 2) single-block exclusive scan of block sums (nb <= 256) ----
__global__ __launch_bounds__(256) void k_scan2(int* __restrict__ bsum, int nb){
  __shared__ int s[256];
  int t = threadIdx.x;
  int v = (t < nb) ? bsum[t] : 0;
  s[t] = v;
  __syncthreads();
  for (int off = 1; off < 256; off <<= 1){
    int u = (t >= off) ? s[t - off] : 0;
    __syncthreads();
    s[t] += u;
    __syncthreads();
  }
  if (t < nb) bsum[t] = s[t] - v; // exclusive
}

// ---- 3) block-local exclusive scan + offset -> row_start, cursor, norm ----
__global__ __launch_bounds__(256) void k_scan3(const int* __restrict__ deg,
    const int* __restrict__ bsum, int* __restrict__ row_start,
    int* __restrict__ cursor, float* __restrict__ norm, int n){
  __shared__ int s[256];
  int t = threadIdx.x;
  int i = blockIdx.x * 256 + t;
  int v = (i < n) ? deg[i] : 0;
  s[t] = v;
  __syncthreads();
  for (int off = 1; off < 256; off <<= 1){
    int u = (t >= off) ? s[t - off] : 0;
    __syncthreads();
    s[t] += u;
    __syncthreads();
  }
  int ex = s[t] - v + bsum[blockIdx.x];
  if (i < n){
    row_start[i] = ex;
    cursor[i] = ex;
    norm[i] = (v > 0) ? rsqrtf((float)v) : 0.f;
    if (i == n - 1) row_start[n] = ex + v;
  }
}

// ---- scatter edges into CSR slots ----
__global__ void k_scatter(const int* __restrict__ src, const int* __restrict__ dstA,
    int* __restrict__ cursor, int* __restrict__ csr_src, int E){
  int e = blockIdx.x * blockDim.x + threadIdx.x;
  if (e < E){
    int d = dstA[e];
    int pos = atomicAdd(&cursor[d], 1);
    csr_src[pos] = src[e];
  }
}

// ---- init (MFMA, swapped-D, B-hoisted): merge = X@Wm + bm; bufA = norm.*relu(X@Wp+bp+merge)
// grid ceil(n/64), 512 threads = 8 waves; wave w owns paired-cols [w*32, w*32+32).
__global__ __launch_bounds__(512) void k_initM(const float* __restrict__ node,
    const u16* __restrict__ WT, const float* __restrict__ bpre,
    const float* __restrict__ bmrg, const float* __restrict__ norm,
    u16* __restrict__ merge, u16* __restrict__ outA, int n){
  __shared__ u16 Al[64 * 128]; // bf16, XOR-swizzled, 16KB
  int t = threadIdx.x;
  int w = t >> 6, l = t & 63;
  int n0 = blockIdx.x * 64;
  int cb = w * 32;             // paired-col base for this wave
  int lk = (l >> 4) * 8;

  // hoist ALL B-fragments to registers (static indices -> VGPRs)
  bf16x8 breg[4][4];
  #pragma unroll
  for (int ks = 0; ks < 4; ++ks)
    #pragma unroll
    for (int fc = 0; fc < 4; ++fc){
      int j = (fc < 2) ? (cb + fc * 16 + (l & 15))
                       : (256 + cb + (fc - 2) * 16 + (l & 15));
      breg[ks][fc] = *(const bf16x8*)(WT + (size_t)j * 128 + ks * 32 + lk);
    }
  // prefetch epilogue operands (hide under K-loop)
  float nr4[4];
  #pragma unroll
  for (int fr = 0; fr < 4; ++fr){
    int row = n0 + fr * 16 + (l & 15);
    nr4[fr] = (row < n) ? norm[row] : 0.f;
  }
  float4 bPr[2], bMr[2];
  #pragma unroll
  for (int fcp = 0; fcp < 2; ++fcp){
    int j0 = cb + fcp * 16 + (l >> 4) * 4;
    bPr[fcp] = *(const float4*)(bpre + j0);
    bMr[fcp] = *(const float4*)(bmrg + j0);
  }

  // stage A: 64 rows x 128 f32 -> bf16 swizzled LDS. thread: row=t>>3, 16 cols.
  {
    int row = t >> 3, c0 = (t & 7) * 16;
    const float* src = node + (size_t)(n0 + row) * ICNST + c0;
    bool ok = (n0 + row) < n;
    #pragma unroll
    for (int q = 0; q < 4; ++q){
      float4 v = ok ? *(const float4*)(src + q * 4) : float4{0.f, 0.f, 0.f, 0.f};
      int byte = (row * 256 + c0 * 2 + q * 8) ^ ((row & 7) << 4);
      uint2 pp; pp.x = pk2(v.x, v.y); pp.y = pk2(v.z, v.w);
      *(uint2*)((char*)Al + byte) = pp;
    }
  }
  __syncthreads();

  f32x4 acc[4][4] = {}; // [row frag][col frag: 0,1=pre 2,3=merge], D transposed
  #pragma unroll
  for (int ks = 0; ks < 4; ++ks){
    bf16x8 af[4];
    #pragma unroll
    for (int fr = 0; fr < 4; ++fr){
      int row = fr * 16 + (l & 15);
      int byte = (row * 256 + ks * 64 + (l >> 4) * 16) ^ ((l & 7) << 4);
      af[fr] = *(const bf16x8*)((const char*)Al + byte);
    }
    #pragma unroll
    for (int fr = 0; fr < 4; ++fr)
      #pragma unroll
      for (int fc = 0; fc < 4; ++fc)
        acc[fr][fc] = __builtin_amdgcn_mfma_f32_16x16x32_bf16(breg[ks][fc], af[fr], acc[fr][fc], 0, 0, 0);
  }

  // epilogue: lane holds 4 consecutive j's (reg r -> j0+r)
  #pragma unroll
  for (int fr = 0; fr < 4; ++fr){
    int row = n0 + fr * 16 + (l & 15);
    bool ok = row < n;
    float nr = nr4[fr];
    #pragma unroll
    for (int fcp = 0; fcp < 2; ++fcp){
      int j0 = cb + fcp * 16 + (l >> 4) * 4;
      f32x4 aP = acc[fr][fcp], aM = acc[fr][fcp + 2];
      float bPe[4] = {bPr[fcp].x, bPr[fcp].y, bPr[fcp].z, bPr[fcp].w};
      float bMe[4] = {bMr[fcp].x, bMr[fcp].y, bMr[fcp].z, bMr[fcp].w};
      ushort4 mgv, outv;
      u16* mgp = (u16*)&mgv; u16* otp = (u16*)&outv;
      #pragma unroll
      for (int r = 0; r < 4; ++r){
        float mg = aM[r] + bMe[r];
        float o  = aP[r] + bPe[r] + mg;
        o = (o > 0.f) ? o : 0.f;
        mgp[r] = f2bf(mg);
        otp[r] = f2bf(nr * o);
      }
      if (ok){
        *(ushort4*)(merge + (size_t)row * C2 + j0) = mgv;
        *(ushort4*)(outA  + (size_t)row * C2 + j0) = outv;
      }
    }
  }
}

// ---- conv (MFMA, swapped-D, B-hoisted), in place ----
template<int FINAL>
__global__ __launch_bounds__(512) void k_convM(u16* __restrict__ buf,
    const u16* __restrict__ Wc, const float* __restrict__ bc,
    const u16* __restrict__ merge, const float* __restrict__ norm,
    float* __restrict__ out, int n){
  __shared__ u16 Al[64 * 256]; // bf16, XOR-swizzled, 32KB
  int t = threadIdx.x;
  int w = t >> 6, l = t & 63;
  int n0 = blockIdx.x * 64;
  int wh = w >> 2;              // which 128-col half (selects A cols + W block)
  int lk = (l >> 4) * 8;

  // hoist B-fragments
  bf16x8 breg[4][2];
  #pragma unroll
  for (int ks = 0; ks < 4; ++ks)
    #pragma unroll
    for (int fc = 0; fc < 2; ++fc){
      int rw = w * 32 + fc * 16 + (l & 15);
      breg[ks][fc] = *(const bf16x8*)(Wc + (size_t)rw * 128 + ks * 32 + lk);
    }
  // prefetch epilogue operands
  float nr4[4];
  #pragma unroll
  for (int fr = 0; fr < 4; ++fr){
    int row = n0 + fr * 16 + (l & 15);
    nr4[fr] = (row < n) ? norm[row] : 0.f;
  }
  float4 bCr[2];
  ushort4 mgr[4][2];
  #pragma unroll
  for (int fc = 0; fc < 2; ++fc)
    bCr[fc] = *(const float4*)(bc + w * 32 + fc * 16 + (l >> 4) * 4);
  #pragma unroll
  for (int fr = 0; fr < 4; ++fr){
    int row = n0 + fr * 16 + (l & 15);
    bool ok = row < n;
    #pragma unroll
    for (int fc = 0; fc < 2; ++fc){
      int j0 = w * 32 + fc * 16 + (l >> 4) * 4;
      mgr[fr][fc] = ok ? *(const ushort4*)(merge + (size_t)row * C2 + j0)
                       : ushort4{0, 0, 0, 0};
    }
  }

  // stage A: 64 rows x 256 bf16. thread: row=t>>3, 32 cols.
  {
    int row = t >> 3, c0 = (t & 7) * 32;
    const u16* src = buf + (size_t)(n0 + row) * C2 + c0;
    bool ok = (n0 + row) < n;
    #pragma unroll
    for (int q = 0; q < 4; ++q){
      uint4 v = ok ? *(const uint4*)(src + q * 8) : uint4{0u, 0u, 0u, 0u};
      int byte = (row * 512 + c0 * 2 + q * 16) ^ ((row & 7) << 4);
      *(uint4*)((char*)Al + byte) = v;
    }
  }
  __syncthreads();

  f32x4 acc[4][2] = {}; // D transposed: reg r -> output col j0+r
  #pragma unroll
  for (int ks = 0; ks < 4; ++ks){
    bf16x8 af[4];
    #pragma unroll
    for (int fr = 0; fr < 4; ++fr){
      int row = fr * 16 + (l & 15);
      int byte = (row * 512 + wh * 256 + ks * 64 + (l >> 4) * 16) ^ ((l & 7) << 4);
      af[fr] = *(const bf16x8*)((const char*)Al + byte);
    }
    #pragma unroll
    for (int fr = 0; fr < 4; ++fr)
      #pragma unroll
      for (int fc = 0; fc < 2; ++fc)
        acc[fr][fc] = __builtin_amdgcn_mfma_f32_16x16x32_bf16(breg[ks][fc], af[fr], acc[fr][fc], 0, 0, 0);
  }

  #pragma unroll
  for (int fr = 0; fr < 4; ++fr){
    int row = n0 + fr * 16 + (l & 15);
    bool ok = row < n;
    float nr = nr4[fr];
    #pragma unroll
    for (int fc = 0; fc < 2; ++fc){
      int j0 = w * 32 + fc * 16 + (l >> 4) * 4;
      float bCe[4] = {bCr[fc].x, bCr[fc].y, bCr[fc].z, bCr[fc].w};
      const u16* mge = (const u16*)&mgr[fr][fc];
      float v[4];
      #pragma unroll
      for (int r = 0; r < 4; ++r){
        float o = acc[fr][fc][r] + bCe[r] + bf2f(mge[r]);
        v[r] = (o > 0.f) ? o : 0.f;
      }
      if (!FINAL){
        ushort4 ov;
        u16* ovp = (u16*)&ov;
        #pragma unroll
        for (int r = 0; r < 4; ++r) ovp[r] = f2bf(nr * v[r]);
        if (ok) *(ushort4*)(buf + (size_t)row * C2 + j0) = ov;
      } else {
        float2 om;
        om.x = 0.5f * (v[0] + v[1]);
        om.y = 0.5f * (v[2] + v[3]);
        if (ok) *(float2*)(out + (size_t)row * 128 + (j0 >> 1)) = om;
      }
    }
  }
}

// ---- propagation: 2 dst rows per wave, 32 lanes x uint4 per row ----
// B[d] = norm[d] * sum_{e in in(d)} A[s]  (A pre-scaled by norm[s])
__global__ __launch_bounds__(256) void k_prop(const u16* __restrict__ A, u16* __restrict__ B,
    const int* __restrict__ row_start, const int* __restrict__ csr,
    const float* __restrict__ norm, int n){
  int wid = (blockIdx.x * 256 + threadIdx.x) >> 6;
  int lane = threadIdx.x & 63;
  int half = lane >> 5, c = lane & 31;
  int gw = wid * 2 + half;
  if (gw >= n) return;
  int b = row_start[gw], e = row_start[gw + 1];
  float a0 = 0.f, a1 = 0.f, a2 = 0.f, a3 = 0.f, a4 = 0.f, a5 = 0.f, a6 = 0.f, a7 = 0.f;
  const u16* Ac = A + (size_t)c * 8;
  int j = b;
  for (; j + 4 <= e; j += 4){
    int s0 = csr[j], s1 = csr[j + 1], s2 = csr[j + 2], s3 = csr[j + 3];
    uint4 r0 = *(const uint4*)(Ac + (size_t)s0 * C2);
    uint4 r1 = *(const uint4*)(Ac + (size_t)s1 * C2);
    uint4 r2 = *(const uint4*)(Ac + (size_t)s2 * C2);
    uint4 r3 = *(const uint4*)(Ac + (size_t)s3 * C2);
    float2 p;
    p = bf2x2(r0.x); a0 += p.x; a1 += p.y; p = bf2x2(r0.y); a2 += p.x; a3 += p.y;
    p = bf2x2(r0.z); a4 += p.x; a5 += p.y; p = bf2x2(r0.w); a6 += p.x; a7 += p.y;
    p = bf2x2(r1.x); a0 += p.x; a1 += p.y; p = bf2x2(r1.y); a2 += p.x; a3 += p.y;
    p = bf2x2(r1.z); a4 += p.x; a5 += p.y; p = bf2x2(r1.w); a6 += p.x; a7 += p.y;
    p = bf2x2(r2.x); a0 += p.x; a1 += p.y; p = bf2x2(r2.y); a2 += p.x; a3 += p.y;
    p = bf2x2(r2.z); a4 += p.x; a5 += p.y; p = bf2x2(r2.w); a6 += p.x; a7 += p.y;
    p = bf2x2(r3.x); a0 += p.x; a1 += p.y; p = bf2x2(r3.y); a2 += p.x; a3 += p.y;
    p = bf2x2(r3.z); a4 += p.x; a5 += p.y; p = bf2x2(r3.w); a6 += p.x; a7 += p.y;
  }
  for (; j < e; ++j){
    int s0 = csr[j];
    uint4 r0 = *(const uint4*)(Ac + (size_t)s0 * C2);
    float2 p;
    p = bf2x2(r0.x); a0 += p.x; a1 += p.y; p = bf2x2(r0.y); a2 += p.x; a3 += p.y;
    p = bf2x2(r0.z); a4 += p.x; a5 += p.y; p = bf2x2(r0.w); a6 += p.x; a7 += p.y;
  }
  float nd = norm[gw];
  uint4 ov;
  ov.x = pk2(nd * a0, nd * a1);
  ov.y = pk2(nd * a2, nd * a3);
  ov.z = pk2(nd * a4, nd * a5);
  ov.w = pk2(nd * a6, nd * a7);
  *(uint4*)(B + (size_t)gw * C2 + c * 8) = ov;
}

extern "C" void kernel_launch(void* const* d_in, const int* in_sizes, int n_in,
                              void* d_out, int out_size, void* d_ws, size_t ws_size,
                              hipStream_t stream){
  const float* node = (const float*)d_in[0];
  const int*   eidx = (const int*)d_in[1];
  const float* Wpre = (const float*)d_in[2];
  const float* bpre = (const float*)d_in[3];
  const float* Wmrg = (const float*)d_in[4];
  const float* bmrg = (const float*)d_in[5];
  const float* Wcv  = (const float*)d_in[6];
  const float* bcv  = (const float*)d_in[7];
  float* out = (float*)d_out;

  const int n = in_sizes[0] / ICNST;
  const int E = in_sizes[1] / 2;
  const int* srcp = eidx;
  const int* dstp = eidx + E;

  char* ws = (char*)d_ws;
  size_t off = 0;
  auto alloc = [&](size_t bytes) -> char* {
    char* p = ws + off;
    off += bytes;
    off = (off + 255) & ~(size_t)255;
    return p;
  };
  int*   deg       = (int*)  alloc((size_t)n * 4);
  float* norm      = (float*)alloc((size_t)n * 4);
  int*   row_start = (int*)  alloc((size_t)(n + 1) * 4);
  int*   cursor    = (int*)  alloc((size_t)n * 4);
  int*   csr       = (int*)  alloc((size_t)E * 4);
  u16*   merge     = (u16*)  alloc((size_t)n * C2 * 2);
  u16*   bufA      = (u16*)  alloc((size_t)n * C2 * 2);
  u16*   bufB      = (u16*)  alloc((size_t)n * C2 * 2);
  u16*   WT        = (u16*)  alloc((size_t)512 * 128 * 2);
  u16*   Wcbf      = (u16*)  alloc((size_t)2 * 128 * 128 * 2);
  int*   bsum      = (int*)  alloc((size_t)256 * 4);
  (void)ws_size; (void)n_in; (void)out_size;

  const int nb = (n + 255) / 256;

  hipMemsetAsync(deg, 0, (size_t)n * 4, stream);
  k_pre<<<384 + (E + 255) / 256, 256, 0, stream>>>(dstp, deg, Wpre, Wmrg, Wcv, WT, Wcbf, E);
  k_scan1<<<nb, 256, 0, stream>>>(deg, bsum, n);
  k_scan2<<<1, 256, 0, stream>>>(bsum, nb);
  k_scan3<<<nb, 256, 0, stream>>>(deg, bsum, row_start, cursor, norm, n);
  k_scatter<<<(E + 255) / 256, 256, 0, stream>>>(srcp, dstp, cursor, csr, E);

  int gb64 = (n + 63) / 64;
  k_initM<<<gb64, 512, 0, stream>>>(node, WT, bpre, bmrg, norm, merge, bufA, n);

  // iteration 1: prop A->B (pre-scaled rows), conv in-place B (writes scaled)
  k_prop<<<(n + 7) / 8, 256, 0, stream>>>(bufA, bufB, row_start, csr, norm, n);
  k_convM<0><<<gb64, 512, 0, stream>>>(bufB, Wcbf, bcv, merge, norm, nullptr, n);
  // iteration 2: prop B->A, conv fused with final mean -> out (f32)
  k_prop<<<(n + 7) / 8, 256, 0, stream>>>(bufB, bufA, row_start, csr, norm, n);
  k_convM<1><<<gb64, 512, 0, stream>>>(bufA, Wcbf, bcv, merge, norm, out, n);
}

// Round 11
// 210.290 us; speedup vs baseline: 4.4175x; 1.0219x over previous
//
#include <hip/hip_runtime.h>

typedef unsigned short u16;
typedef __attribute__((ext_vector_type(8))) short bf16x8;
typedef __attribute__((ext_vector_type(4))) float f32x4;

#define ICNST 128
#define C2 256   // OC*WIDTH

__device__ __forceinline__ float bf2f(u16 u){
  return __uint_as_float(((unsigned int)u) << 16);
}
__device__ __forceinline__ float2 bf2x2(unsigned int u){
  float2 r;
  r.x = __uint_as_float(u << 16);
  r.y = __uint_as_float(u & 0xffff0000u);
  return r;
}
__device__ __forceinline__ u16 f2bf(float f){
  unsigned int u = __float_as_uint(f);
  unsigned int r = (u + 0x7fffu + ((u >> 16) & 1u)) >> 16;
  return (u16)r;
}
__device__ __forceinline__ unsigned int pk2(float a, float b){
  return (unsigned int)f2bf(a) | ((unsigned int)f2bf(b) << 16);
}

// ---- fused: weight bf16 conversion (blocks 0..383) + degree count ----
__global__ __launch_bounds__(256) void k_pre(const int* __restrict__ dst,
    int* __restrict__ deg, const float* __restrict__ Wpre,
    const float* __restrict__ Wmrg, const float* __restrict__ Wcv,
    u16* __restrict__ WT, u16* __restrict__ Wc, int E){
  int bid = blockIdx.x;
  if (bid < 384){
    int idx = bid * 256 + threadIdx.x;
    if (idx < 65536){
      int j = idx & 511, k = idx >> 9;
      float v = (j < 256) ? Wpre[k * 256 + j] : Wmrg[k * 256 + (j - 256)];
      WT[j * 128 + k] = f2bf(v);
    } else if (idx < 65536 + 32768){
      int x = idx - 65536;
      Wc[x] = f2bf(Wcv[x]);
    }
  } else {
    int e = (bid - 384) * 256 + threadIdx.x;
    if (e < E) atomicAdd(&deg[dst[e]], 1);
  }
}

// ---- hierarchical scan: 1) per-block sums ----
__global__ __launch_bounds__(256) void k_scan1(const int* __restrict__ deg,
    int* __restrict__ bsum, int n){
  __shared__ int red[256];
  int t = threadIdx.x;
  int i = blockIdx.x * 256 + t;
  red[t] = (i < n) ? deg[i] : 0;
  __syncthreads();
  for (int off = 128; off > 0; off >>= 1){
    if (t < off) red[t] += red[t + off];
    __syncthreads();
  }
  if (t == 0) bsum[blockIdx.x] = red[0];
}

// ---- 2) single-block exclusive scan of block sums (nb <= 256) ----
__global__ __launch_bounds__(256) void k_scan2(int* __restrict__ bsum, int nb){
  __shared__ int s[256];
  int t = threadIdx.x;
  int v = (t < nb) ? bsum[t] : 0;
  s[t] = v;
  __syncthreads();
  for (int off = 1; off < 256; off <<= 1){
    int u = (t >= off) ? s[t - off] : 0;
    __syncthreads();
    s[t] += u;
    __syncthreads();
  }
  if (t < nb) bsum[t] = s[t] - v; // exclusive
}

// ---- 3) block-local exclusive scan + offset -> row_start, cursor, norm ----
__global__ __launch_bounds__(256) void k_scan3(const int* __restrict__ deg,
    const int* __restrict__ bsum, int* __restrict__ row_start,
    int* __restrict__ cursor, float* __restrict__ norm, int n){
  __shared__ int s[256];
  int t = threadIdx.x;
  int i = blockIdx.x * 256 + t;
  int v = (i < n) ? deg[i] : 0;
  s[t] = v;
  __syncthreads();
  for (int off = 1; off < 256; off <<= 1){
    int u = (t >= off) ? s[t - off] : 0;
    __syncthreads();
    s[t] += u;
    __syncthreads();
  }
  int ex = s[t] - v + bsum[blockIdx.x];
  if (i < n){
    row_start[i] = ex;
    cursor[i] = ex;
    norm[i] = (v > 0) ? rsqrtf((float)v) : 0.f;
    if (i == n - 1) row_start[n] = ex + v;
  }
}

// ---- scatter edges into CSR slots ----
__global__ void k_scatter(const int* __restrict__ src, const int* __restrict__ dstA,
    int* __restrict__ cursor, int* __restrict__ csr_src, int E){
  int e = blockIdx.x * blockDim.x + threadIdx.x;
  if (e < E){
    int d = dstA[e];
    int pos = atomicAdd(&cursor[d], 1);
    csr_src[pos] = src[e];
  }
}

// ---- init (MFMA, swapped-D, LDS-coalesced epilogue) ----
// merge = X@Wm + bm; bufA = norm .* relu(X@Wp + bp + merge)
// grid ceil(n/64), 512 threads = 8 waves; wave w owns paired-cols [w*32, w*32+32).
__global__ __launch_bounds__(512) void k_initM(const float* __restrict__ node,
    const u16* __restrict__ WT, const float* __restrict__ bpre,
    const float* __restrict__ bmrg, const float* __restrict__ norm,
    u16* __restrict__ merge, u16* __restrict__ outA, int n){
  __shared__ u16 Al[64 * 128];  // A tile, swizzled, 16KB
  __shared__ u16 Ep[64 * 256];  // epilogue tile (64 rows x 512B), swizzled, 32KB
  int t = threadIdx.x;
  int w = t >> 6, l = t & 63;
  int n0 = blockIdx.x * 64;
  int cb = w * 32;
  int lk = (l >> 4) * 8;

  // prefetch epilogue scalars
  float nr4[4];
  #pragma unroll
  for (int fr = 0; fr < 4; ++fr){
    int row = n0 + fr * 16 + (l & 15);
    nr4[fr] = (row < n) ? norm[row] : 0.f;
  }
  float4 bPr[2], bMr[2];
  #pragma unroll
  for (int fcp = 0; fcp < 2; ++fcp){
    int j0 = cb + fcp * 16 + (l >> 4) * 4;
    bPr[fcp] = *(const float4*)(bpre + j0);
    bMr[fcp] = *(const float4*)(bmrg + j0);
  }

  // stage A: 64 rows x 128 f32 -> bf16 swizzled LDS
  {
    int row = t >> 3, c0 = (t & 7) * 16;
    const float* src = node + (size_t)(n0 + row) * ICNST + c0;
    bool ok = (n0 + row) < n;
    #pragma unroll
    for (int q = 0; q < 4; ++q){
      float4 v = ok ? *(const float4*)(src + q * 4) : float4{0.f, 0.f, 0.f, 0.f};
      int byte = (row * 256 + c0 * 2 + q * 8) ^ ((row & 7) << 4);
      uint2 pp; pp.x = pk2(v.x, v.y); pp.y = pk2(v.z, v.w);
      *(uint2*)((char*)Al + byte) = pp;
    }
  }
  __syncthreads();

  f32x4 acc[4][4] = {}; // [row frag][col frag: 0,1=pre 2,3=merge], D transposed
  #pragma unroll
  for (int ks = 0; ks < 4; ++ks){
    bf16x8 bf[4];
    #pragma unroll
    for (int fc = 0; fc < 4; ++fc){
      int j = (fc < 2) ? (cb + fc * 16 + (l & 15))
                       : (256 + cb + (fc - 2) * 16 + (l & 15));
      bf[fc] = *(const bf16x8*)(WT + (size_t)j * 128 + ks * 32 + lk);
    }
    bf16x8 af[4];
    #pragma unroll
    for (int fr = 0; fr < 4; ++fr){
      int row = fr * 16 + (l & 15);
      int byte = (row * 256 + ks * 64 + (l >> 4) * 16) ^ ((l & 7) << 4);
      af[fr] = *(const bf16x8*)((const char*)Al + byte);
    }
    #pragma unroll
    for (int fr = 0; fr < 4; ++fr)
      #pragma unroll
      for (int fc = 0; fc < 4; ++fc)
        acc[fr][fc] = __builtin_amdgcn_mfma_f32_16x16x32_bf16(bf[fc], af[fr], acc[fr][fc], 0, 0, 0);
  }

  // compute merge + out values; keep out values in regs, write merge to Ep
  ushort4 outv[4][2];
  #pragma unroll
  for (int fr = 0; fr < 4; ++fr){
    int rl = fr * 16 + (l & 15);
    float nr = nr4[fr];
    #pragma unroll
    for (int fcp = 0; fcp < 2; ++fcp){
      int j0 = cb + fcp * 16 + (l >> 4) * 4;
      f32x4 aP = acc[fr][fcp], aM = acc[fr][fcp + 2];
      float bPe[4] = {bPr[fcp].x, bPr[fcp].y, bPr[fcp].z, bPr[fcp].w};
      float bMe[4] = {bMr[fcp].x, bMr[fcp].y, bMr[fcp].z, bMr[fcp].w};
      ushort4 mgv;
      u16* mgp = (u16*)&mgv; u16* otp = (u16*)&outv[fr][fcp];
      #pragma unroll
      for (int r = 0; r < 4; ++r){
        float mg = aM[r] + bMe[r];
        float o  = aP[r] + bPe[r] + mg;
        o = (o > 0.f) ? o : 0.f;
        mgp[r] = f2bf(mg);
        otp[r] = f2bf(nr * o);
      }
      int byte = (rl * 512 + j0 * 2) ^ ((rl & 7) << 4);
      *(ushort4*)((char*)Ep + byte) = mgv;
    }
  }
  __syncthreads();
  // coalesced store merge
  #pragma unroll
  for (int round = 0; round < 4; ++round){
    int idx = round * 512 + t;            // 16B chunk index
    int rl = idx >> 5, off = (idx & 31) * 16;
    int byte = (rl * 512 + off) ^ ((rl & 7) << 4);
    uint4 v = *(const uint4*)((const char*)Ep + byte);
    if (n0 + rl < n)
      *(uint4*)((char*)merge + (size_t)(n0 + rl) * 512 + off) = v;
  }
  __syncthreads();
  // write out tile to Ep
  #pragma unroll
  for (int fr = 0; fr < 4; ++fr){
    int rl = fr * 16 + (l & 15);
    #pragma unroll
    for (int fcp = 0; fcp < 2; ++fcp){
      int j0 = cb + fcp * 16 + (l >> 4) * 4;
      int byte = (rl * 512 + j0 * 2) ^ ((rl & 7) << 4);
      *(ushort4*)((char*)Ep + byte) = outv[fr][fcp];
    }
  }
  __syncthreads();
  // coalesced store outA
  #pragma unroll
  for (int round = 0; round < 4; ++round){
    int idx = round * 512 + t;
    int rl = idx >> 5, off = (idx & 31) * 16;
    int byte = (rl * 512 + off) ^ ((rl & 7) << 4);
    uint4 v = *(const uint4*)((const char*)Ep + byte);
    if (n0 + rl < n)
      *(uint4*)((char*)outA + (size_t)(n0 + rl) * 512 + off) = v;
  }
}

// ---- conv (MFMA, swapped-D, LDS-coalesced merge+epilogue), in place ----
// FINAL=0: buf = norm .* relu(conv+bc+merge); FINAL=1: out = pair-mean (f32)
template<int FINAL>
__global__ __launch_bounds__(512) void k_convM(u16* __restrict__ buf,
    const u16* __restrict__ Wc, const float* __restrict__ bc,
    const u16* __restrict__ merge, const float* __restrict__ norm,
    float* __restrict__ out, int n){
  __shared__ u16 Al[64 * 256];  // A tile, swizzled, 32KB
  __shared__ u16 Ep[64 * 256];  // merge-in / result-out tile (64 x 512B), 32KB
  int t = threadIdx.x;
  int w = t >> 6, l = t & 63;
  int n0 = blockIdx.x * 64;
  int wh = w >> 2;
  int lk = (l >> 4) * 8;

  float nr4[4];
  #pragma unroll
  for (int fr = 0; fr < 4; ++fr){
    int row = n0 + fr * 16 + (l & 15);
    nr4[fr] = (row < n) ? norm[row] : 0.f;
  }
  float4 bCr[2];
  #pragma unroll
  for (int fc = 0; fc < 2; ++fc)
    bCr[fc] = *(const float4*)(bc + w * 32 + fc * 16 + (l >> 4) * 4);

  // stage A (buf) and merge, both coalesced, swizzled LDS
  {
    int row = t >> 3, c0 = (t & 7) * 32;
    bool ok = (n0 + row) < n;
    const u16* srcA = buf   + (size_t)(n0 + row) * C2 + c0;
    const u16* srcM = merge + (size_t)(n0 + row) * C2 + c0;
    #pragma unroll
    for (int q = 0; q < 4; ++q){
      uint4 va = ok ? *(const uint4*)(srcA + q * 8) : uint4{0u, 0u, 0u, 0u};
      int byte = (row * 512 + c0 * 2 + q * 16) ^ ((row & 7) << 4);
      *(uint4*)((char*)Al + byte) = va;
      uint4 vm = ok ? *(const uint4*)(srcM + q * 8) : uint4{0u, 0u, 0u, 0u};
      *(uint4*)((char*)Ep + byte) = vm;
    }
  }
  __syncthreads();

  f32x4 acc[4][2] = {}; // D transposed: reg r -> output col j0+r
  #pragma unroll
  for (int ks = 0; ks < 4; ++ks){
    bf16x8 bf[2];
    #pragma unroll
    for (int fc = 0; fc < 2; ++fc){
      int rw = w * 32 + fc * 16 + (l & 15);
      bf[fc] = *(const bf16x8*)(Wc + (size_t)rw * 128 + ks * 32 + lk);
    }
    bf16x8 af[4];
    #pragma unroll
    for (int fr = 0; fr < 4; ++fr){
      int row = fr * 16 + (l & 15);
      int byte = (row * 512 + wh * 256 + ks * 64 + (l >> 4) * 16) ^ ((l & 7) << 4);
      af[fr] = *(const bf16x8*)((const char*)Al + byte);
    }
    #pragma unroll
    for (int fr = 0; fr < 4; ++fr)
      #pragma unroll
      for (int fc = 0; fc < 2; ++fc)
        acc[fr][fc] = __builtin_amdgcn_mfma_f32_16x16x32_bf16(bf[fc], af[fr], acc[fr][fc], 0, 0, 0);
  }

  // epilogue: read merge from Ep slot, write result (8B) to the SAME slot
  #pragma unroll
  for (int fr = 0; fr < 4; ++fr){
    int rl = fr * 16 + (l & 15);
    float nr = nr4[fr];
    #pragma unroll
    for (int fc = 0; fc < 2; ++fc){
      int j0 = w * 32 + fc * 16 + (l >> 4) * 4;
      int byte = (rl * 512 + j0 * 2) ^ ((rl & 7) << 4);
      ushort4 mg4 = *(const ushort4*)((const char*)Ep + byte);
      const u16* mge = (const u16*)&mg4;
      float bCe[4] = {bCr[fc].x, bCr[fc].y, bCr[fc].z, bCr[fc].w};
      float v[4];
      #pragma unroll
      for (int r = 0; r < 4; ++r){
        float o = acc[fr][fc][r] + bCe[r] + bf2f(mge[r]);
        v[r] = (o > 0.f) ? o : 0.f;
      }
      if (!FINAL){
        ushort4 ov;
        u16* ovp = (u16*)&ov;
        #pragma unroll
        for (int r = 0; r < 4; ++r) ovp[r] = f2bf(nr * v[r]);
        *(ushort4*)((char*)Ep + byte) = ov;
      } else {
        float2 om;
        om.x = 0.5f * (v[0] + v[1]);
        om.y = 0.5f * (v[2] + v[3]);
        *(float2*)((char*)Ep + byte) = om;   // same 8B slot: (j0>>1)*4 == j0*2
      }
    }
  }
  __syncthreads();
  // coalesced store: Ep rows (512B) -> buf rows (512B u16) or out rows (512B f32)
  char* dstBase = FINAL ? (char*)out : (char*)buf;
  #pragma unroll
  for (int round = 0; round < 4; ++round){
    int idx = round * 512 + t;
    int rl = idx >> 5, off = (idx & 31) * 16;
    int byte = (rl * 512 + off) ^ ((rl & 7) << 4);
    uint4 v = *(const uint4*)((const char*)Ep + byte);
    if (n0 + rl < n)
      *(uint4*)(dstBase + (size_t)(n0 + rl) * 512 + off) = v;
  }
}

// ---- propagation: 2 dst rows per wave, 32 lanes x uint4 per row ----
// B[d] = norm[d] * sum_{e in in(d)} A[s]  (A pre-scaled by norm[s])
__global__ __launch_bounds__(256) void k_prop(const u16* __restrict__ A, u16* __restrict__ B,
    const int* __restrict__ row_start, const int* __restrict__ csr,
    const float* __restrict__ norm, int n){
  int wid = (blockIdx.x * 256 + threadIdx.x) >> 6;
  int lane = threadIdx.x & 63;
  int half = lane >> 5, c = lane & 31;
  int gw = wid * 2 + half;
  if (gw >= n) return;
  int b = row_start[gw], e = row_start[gw + 1];
  float a0 = 0.f, a1 = 0.f, a2 = 0.f, a3 = 0.f, a4 = 0.f, a5 = 0.f, a6 = 0.f, a7 = 0.f;
  const u16* Ac = A + (size_t)c * 8;
  int j = b;
  for (; j + 4 <= e; j += 4){
    int s0 = csr[j], s1 = csr[j + 1], s2 = csr[j + 2], s3 = csr[j + 3];
    uint4 r0 = *(const uint4*)(Ac + (size_t)s0 * C2);
    uint4 r1 = *(const uint4*)(Ac + (size_t)s1 * C2);
    uint4 r2 = *(const uint4*)(Ac + (size_t)s2 * C2);
    uint4 r3 = *(const uint4*)(Ac + (size_t)s3 * C2);
    float2 p;
    p = bf2x2(r0.x); a0 += p.x; a1 += p.y; p = bf2x2(r0.y); a2 += p.x; a3 += p.y;
    p = bf2x2(r0.z); a4 += p.x; a5 += p.y; p = bf2x2(r0.w); a6 += p.x; a7 += p.y;
    p = bf2x2(r1.x); a0 += p.x; a1 += p.y; p = bf2x2(r1.y); a2 += p.x; a3 += p.y;
    p = bf2x2(r1.z); a4 += p.x; a5 += p.y; p = bf2x2(r1.w); a6 += p.x; a7 += p.y;
    p = bf2x2(r2.x); a0 += p.x; a1 += p.y; p = bf2x2(r2.y); a2 += p.x; a3 += p.y;
    p = bf2x2(r2.z); a4 += p.x; a5 += p.y; p = bf2x2(r2.w); a6 += p.x; a7 += p.y;
    p = bf2x2(r3.x); a0 += p.x; a1 += p.y; p = bf2x2(r3.y); a2 += p.x; a3 += p.y;
    p = bf2x2(r3.z); a4 += p.x; a5 += p.y; p = bf2x2(r3.w); a6 += p.x; a7 += p.y;
  }
  for (; j < e; ++j){
    int s0 = csr[j];
    uint4 r0 = *(const uint4*)(Ac + (size_t)s0 * C2);
    float2 p;
    p = bf2x2(r0.x); a0 += p.x; a1 += p.y; p = bf2x2(r0.y); a2 += p.x; a3 += p.y;
    p = bf2x2(r0.z); a4 += p.x; a5 += p.y; p = bf2x2(r0.w); a6 += p.x; a7 += p.y;
  }
  float nd = norm[gw];
  uint4 ov;
  ov.x = pk2(nd * a0, nd * a1);
  ov.y = pk2(nd * a2, nd * a3);
  ov.z = pk2(nd * a4, nd * a5);
  ov.w = pk2(nd * a6, nd * a7);
  *(uint4*)(B + (size_t)gw * C2 + c * 8) = ov;
}

extern "C" void kernel_launch(void* const* d_in, const int* in_sizes, int n_in,
                              void* d_out, int out_size, void* d_ws, size_t ws_size,
                              hipStream_t stream){
  const float* node = (const float*)d_in[0];
  const int*   eidx = (const int*)d_in[1];
  const float* Wpre = (const float*)d_in[2];
  const float* bpre = (const float*)d_in[3];
  const float* Wmrg = (const float*)d_in[4];
  const float* bmrg = (const float*)d_in[5];
  const float* Wcv  = (const float*)d_in[6];
  const float* bcv  = (const float*)d_in[7];
  float* out = (float*)d_out;

  const int n = in_sizes[0] / ICNST;
  const int E = in_sizes[1] / 2;
  const int* srcp = eidx;
  const int* dstp = eidx + E;

  char* ws = (char*)d_ws;
  size_t off = 0;
  auto alloc = [&](size_t bytes) -> char* {
    char* p = ws + off;
    off += bytes;
    off = (off + 255) & ~(size_t)255;
    return p;
  };
  int*   deg       = (int*)  alloc((size_t)n * 4);
  float* norm      = (float*)alloc((size_t)n * 4);
  int*   row_start = (int*)  alloc((size_t)(n + 1) * 4);
  int*   cursor    = (int*)  alloc((size_t)n * 4);
  int*   csr       = (int*)  alloc((size_t)E * 4);
  u16*   merge     = (u16*)  alloc((size_t)n * C2 * 2);
  u16*   bufA      = (u16*)  alloc((size_t)n * C2 * 2);
  u16*   bufB      = (u16*)  alloc((size_t)n * C2 * 2);
  u16*   WT        = (u16*)  alloc((size_t)512 * 128 * 2);
  u16*   Wcbf      = (u16*)  alloc((size_t)2 * 128 * 128 * 2);
  int*   bsum      = (int*)  alloc((size_t)256 * 4);
  (void)ws_size; (void)n_in; (void)out_size;

  const int nb = (n + 255) / 256;

  hipMemsetAsync(deg, 0, (size_t)n * 4, stream);
  k_pre<<<384 + (E + 255) / 256, 256, 0, stream>>>(dstp, deg, Wpre, Wmrg, Wcv, WT, Wcbf, E);
  k_scan1<<<nb, 256, 0, stream>>>(deg, bsum, n);
  k_scan2<<<1, 256, 0, stream>>>(bsum, nb);
  k_scan3<<<nb, 256, 0, stream>>>(deg, bsum, row_start, cursor, norm, n);
  k_scatter<<<(E + 255) / 256, 256, 0, stream>>>(srcp, dstp, cursor, csr, E);

  int gb64 = (n + 63) / 64;
  k_initM<<<gb64, 512, 0, stream>>>(node, WT, bpre, bmrg, norm, merge, bufA, n);

  // iteration 1: prop A->B (pre-scaled rows), conv in-place B (writes scaled)
  k_prop<<<(n + 7) / 8, 256, 0, stream>>>(bufA, bufB, row_start, csr, norm, n);
  k_convM<0><<<gb64, 512, 0, stream>>>(bufB, Wcbf, bcv, merge, norm, nullptr, n);
  // iteration 2: prop B->A, conv fused with final mean -> out (f32)
  k_prop<<<(n + 7) / 8, 256, 0, stream>>>(bufB, bufA, row_start, csr, norm, n);
  k_convM<1><<<gb64, 512, 0, stream>>>(bufA, Wcbf, bcv, merge, norm, out, n);
}

// Round 12
// 209.064 us; speedup vs baseline: 4.4434x; 1.0059x over previous
//
#include <hip/hip_runtime.h>

typedef unsigned short u16;
typedef __attribute__((ext_vector_type(8))) short bf16x8;
typedef __attribute__((ext_vector_type(4))) float f32x4;

#define ICNST 128
#define C2 256   // OC*WIDTH

__device__ __forceinline__ float bf2f(u16 u){
  return __uint_as_float(((unsigned int)u) << 16);
}
__device__ __forceinline__ float2 bf2x2(unsigned int u){
  float2 r;
  r.x = __uint_as_float(u << 16);
  r.y = __uint_as_float(u & 0xffff0000u);
  return r;
}
__device__ __forceinline__ u16 f2bf(float f){
  unsigned int u = __float_as_uint(f);
  unsigned int r = (u + 0x7fffu + ((u >> 16) & 1u)) >> 16;
  return (u16)r;
}
__device__ __forceinline__ unsigned int pk2(float a, float b){
  return (unsigned int)f2bf(a) | ((unsigned int)f2bf(b) << 16);
}

// ---- zero deg (replaces 40us rocclr fillBuffer in replay path) ----
__global__ __launch_bounds__(512) void k_zero(int* __restrict__ deg, int n){
  int i = blockIdx.x * 512 + threadIdx.x;
  if (i < n) deg[i] = 0;
}

// ---- fused: weight bf16 conversion (blocks 0..383) + degree count ----
__global__ __launch_bounds__(256) void k_pre(const int* __restrict__ dst,
    int* __restrict__ deg, const float* __restrict__ Wpre,
    const float* __restrict__ Wmrg, const float* __restrict__ Wcv,
    u16* __restrict__ WT, u16* __restrict__ Wc, int E){
  int bid = blockIdx.x;
  if (bid < 384){
    int idx = bid * 256 + threadIdx.x;
    if (idx < 65536){
      int j = idx & 511, k = idx >> 9;
      float v = (j < 256) ? Wpre[k * 256 + j] : Wmrg[k * 256 + (j - 256)];
      WT[j * 128 + k] = f2bf(v);
    } else if (idx < 65536 + 32768){
      int x = idx - 65536;
      Wc[x] = f2bf(Wcv[x]);
    }
  } else {
    int e = (bid - 384) * 256 + threadIdx.x;
    if (e < E) atomicAdd(&deg[dst[e]], 1);
  }
}

// ---- hierarchical scan: 1) per-block sums ----
__global__ __launch_bounds__(256) void k_scan1(const int* __restrict__ deg,
    int* __restrict__ bsum, int n){
  __shared__ int red[256];
  int t = threadIdx.x;
  int i = blockIdx.x * 256 + t;
  red[t] = (i < n) ? deg[i] : 0;
  __syncthreads();
  for (int off = 128; off > 0; off >>= 1){
    if (t < off) red[t] += red[t + off];
    __syncthreads();
  }
  if (t == 0) bsum[blockIdx.x] = red[0];
}

// ---- 2) single-block exclusive scan of block sums (nb <= 256) ----
__global__ __launch_bounds__(256) void k_scan2(int* __restrict__ bsum, int nb){
  __shared__ int s[256];
  int t = threadIdx.x;
  int v = (t < nb) ? bsum[t] : 0;
  s[t] = v;
  __syncthreads();
  for (int off = 1; off < 256; off <<= 1){
    int u = (t >= off) ? s[t - off] : 0;
    __syncthreads();
    s[t] += u;
    __syncthreads();
  }
  if (t < nb) bsum[t] = s[t] - v; // exclusive
}

// ---- 3) block-local exclusive scan + offset -> row_start, cursor, norm ----
__global__ __launch_bounds__(256) void k_scan3(const int* __restrict__ deg,
    const int* __restrict__ bsum, int* __restrict__ row_start,
    int* __restrict__ cursor, float* __restrict__ norm, int n){
  __shared__ int s[256];
  int t = threadIdx.x;
  int i = blockIdx.x * 256 + t;
  int v = (i < n) ? deg[i] : 0;
  s[t] = v;
  __syncthreads();
  for (int off = 1; off < 256; off <<= 1){
    int u = (t >= off) ? s[t - off] : 0;
    __syncthreads();
    s[t] += u;
    __syncthreads();
  }
  int ex = s[t] - v + bsum[blockIdx.x];
  if (i < n){
    row_start[i] = ex;
    cursor[i] = ex;
    norm[i] = (v > 0) ? rsqrtf((float)v) : 0.f;
    if (i == n - 1) row_start[n] = ex + v;
  }
}

// ---- scatter edges into CSR slots ----
__global__ void k_scatter(const int* __restrict__ src, const int* __restrict__ dstA,
    int* __restrict__ cursor, int* __restrict__ csr_src, int E){
  int e = blockIdx.x * blockDim.x + threadIdx.x;
  if (e < E){
    int d = dstA[e];
    int pos = atomicAdd(&cursor[d], 1);
    csr_src[pos] = src[e];
  }
}

// ---- init (MFMA, swapped-D): merge = X@Wm + bm; bufA = norm .* relu(X@Wp + bp + merge)
// grid ceil(n/64), 512 threads = 8 waves; wave w owns paired-cols [w*32, w*32+32).
__global__ __launch_bounds__(512) void k_initM(const float* __restrict__ node,
    const u16* __restrict__ WT, const float* __restrict__ bpre,
    const float* __restrict__ bmrg, const float* __restrict__ norm,
    u16* __restrict__ merge, u16* __restrict__ outA, int n){
  __shared__ u16 Al[64 * 128];  // A tile, swizzled, 16KB
  __shared__ u16 Ep[64 * 256];  // out tile (64 rows x 512B), swizzled, 32KB
  int t = threadIdx.x;
  int w = t >> 6, l = t & 63;
  int n0 = blockIdx.x * 64;
  int cb = w * 32;
  int lk = (l >> 4) * 8;

  // prefetch epilogue scalars
  float nr4[4];
  #pragma unroll
  for (int fr = 0; fr < 4; ++fr){
    int row = n0 + fr * 16 + (l & 15);
    nr4[fr] = (row < n) ? norm[row] : 0.f;
  }
  float4 bPr[2], bMr[2];
  #pragma unroll
  for (int fcp = 0; fcp < 2; ++fcp){
    int j0 = cb + fcp * 16 + (l >> 4) * 4;
    bPr[fcp] = *(const float4*)(bpre + j0);
    bMr[fcp] = *(const float4*)(bmrg + j0);
  }

  // stage A: 64 rows x 128 f32 -> bf16 swizzled LDS
  {
    int row = t >> 3, c0 = (t & 7) * 16;
    const float* src = node + (size_t)(n0 + row) * ICNST + c0;
    bool ok = (n0 + row) < n;
    #pragma unroll
    for (int q = 0; q < 4; ++q){
      float4 v = ok ? *(const float4*)(src + q * 4) : float4{0.f, 0.f, 0.f, 0.f};
      int byte = (row * 256 + c0 * 2 + q * 8) ^ ((row & 7) << 4);
      uint2 pp; pp.x = pk2(v.x, v.y); pp.y = pk2(v.z, v.w);
      *(uint2*)((char*)Al + byte) = pp;
    }
  }
  __syncthreads();

  f32x4 acc[4][4] = {}; // [row frag][col frag: 0,1=pre 2,3=merge], D transposed
  #pragma unroll
  for (int ks = 0; ks < 4; ++ks){
    bf16x8 bf[4];
    #pragma unroll
    for (int fc = 0; fc < 4; ++fc){
      int j = (fc < 2) ? (cb + fc * 16 + (l & 15))
                       : (256 + cb + (fc - 2) * 16 + (l & 15));
      bf[fc] = *(const bf16x8*)(WT + (size_t)j * 128 + ks * 32 + lk);
    }
    bf16x8 af[4];
    #pragma unroll
    for (int fr = 0; fr < 4; ++fr){
      int row = fr * 16 + (l & 15);
      int byte = (row * 256 + ks * 64 + (l >> 4) * 16) ^ ((l & 7) << 4);
      af[fr] = *(const bf16x8*)((const char*)Al + byte);
    }
    #pragma unroll
    for (int fr = 0; fr < 4; ++fr)
      #pragma unroll
      for (int fc = 0; fc < 4; ++fc)
        acc[fr][fc] = __builtin_amdgcn_mfma_f32_16x16x32_bf16(bf[fc], af[fr], acc[fr][fc], 0, 0, 0);
  }

  // epilogue: merge direct (scattered ushort4 — measured neutral), out via Ep
  #pragma unroll
  for (int fr = 0; fr < 4; ++fr){
    int rl = fr * 16 + (l & 15);
    int row = n0 + rl;
    bool ok = row < n;
    float nr = nr4[fr];
    #pragma unroll
    for (int fcp = 0; fcp < 2; ++fcp){
      int j0 = cb + fcp * 16 + (l >> 4) * 4;
      f32x4 aP = acc[fr][fcp], aM = acc[fr][fcp + 2];
      float bPe[4] = {bPr[fcp].x, bPr[fcp].y, bPr[fcp].z, bPr[fcp].w};
      float bMe[4] = {bMr[fcp].x, bMr[fcp].y, bMr[fcp].z, bMr[fcp].w};
      ushort4 mgv, outv;
      u16* mgp = (u16*)&mgv; u16* otp = (u16*)&outv;
      #pragma unroll
      for (int r = 0; r < 4; ++r){
        float mg = aM[r] + bMe[r];
        float o  = aP[r] + bPe[r] + mg;
        o = (o > 0.f) ? o : 0.f;
        mgp[r] = f2bf(mg);
        otp[r] = f2bf(nr * o);
      }
      if (ok) *(ushort4*)(merge + (size_t)row * C2 + j0) = mgv;
      int byte = (rl * 512 + j0 * 2) ^ ((rl & 7) << 4);
      *(ushort4*)((char*)Ep + byte) = outv;
    }
  }
  __syncthreads();
  // coalesced store outA
  #pragma unroll
  for (int round = 0; round < 4; ++round){
    int idx = round * 512 + t;
    int rl = idx >> 5, off = (idx & 31) * 16;
    int byte = (rl * 512 + off) ^ ((rl & 7) << 4);
    uint4 v = *(const uint4*)((const char*)Ep + byte);
    if (n0 + rl < n)
      *(uint4*)((char*)outA + (size_t)(n0 + rl) * 512 + off) = v;
  }
}

// ---- conv (MFMA, swapped-D, LDS-coalesced merge+epilogue), in place ----
// FINAL=0: buf = norm .* relu(conv+bc+merge); FINAL=1: out = pair-mean (f32)
template<int FINAL>
__global__ __launch_bounds__(512) void k_convM(u16* __restrict__ buf,
    const u16* __restrict__ Wc, const float* __restrict__ bc,
    const u16* __restrict__ merge, const float* __restrict__ norm,
    float* __restrict__ out, int n){
  __shared__ u16 Al[64 * 256];  // A tile, swizzled, 32KB
  __shared__ u16 Ep[64 * 256];  // merge-in / result-out tile (64 x 512B), 32KB
  int t = threadIdx.x;
  int w = t >> 6, l = t & 63;
  int n0 = blockIdx.x * 64;
  int wh = w >> 2;
  int lk = (l >> 4) * 8;

  float nr4[4];
  #pragma unroll
  for (int fr = 0; fr < 4; ++fr){
    int row = n0 + fr * 16 + (l & 15);
    nr4[fr] = (row < n) ? norm[row] : 0.f;
  }
  float4 bCr[2];
  #pragma unroll
  for (int fc = 0; fc < 2; ++fc)
    bCr[fc] = *(const float4*)(bc + w * 32 + fc * 16 + (l >> 4) * 4);

  // stage A (buf) and merge, both coalesced, swizzled LDS
  {
    int row = t >> 3, c0 = (t & 7) * 32;
    bool ok = (n0 + row) < n;
    const u16* srcA = buf   + (size_t)(n0 + row) * C2 + c0;
    const u16* srcM = merge + (size_t)(n0 + row) * C2 + c0;
    #pragma unroll
    for (int q = 0; q < 4; ++q){
      uint4 va = ok ? *(const uint4*)(srcA + q * 8) : uint4{0u, 0u, 0u, 0u};
      int byte = (row * 512 + c0 * 2 + q * 16) ^ ((row & 7) << 4);
      *(uint4*)((char*)Al + byte) = va;
      uint4 vm = ok ? *(const uint4*)(srcM + q * 8) : uint4{0u, 0u, 0u, 0u};
      *(uint4*)((char*)Ep + byte) = vm;
    }
  }
  __syncthreads();

  f32x4 acc[4][2] = {}; // D transposed: reg r -> output col j0+r
  #pragma unroll
  for (int ks = 0; ks < 4; ++ks){
    bf16x8 bf[2];
    #pragma unroll
    for (int fc = 0; fc < 2; ++fc){
      int rw = w * 32 + fc * 16 + (l & 15);
      bf[fc] = *(const bf16x8*)(Wc + (size_t)rw * 128 + ks * 32 + lk);
    }
    bf16x8 af[4];
    #pragma unroll
    for (int fr = 0; fr < 4; ++fr){
      int row = fr * 16 + (l & 15);
      int byte = (row * 512 + wh * 256 + ks * 64 + (l >> 4) * 16) ^ ((l & 7) << 4);
      af[fr] = *(const bf16x8*)((const char*)Al + byte);
    }
    #pragma unroll
    for (int fr = 0; fr < 4; ++fr)
      #pragma unroll
      for (int fc = 0; fc < 2; ++fc)
        acc[fr][fc] = __builtin_amdgcn_mfma_f32_16x16x32_bf16(bf[fc], af[fr], acc[fr][fc], 0, 0, 0);
  }

  // epilogue: read merge from Ep slot, write result (8B) to the SAME slot
  #pragma unroll
  for (int fr = 0; fr < 4; ++fr){
    int rl = fr * 16 + (l & 15);
    float nr = nr4[fr];
    #pragma unroll
    for (int fc = 0; fc < 2; ++fc){
      int j0 = w * 32 + fc * 16 + (l >> 4) * 4;
      int byte = (rl * 512 + j0 * 2) ^ ((rl & 7) << 4);
      ushort4 mg4 = *(const ushort4*)((const char*)Ep + byte);
      const u16* mge = (const u16*)&mg4;
      float bCe[4] = {bCr[fc].x, bCr[fc].y, bCr[fc].z, bCr[fc].w};
      float v[4];
      #pragma unroll
      for (int r = 0; r < 4; ++r){
        float o = acc[fr][fc][r] + bCe[r] + bf2f(mge[r]);
        v[r] = (o > 0.f) ? o : 0.f;
      }
      if (!FINAL){
        ushort4 ov;
        u16* ovp = (u16*)&ov;
        #pragma unroll
        for (int r = 0; r < 4; ++r) ovp[r] = f2bf(nr * v[r]);
        *(ushort4*)((char*)Ep + byte) = ov;
      } else {
        float2 om;
        om.x = 0.5f * (v[0] + v[1]);
        om.y = 0.5f * (v[2] + v[3]);
        *(float2*)((char*)Ep + byte) = om;   // same 8B slot: (j0>>1)*4 == j0*2
      }
    }
  }
  __syncthreads();
  // coalesced store: Ep rows (512B) -> buf rows (512B u16) or out rows (512B f32)
  char* dstBase = FINAL ? (char*)out : (char*)buf;
  #pragma unroll
  for (int round = 0; round < 4; ++round){
    int idx = round * 512 + t;
    int rl = idx >> 5, off = (idx & 31) * 16;
    int byte = (rl * 512 + off) ^ ((rl & 7) << 4);
    uint4 v = *(const uint4*)((const char*)Ep + byte);
    if (n0 + rl < n)
      *(uint4*)(dstBase + (size_t)(n0 + rl) * 512 + off) = v;
  }
}

// ---- propagation: 2 dst rows per wave, 32 lanes x uint4 per row ----
// B[d] = norm[d] * sum_{e in in(d)} A[s]  (A pre-scaled by norm[s])
__global__ __launch_bounds__(256) void k_prop(const u16* __restrict__ A, u16* __restrict__ B,
    const int* __restrict__ row_start, const int* __restrict__ csr,
    const float* __restrict__ norm, int n){
  int wid = (blockIdx.x * 256 + threadIdx.x) >> 6;
  int lane = threadIdx.x & 63;
  int half = lane >> 5, c = lane & 31;
  int gw = wid * 2 + half;
  if (gw >= n) return;
  int b = row_start[gw], e = row_start[gw + 1];
  float a0 = 0.f, a1 = 0.f, a2 = 0.f, a3 = 0.f, a4 = 0.f, a5 = 0.f, a6 = 0.f, a7 = 0.f;
  const u16* Ac = A + (size_t)c * 8;
  int j = b;
  for (; j + 4 <= e; j += 4){
    int s0 = csr[j], s1 = csr[j + 1], s2 = csr[j + 2], s3 = csr[j + 3];
    uint4 r0 = *(const uint4*)(Ac + (size_t)s0 * C2);
    uint4 r1 = *(const uint4*)(Ac + (size_t)s1 * C2);
    uint4 r2 = *(const uint4*)(Ac + (size_t)s2 * C2);
    uint4 r3 = *(const uint4*)(Ac + (size_t)s3 * C2);
    float2 p;
    p = bf2x2(r0.x); a0 += p.x; a1 += p.y; p = bf2x2(r0.y); a2 += p.x; a3 += p.y;
    p = bf2x2(r0.z); a4 += p.x; a5 += p.y; p = bf2x2(r0.w); a6 += p.x; a7 += p.y;
    p = bf2x2(r1.x); a0 += p.x; a1 += p.y; p = bf2x2(r1.y); a2 += p.x; a3 += p.y;
    p = bf2x2(r1.z); a4 += p.x; a5 += p.y; p = bf2x2(r1.w); a6 += p.x; a7 += p.y;
    p = bf2x2(r2.x); a0 += p.x; a1 += p.y; p = bf2x2(r2.y); a2 += p.x; a3 += p.y;
    p = bf2x2(r2.z); a4 += p.x; a5 += p.y; p = bf2x2(r2.w); a6 += p.x; a7 += p.y;
    p = bf2x2(r3.x); a0 += p.x; a1 += p.y; p = bf2x2(r3.y); a2 += p.x; a3 += p.y;
    p = bf2x2(r3.z); a4 += p.x; a5 += p.y; p = bf2x2(r3.w); a6 += p.x; a7 += p.y;
  }
  for (; j < e; ++j){
    int s0 = csr[j];
    uint4 r0 = *(const uint4*)(Ac + (size_t)s0 * C2);
    float2 p;
    p = bf2x2(r0.x); a0 += p.x; a1 += p.y; p = bf2x2(r0.y); a2 += p.x; a3 += p.y;
    p = bf2x2(r0.z); a4 += p.x; a5 += p.y; p = bf2x2(r0.w); a6 += p.x; a7 += p.y;
  }
  float nd = norm[gw];
  uint4 ov;
  ov.x = pk2(nd * a0, nd * a1);
  ov.y = pk2(nd * a2, nd * a3);
  ov.z = pk2(nd * a4, nd * a5);
  ov.w = pk2(nd * a6, nd * a7);
  *(uint4*)(B + (size_t)gw * C2 + c * 8) = ov;
}

extern "C" void kernel_launch(void* const* d_in, const int* in_sizes, int n_in,
                              void* d_out, int out_size, void* d_ws, size_t ws_size,
                              hipStream_t stream){
  const float* node = (const float*)d_in[0];
  const int*   eidx = (const int*)d_in[1];
  const float* Wpre = (const float*)d_in[2];
  const float* bpre = (const float*)d_in[3];
  const float* Wmrg = (const float*)d_in[4];
  const float* bmrg = (const float*)d_in[5];
  const float* Wcv  = (const float*)d_in[6];
  const float* bcv  = (const float*)d_in[7];
  float* out = (float*)d_out;

  const int n = in_sizes[0] / ICNST;
  const int E = in_sizes[1] / 2;
  const int* srcp = eidx;
  const int* dstp = eidx + E;

  char* ws = (char*)d_ws;
  size_t off = 0;
  auto alloc = [&](size_t bytes) -> char* {
    char* p = ws + off;
    off += bytes;
    off = (off + 255) & ~(size_t)255;
    return p;
  };
  int*   deg       = (int*)  alloc((size_t)n * 4);
  float* norm      = (float*)alloc((size_t)n * 4);
  int*   row_start = (int*)  alloc((size_t)(n + 1) * 4);
  int*   cursor    = (int*)  alloc((size_t)n * 4);
  int*   csr       = (int*)  alloc((size_t)E * 4);
  u16*   merge     = (u16*)  alloc((size_t)n * C2 * 2);
  u16*   bufA      = (u16*)  alloc((size_t)n * C2 * 2);
  u16*   bufB      = (u16*)  alloc((size_t)n * C2 * 2);
  u16*   WT        = (u16*)  alloc((size_t)512 * 128 * 2);
  u16*   Wcbf      = (u16*)  alloc((size_t)2 * 128 * 128 * 2);
  int*   bsum      = (int*)  alloc((size_t)256 * 4);
  (void)ws_size; (void)n_in; (void)out_size;

  const int nb = (n + 255) / 256;

  k_zero<<<(n + 511) / 512, 512, 0, stream>>>(deg, n);
  k_pre<<<384 + (E + 255) / 256, 256, 0, stream>>>(dstp, deg, Wpre, Wmrg, Wcv, WT, Wcbf, E);
  k_scan1<<<nb, 256, 0, stream>>>(deg, bsum, n);
  k_scan2<<<1, 256, 0, stream>>>(bsum, nb);
  k_scan3<<<nb, 256, 0, stream>>>(deg, bsum, row_start, cursor, norm, n);
  k_scatter<<<(E + 255) / 256, 256, 0, stream>>>(srcp, dstp, cursor, csr, E);

  int gb64 = (n + 63) / 64;
  k_initM<<<gb64, 512, 0, stream>>>(node, WT, bpre, bmrg, norm, merge, bufA, n);

  // iteration 1: prop A->B (pre-scaled rows), conv in-place B (writes scaled)
  k_prop<<<(n + 7) / 8, 256, 0, stream>>>(bufA, bufB, row_start, csr, norm, n);
  k_convM<0><<<gb64, 512, 0, stream>>>(bufB, Wcbf, bcv, merge, norm, nullptr, n);
  // iteration 2: prop B->A, conv fused with final mean -> out (f32)
  k_prop<<<(n + 7) / 8, 256, 0, stream>>>(bufB, bufA, row_start, csr, norm, n);
  k_convM<1><<<gb64, 512, 0, stream>>>(bufA, Wcbf, bcv, merge, norm, out, n);
}

// Round 13
// 204.623 us; speedup vs baseline: 4.5398x; 1.0217x over previous
//
#include <hip/hip_runtime.h>

typedef unsigned short u16;
typedef __attribute__((ext_vector_type(8))) short bf16x8;
typedef __attribute__((ext_vector_type(4))) float f32x4;

#define ICNST 128
#define C2 256   // OC*WIDTH

__device__ __forceinline__ float bf2f(u16 u){
  return __uint_as_float(((unsigned int)u) << 16);
}
__device__ __forceinline__ float2 bf2x2(unsigned int u){
  float2 r;
  r.x = __uint_as_float(u << 16);
  r.y = __uint_as_float(u & 0xffff0000u);
  return r;
}
__device__ __forceinline__ u16 f2bf(float f){
  unsigned int u = __float_as_uint(f);
  unsigned int r = (u + 0x7fffu + ((u >> 16) & 1u)) >> 16;
  return (u16)r;
}
__device__ __forceinline__ unsigned int pk2(float a, float b){
  return (unsigned int)f2bf(a) | ((unsigned int)f2bf(b) << 16);
}

// ---- zero deg ----
__global__ __launch_bounds__(512) void k_zero(int* __restrict__ deg, int n){
  int i = blockIdx.x * 512 + threadIdx.x;
  if (i < n) deg[i] = 0;
}

// ---- fused: weight bf16 conversion (blocks 0..383) + degree count ----
__global__ __launch_bounds__(256) void k_pre(const int* __restrict__ dst,
    int* __restrict__ deg, const float* __restrict__ Wpre,
    const float* __restrict__ Wmrg, const float* __restrict__ Wcv,
    u16* __restrict__ WT, u16* __restrict__ Wc, int E){
  int bid = blockIdx.x;
  if (bid < 384){
    int idx = bid * 256 + threadIdx.x;
    if (idx < 65536){
      int j = idx & 511, k = idx >> 9;
      float v = (j < 256) ? Wpre[k * 256 + j] : Wmrg[k * 256 + (j - 256)];
      WT[j * 128 + k] = f2bf(v);
    } else if (idx < 65536 + 32768){
      int x = idx - 65536;
      Wc[x] = f2bf(Wcv[x]);
    }
  } else {
    int e = (bid - 384) * 256 + threadIdx.x;
    if (e < E) atomicAdd(&deg[dst[e]], 1);
  }
}

// ---- hierarchical scan: 1) per-block sums ----
__global__ __launch_bounds__(256) void k_scan1(const int* __restrict__ deg,
    int* __restrict__ bsum, int n){
  __shared__ int red[256];
  int t = threadIdx.x;
  int i = blockIdx.x * 256 + t;
  red[t] = (i < n) ? deg[i] : 0;
  __syncthreads();
  for (int off = 128; off > 0; off >>= 1){
    if (t < off) red[t] += red[t + off];
    __syncthreads();
  }
  if (t == 0) bsum[blockIdx.x] = red[0];
}

// ---- 2) single-block exclusive scan of block sums (nb <= 256) ----
__global__ __launch_bounds__(256) void k_scan2(int* __restrict__ bsum, int nb){
  __shared__ int s[256];
  int t = threadIdx.x;
  int v = (t < nb) ? bsum[t] : 0;
  s[t] = v;
  __syncthreads();
  for (int off = 1; off < 256; off <<= 1){
    int u = (t >= off) ? s[t - off] : 0;
    __syncthreads();
    s[t] += u;
    __syncthreads();
  }
  if (t < nb) bsum[t] = s[t] - v; // exclusive
}

// ---- 3) block-local exclusive scan + offset -> row_start, cursor, norm ----
__global__ __launch_bounds__(256) void k_scan3(const int* __restrict__ deg,
    const int* __restrict__ bsum, int* __restrict__ row_start,
    int* __restrict__ cursor, float* __restrict__ norm, int n){
  __shared__ int s[256];
  int t = threadIdx.x;
  int i = blockIdx.x * 256 + t;
  int v = (i < n) ? deg[i] : 0;
  s[t] = v;
  __syncthreads();
  for (int off = 1; off < 256; off <<= 1){
    int u = (t >= off) ? s[t - off] : 0;
    __syncthreads();
    s[t] += u;
    __syncthreads();
  }
  int ex = s[t] - v + bsum[blockIdx.x];
  if (i < n){
    row_start[i] = ex;
    cursor[i] = ex;
    norm[i] = (v > 0) ? rsqrtf((float)v) : 0.f;
    if (i == n - 1) row_start[n] = ex + v;
  }
}

// ---- scatter edges into CSR slots ----
__global__ void k_scatter(const int* __restrict__ src, const int* __restrict__ dstA,
    int* __restrict__ cursor, int* __restrict__ csr_src, int E){
  int e = blockIdx.x * blockDim.x + threadIdx.x;
  if (e < E){
    int d = dstA[e];
    int pos = atomicAdd(&cursor[d], 1);
    csr_src[pos] = src[e];
  }
}

// ---- init (MFMA, swapped-D): merge = X@Wm + bm; bufA = norm .* relu(X@Wp + bp + merge)
__global__ __launch_bounds__(512) void k_initM(const float* __restrict__ node,
    const u16* __restrict__ WT, const float* __restrict__ bpre,
    const float* __restrict__ bmrg, const float* __restrict__ norm,
    u16* __restrict__ merge, u16* __restrict__ outA, int n){
  __shared__ u16 Al[64 * 128];  // A tile, swizzled, 16KB
  __shared__ u16 Ep[64 * 256];  // out tile, swizzled, 32KB
  int t = threadIdx.x;
  int w = t >> 6, l = t & 63;
  int n0 = blockIdx.x * 64;
  int cb = w * 32;
  int lk = (l >> 4) * 8;

  float nr4[4];
  #pragma unroll
  for (int fr = 0; fr < 4; ++fr){
    int row = n0 + fr * 16 + (l & 15);
    nr4[fr] = (row < n) ? norm[row] : 0.f;
  }
  float4 bPr[2], bMr[2];
  #pragma unroll
  for (int fcp = 0; fcp < 2; ++fcp){
    int j0 = cb + fcp * 16 + (l >> 4) * 4;
    bPr[fcp] = *(const float4*)(bpre + j0);
    bMr[fcp] = *(const float4*)(bmrg + j0);
  }

  {
    int row = t >> 3, c0 = (t & 7) * 16;
    const float* src = node + (size_t)(n0 + row) * ICNST + c0;
    bool ok = (n0 + row) < n;
    #pragma unroll
    for (int q = 0; q < 4; ++q){
      float4 v = ok ? *(const float4*)(src + q * 4) : float4{0.f, 0.f, 0.f, 0.f};
      int byte = (row * 256 + c0 * 2 + q * 8) ^ ((row & 7) << 4);
      uint2 pp; pp.x = pk2(v.x, v.y); pp.y = pk2(v.z, v.w);
      *(uint2*)((char*)Al + byte) = pp;
    }
  }
  __syncthreads();

  f32x4 acc[4][4] = {};
  #pragma unroll
  for (int ks = 0; ks < 4; ++ks){
    bf16x8 bf[4];
    #pragma unroll
    for (int fc = 0; fc < 4; ++fc){
      int j = (fc < 2) ? (cb + fc * 16 + (l & 15))
                       : (256 + cb + (fc - 2) * 16 + (l & 15));
      bf[fc] = *(const bf16x8*)(WT + (size_t)j * 128 + ks * 32 + lk);
    }
    bf16x8 af[4];
    #pragma unroll
    for (int fr = 0; fr < 4; ++fr){
      int row = fr * 16 + (l & 15);
      int byte = (row * 256 + ks * 64 + (l >> 4) * 16) ^ ((l & 7) << 4);
      af[fr] = *(const bf16x8*)((const char*)Al + byte);
    }
    #pragma unroll
    for (int fr = 0; fr < 4; ++fr)
      #pragma unroll
      for (int fc = 0; fc < 4; ++fc)
        acc[fr][fc] = __builtin_amdgcn_mfma_f32_16x16x32_bf16(bf[fc], af[fr], acc[fr][fc], 0, 0, 0);
  }

  #pragma unroll
  for (int fr = 0; fr < 4; ++fr){
    int rl = fr * 16 + (l & 15);
    int row = n0 + rl;
    bool ok = row < n;
    float nr = nr4[fr];
    #pragma unroll
    for (int fcp = 0; fcp < 2; ++fcp){
      int j0 = cb + fcp * 16 + (l >> 4) * 4;
      f32x4 aP = acc[fr][fcp], aM = acc[fr][fcp + 2];
      float bPe[4] = {bPr[fcp].x, bPr[fcp].y, bPr[fcp].z, bPr[fcp].w};
      float bMe[4] = {bMr[fcp].x, bMr[fcp].y, bMr[fcp].z, bMr[fcp].w};
      ushort4 mgv, outv;
      u16* mgp = (u16*)&mgv; u16* otp = (u16*)&outv;
      #pragma unroll
      for (int r = 0; r < 4; ++r){
        float mg = aM[r] + bMe[r];
        float o  = aP[r] + bPe[r] + mg;
        o = (o > 0.f) ? o : 0.f;
        mgp[r] = f2bf(mg);
        otp[r] = f2bf(nr * o);
      }
      if (ok) *(ushort4*)(merge + (size_t)row * C2 + j0) = mgv;
      int byte = (rl * 512 + j0 * 2) ^ ((rl & 7) << 4);
      *(ushort4*)((char*)Ep + byte) = outv;
    }
  }
  __syncthreads();
  #pragma unroll
  for (int round = 0; round < 4; ++round){
    int idx = round * 512 + t;
    int rl = idx >> 5, off = (idx & 31) * 16;
    int byte = (rl * 512 + off) ^ ((rl & 7) << 4);
    uint4 v = *(const uint4*)((const char*)Ep + byte);
    if (n0 + rl < n)
      *(uint4*)((char*)outA + (size_t)(n0 + rl) * 512 + off) = v;
  }
}

// ---- FUSED prop + conv (MFMA, swapped-D) ----
// Gather-sum P*src directly into the swizzled LDS A-tile, then block-diag conv.
// FINAL=0: dstB = norm .* relu(conv(P*src) + bc + merge)
// FINAL=1: out  = pair-mean of relu(conv(P*src) + bc + merge), f32
template<int FINAL>
__global__ __launch_bounds__(512) void k_pconv(const u16* __restrict__ src,
    const int* __restrict__ row_start, const int* __restrict__ csr,
    const float* __restrict__ norm,
    const u16* __restrict__ Wc, const float* __restrict__ bc,
    const u16* __restrict__ merge,
    u16* __restrict__ dstB, float* __restrict__ out, int n){
  __shared__ u16 Al[64 * 256];  // A tile (prop result), swizzled, 32KB
  int t = threadIdx.x;
  int w = t >> 6, l = t & 63;
  int n0 = blockIdx.x * 64;
  int wh = w >> 2;
  int lk = (l >> 4) * 8;
  int half = l >> 5, c = l & 31;

  // epilogue scalars
  float nr4[4];
  #pragma unroll
  for (int fr = 0; fr < 4; ++fr){
    int row = n0 + fr * 16 + (l & 15);
    nr4[fr] = (row < n) ? norm[row] : 0.f;
  }
  float4 bCr[2];
  #pragma unroll
  for (int fc = 0; fc < 2; ++fc)
    bCr[fc] = *(const float4*)(bc + w * 32 + fc * 16 + (l >> 4) * 4);

  // ---- PROP phase: wave w computes dst rows [w*8, w*8+8), 2 rows at a time ----
  const u16* Ac = src + (size_t)c * 8;
  #pragma unroll
  for (int it = 0; it < 4; ++it){
    int rl = w * 8 + it * 2 + half;
    int gw = n0 + rl;
    float a0 = 0.f, a1 = 0.f, a2 = 0.f, a3 = 0.f, a4 = 0.f, a5 = 0.f, a6 = 0.f, a7 = 0.f;
    float nd = 0.f;
    if (gw < n){
      int b = row_start[gw], e = row_start[gw + 1];
      int j = b;
      for (; j + 4 <= e; j += 4){
        int s0 = csr[j], s1 = csr[j + 1], s2 = csr[j + 2], s3 = csr[j + 3];
        uint4 r0 = *(const uint4*)(Ac + (size_t)s0 * C2);
        uint4 r1 = *(const uint4*)(Ac + (size_t)s1 * C2);
        uint4 r2 = *(const uint4*)(Ac + (size_t)s2 * C2);
        uint4 r3 = *(const uint4*)(Ac + (size_t)s3 * C2);
        float2 p;
        p = bf2x2(r0.x); a0 += p.x; a1 += p.y; p = bf2x2(r0.y); a2 += p.x; a3 += p.y;
        p = bf2x2(r0.z); a4 += p.x; a5 += p.y; p = bf2x2(r0.w); a6 += p.x; a7 += p.y;
        p = bf2x2(r1.x); a0 += p.x; a1 += p.y; p = bf2x2(r1.y); a2 += p.x; a3 += p.y;
        p = bf2x2(r1.z); a4 += p.x; a5 += p.y; p = bf2x2(r1.w); a6 += p.x; a7 += p.y;
        p = bf2x2(r2.x); a0 += p.x; a1 += p.y; p = bf2x2(r2.y); a2 += p.x; a3 += p.y;
        p = bf2x2(r2.z); a4 += p.x; a5 += p.y; p = bf2x2(r2.w); a6 += p.x; a7 += p.y;
        p = bf2x2(r3.x); a0 += p.x; a1 += p.y; p = bf2x2(r3.y); a2 += p.x; a3 += p.y;
        p = bf2x2(r3.z); a4 += p.x; a5 += p.y; p = bf2x2(r3.w); a6 += p.x; a7 += p.y;
      }
      for (; j < e; ++j){
        int s0 = csr[j];
        uint4 r0 = *(const uint4*)(Ac + (size_t)s0 * C2);
        float2 p;
        p = bf2x2(r0.x); a0 += p.x; a1 += p.y; p = bf2x2(r0.y); a2 += p.x; a3 += p.y;
        p = bf2x2(r0.z); a4 += p.x; a5 += p.y; p = bf2x2(r0.w); a6 += p.x; a7 += p.y;
      }
      nd = norm[gw];
    }
    uint4 ov;
    ov.x = pk2(nd * a0, nd * a1);
    ov.y = pk2(nd * a2, nd * a3);
    ov.z = pk2(nd * a4, nd * a5);
    ov.w = pk2(nd * a6, nd * a7);
    int byte = (rl * 512 + c * 16) ^ ((rl & 7) << 4);
    *(uint4*)((char*)Al + byte) = ov;
  }
  __syncthreads();

  // ---- CONV phase (same as proven k_convM) ----
  f32x4 acc[4][2] = {};
  #pragma unroll
  for (int ks = 0; ks < 4; ++ks){
    bf16x8 bf[2];
    #pragma unroll
    for (int fc = 0; fc < 2; ++fc){
      int rw = w * 32 + fc * 16 + (l & 15);
      bf[fc] = *(const bf16x8*)(Wc + (size_t)rw * 128 + ks * 32 + lk);
    }
    bf16x8 af[4];
    #pragma unroll
    for (int fr = 0; fr < 4; ++fr){
      int row = fr * 16 + (l & 15);
      int byte = (row * 512 + wh * 256 + ks * 64 + (l >> 4) * 16) ^ ((l & 7) << 4);
      af[fr] = *(const bf16x8*)((const char*)Al + byte);
    }
    #pragma unroll
    for (int fr = 0; fr < 4; ++fr)
      #pragma unroll
      for (int fc = 0; fc < 2; ++fc)
        acc[fr][fc] = __builtin_amdgcn_mfma_f32_16x16x32_bf16(bf[fc], af[fr], acc[fr][fc], 0, 0, 0);
  }

  // epilogue: scattered merge read (measured neutral), results into regs
  ushort4 resB[4][2];
  float2  resF[4][2];
  #pragma unroll
  for (int fr = 0; fr < 4; ++fr){
    int row = n0 + fr * 16 + (l & 15);
    bool ok = row < n;
    float nr = nr4[fr];
    #pragma unroll
    for (int fc = 0; fc < 2; ++fc){
      int j0 = w * 32 + fc * 16 + (l >> 4) * 4;
      ushort4 mg4 = ok ? *(const ushort4*)(merge + (size_t)row * C2 + j0)
                       : ushort4{0, 0, 0, 0};
      const u16* mge = (const u16*)&mg4;
      float bCe[4] = {bCr[fc].x, bCr[fc].y, bCr[fc].z, bCr[fc].w};
      float v[4];
      #pragma unroll
      for (int r = 0; r < 4; ++r){
        float o = acc[fr][fc][r] + bCe[r] + bf2f(mge[r]);
        v[r] = (o > 0.f) ? o : 0.f;
      }
      if (!FINAL){
        u16* rp = (u16*)&resB[fr][fc];
        #pragma unroll
        for (int r = 0; r < 4; ++r) rp[r] = f2bf(nr * v[r]);
      } else {
        resF[fr][fc].x = 0.5f * (v[0] + v[1]);
        resF[fr][fc].y = 0.5f * (v[2] + v[3]);
      }
    }
  }
  __syncthreads();   // all MFMA A-reads done; safe to overwrite Al
  #pragma unroll
  for (int fr = 0; fr < 4; ++fr){
    int rl = fr * 16 + (l & 15);
    #pragma unroll
    for (int fc = 0; fc < 2; ++fc){
      int j0 = w * 32 + fc * 16 + (l >> 4) * 4;
      int byte = (rl * 512 + j0 * 2) ^ ((rl & 7) << 4);
      if (!FINAL) *(ushort4*)((char*)Al + byte) = resB[fr][fc];
      else        *(float2*)((char*)Al + byte) = resF[fr][fc];
    }
  }
  __syncthreads();
  char* dstBase = FINAL ? (char*)out : (char*)dstB;
  #pragma unroll
  for (int round = 0; round < 4; ++round){
    int idx = round * 512 + t;
    int rl = idx >> 5, off = (idx & 31) * 16;
    int byte = (rl * 512 + off) ^ ((rl & 7) << 4);
    uint4 v = *(const uint4*)((const char*)Al + byte);
    if (n0 + rl < n)
      *(uint4*)(dstBase + (size_t)(n0 + rl) * 512 + off) = v;
  }
}

extern "C" void kernel_launch(void* const* d_in, const int* in_sizes, int n_in,
                              void* d_out, int out_size, void* d_ws, size_t ws_size,
                              hipStream_t stream){
  const float* node = (const float*)d_in[0];
  const int*   eidx = (const int*)d_in[1];
  const float* Wpre = (const float*)d_in[2];
  const float* bpre = (const float*)d_in[3];
  const float* Wmrg = (const float*)d_in[4];
  const float* bmrg = (const float*)d_in[5];
  const float* Wcv  = (const float*)d_in[6];
  const float* bcv  = (const float*)d_in[7];
  float* out = (float*)d_out;

  const int n = in_sizes[0] / ICNST;
  const int E = in_sizes[1] / 2;
  const int* srcp = eidx;
  const int* dstp = eidx + E;

  char* ws = (char*)d_ws;
  size_t off = 0;
  auto alloc = [&](size_t bytes) -> char* {
    char* p = ws + off;
    off += bytes;
    off = (off + 255) & ~(size_t)255;
    return p;
  };
  int*   deg       = (int*)  alloc((size_t)n * 4);
  float* norm      = (float*)alloc((size_t)n * 4);
  int*   row_start = (int*)  alloc((size_t)(n + 1) * 4);
  int*   cursor    = (int*)  alloc((size_t)n * 4);
  int*   csr       = (int*)  alloc((size_t)E * 4);
  u16*   merge     = (u16*)  alloc((size_t)n * C2 * 2);
  u16*   bufA      = (u16*)  alloc((size_t)n * C2 * 2);
  u16*   bufB      = (u16*)  alloc((size_t)n * C2 * 2);
  u16*   WT        = (u16*)  alloc((size_t)512 * 128 * 2);
  u16*   Wcbf      = (u16*)  alloc((size_t)2 * 128 * 128 * 2);
  int*   bsum      = (int*)  alloc((size_t)256 * 4);
  (void)ws_size; (void)n_in; (void)out_size;

  const int nb = (n + 255) / 256;

  k_zero<<<(n + 511) / 512, 512, 0, stream>>>(deg, n);
  k_pre<<<384 + (E + 255) / 256, 256, 0, stream>>>(dstp, deg, Wpre, Wmrg, Wcv, WT, Wcbf, E);
  k_scan1<<<nb, 256, 0, stream>>>(deg, bsum, n);
  k_scan2<<<1, 256, 0, stream>>>(bsum, nb);
  k_scan3<<<nb, 256, 0, stream>>>(deg, bsum, row_start, cursor, norm, n);
  k_scatter<<<(E + 255) / 256, 256, 0, stream>>>(srcp, dstp, cursor, csr, E);

  int gb64 = (n + 63) / 64;
  k_initM<<<gb64, 512, 0, stream>>>(node, WT, bpre, bmrg, norm, merge, bufA, n);

  // iteration 1: fused prop+conv, bufA -> bufB
  k_pconv<0><<<gb64, 512, 0, stream>>>(bufA, row_start, csr, norm, Wcbf, bcv, merge, bufB, nullptr, n);
  // iteration 2: fused prop+conv + final mean, bufB -> out (f32)
  k_pconv<1><<<gb64, 512, 0, stream>>>(bufB, row_start, csr, norm, Wcbf, bcv, merge, nullptr, out, n);
}

// Round 15
// 200.573 us; speedup vs baseline: 4.6315x; 1.0202x over previous
//
#include <hip/hip_runtime.h>

typedef unsigned short u16;
typedef unsigned char u8;
typedef __attribute__((ext_vector_type(8))) short bf16x8;
typedef __attribute__((ext_vector_type(4))) float f32x4;
typedef __attribute__((ext_vector_type(2))) float f32x2;

#define ICNST 128
#define C2 256   // OC*WIDTH

__device__ __forceinline__ float bf2f(u16 u){
  return __uint_as_float(((unsigned int)u) << 16);
}
__device__ __forceinline__ float2 bf2x2(unsigned int u){
  float2 r;
  r.x = __uint_as_float(u << 16);
  r.y = __uint_as_float(u & 0xffff0000u);
  return r;
}
__device__ __forceinline__ u16 f2bf(float f){
  unsigned int u = __float_as_uint(f);
  unsigned int r = (u + 0x7fffu + ((u >> 16) & 1u)) >> 16;
  return (u16)r;
}
__device__ __forceinline__ unsigned int pk2(float a, float b){
  return (unsigned int)f2bf(a) | ((unsigned int)f2bf(b) << 16);
}

// ---- fp8 e4m3 helpers (HW cvt on gfx950; manual fallback) ----
#if defined(__has_builtin)
#if __has_builtin(__builtin_amdgcn_cvt_pk_f32_fp8) && __has_builtin(__builtin_amdgcn_cvt_pk_fp8_f32)
#define HAVE_FP8_BUILTINS 1
#endif
#endif

#ifndef HAVE_FP8_BUILTINS
__device__ __forceinline__ float fp8tof(unsigned int b){
  unsigned int sgn = (b & 0x80u) << 24;
  unsigned int em = b & 0x7fu;
  float mag;
  if (em >= 8u){
    unsigned int e = em >> 3, m = em & 7u;
    mag = __uint_as_float(((e + 120u) << 23) | (m << 20));
  } else {
    mag = (float)em * 0.001953125f; // 2^-9
  }
  return __uint_as_float(__float_as_uint(mag) | sgn);
}
__device__ __forceinline__ unsigned int ftofp8(float f){
  unsigned int u = __float_as_uint(f);
  unsigned int s = (u >> 24) & 0x80u;
  float a = __uint_as_float(u & 0x7fffffffu);
  if (a > 448.f) a = 448.f;
  if (a < 0.015625f){
    int q = (int)(a * 512.f + 0.5f);
    return s | (unsigned int)q;
  }
  int e; float m = frexpf(a, &e);
  int q = (int)(m * 16.f + 0.5f);
  if (q == 16){ q = 8; e += 1; }
  int E = e - 1 + 7;
  if (E > 15){ E = 15; q = 14; }
  return s | (unsigned int)((E << 3) | (q & 7));
}
#endif

template<bool HI>
__device__ __forceinline__ f32x2 up2(unsigned int v){
#ifdef HAVE_FP8_BUILTINS
  return __builtin_amdgcn_cvt_pk_f32_fp8(v, HI);
#else
  f32x2 r;
  constexpr unsigned int sh = HI ? 16u : 0u;
  r.x = fp8tof((v >> sh) & 0xffu);
  r.y = fp8tof((v >> (sh + 8u)) & 0xffu);
  return r;
#endif
}
__device__ __forceinline__ unsigned int pk4fp8(float a, float b, float c, float d){
#ifdef HAVE_FP8_BUILTINS
  unsigned int o = (unsigned int)__builtin_amdgcn_cvt_pk_fp8_f32(a, b, 0, false);
  o = (unsigned int)__builtin_amdgcn_cvt_pk_fp8_f32(c, d, (int)o, true);
  return o;
#else
  return ftofp8(a) | (ftofp8(b) << 8) | (ftofp8(c) << 16) | (ftofp8(d) << 24);
#endif
}

// ---- zero deg ----
__global__ __launch_bounds__(512) void k_zero(int* __restrict__ deg, int n){
  int i = blockIdx.x * 512 + threadIdx.x;
  if (i < n) deg[i] = 0;
}

// ---- fused: weight bf16 conversion (blocks 0..383) + degree count ----
__global__ __launch_bounds__(256) void k_pre(const int* __restrict__ dst,
    int* __restrict__ deg, const float* __restrict__ Wpre,
    const float* __restrict__ Wmrg, const float* __restrict__ Wcv,
    u16* __restrict__ WT, u16* __restrict__ Wc, int E){
  int bid = blockIdx.x;
  if (bid < 384){
    int idx = bid * 256 + threadIdx.x;
    if (idx < 65536){
      int j = idx & 511, k = idx >> 9;
      float v = (j < 256) ? Wpre[k * 256 + j] : Wmrg[k * 256 + (j - 256)];
      WT[j * 128 + k] = f2bf(v);
    } else if (idx < 65536 + 32768){
      int x = idx - 65536;
      Wc[x] = f2bf(Wcv[x]);
    }
  } else {
    int e = (bid - 384) * 256 + threadIdx.x;
    if (e < E) atomicAdd(&deg[dst[e]], 1);
  }
}

// ---- hierarchical scan ----
__global__ __launch_bounds__(256) void k_scan1(const int* __restrict__ deg,
    int* __restrict__ bsum, int n){
  __shared__ int red[256];
  int t = threadIdx.x;
  int i = blockIdx.x * 256 + t;
  red[t] = (i < n) ? deg[i] : 0;
  __syncthreads();
  for (int off = 128; off > 0; off >>= 1){
    if (t < off) red[t] += red[t + off];
    __syncthreads();
  }
  if (t == 0) bsum[blockIdx.x] = red[0];
}

__global__ __launch_bounds__(256) void k_scan2(int* __restrict__ bsum, int nb){
  __shared__ int s[256];
  int t = threadIdx.x;
  int v = (t < nb) ? bsum[t] : 0;
  s[t] = v;
  __syncthreads();
  for (int off = 1; off < 256; off <<= 1){
    int u = (t >= off) ? s[t - off] : 0;
    __syncthreads();
    s[t] += u;
    __syncthreads();
  }
  if (t < nb) bsum[t] = s[t] - v;
}

__global__ __launch_bounds__(256) void k_scan3(const int* __restrict__ deg,
    const int* __restrict__ bsum, int* __restrict__ row_start,
    int* __restrict__ cursor, float* __restrict__ norm, int n){
  __shared__ int s[256];
  int t = threadIdx.x;
  int i = blockIdx.x * 256 + t;
  int v = (i < n) ? deg[i] : 0;
  s[t] = v;
  __syncthreads();
  for (int off = 1; off < 256; off <<= 1){
    int u = (t >= off) ? s[t - off] : 0;
    __syncthreads();
    s[t] += u;
    __syncthreads();
  }
  int ex = s[t] - v + bsum[blockIdx.x];
  if (i < n){
    row_start[i] = ex;
    cursor[i] = ex;
    norm[i] = (v > 0) ? rsqrtf((float)v) : 0.f;
    if (i == n - 1) row_start[n] = ex + v;
  }
}

__global__ void k_scatter(const int* __restrict__ src, const int* __restrict__ dstA,
    int* __restrict__ cursor, int* __restrict__ csr_src, int E){
  int e = blockIdx.x * blockDim.x + threadIdx.x;
  if (e < E){
    int d = dstA[e];
    int pos = atomicAdd(&cursor[d], 1);
    csr_src[pos] = src[e];
  }
}

// ---- init (MFMA, swapped-D): merge = X@Wm + bm (bf16); outA = fp8(norm.*relu(X@Wp+bp+merge))
__global__ __launch_bounds__(512) void k_initM(const float* __restrict__ node,
    const u16* __restrict__ WT, const float* __restrict__ bpre,
    const float* __restrict__ bmrg, const float* __restrict__ norm,
    u16* __restrict__ merge, u8* __restrict__ outA, int n){
  __shared__ u16 Al[64 * 128];  // A tile, swizzled, 16KB
  int t = threadIdx.x;
  int w = t >> 6, l = t & 63;
  int n0 = blockIdx.x * 64;
  int cb = w * 32;
  int lk = (l >> 4) * 8;

  float nr4[4];
  #pragma unroll
  for (int fr = 0; fr < 4; ++fr){
    int row = n0 + fr * 16 + (l & 15);
    nr4[fr] = (row < n) ? norm[row] : 0.f;
  }
  float4 bPr[2], bMr[2];
  #pragma unroll
  for (int fcp = 0; fcp < 2; ++fcp){
    int j0 = cb + fcp * 16 + (l >> 4) * 4;
    bPr[fcp] = *(const float4*)(bpre + j0);
    bMr[fcp] = *(const float4*)(bmrg + j0);
  }

  {
    int row = t >> 3, c0 = (t & 7) * 16;
    const float* src = node + (size_t)(n0 + row) * ICNST + c0;
    bool ok = (n0 + row) < n;
    #pragma unroll
    for (int q = 0; q < 4; ++q){
      float4 v = ok ? *(const float4*)(src + q * 4) : float4{0.f, 0.f, 0.f, 0.f};
      int byte = (row * 256 + c0 * 2 + q * 8) ^ ((row & 7) << 4);
      uint2 pp; pp.x = pk2(v.x, v.y); pp.y = pk2(v.z, v.w);
      *(uint2*)((char*)Al + byte) = pp;
    }
  }
  __syncthreads();

  f32x4 acc[4][4] = {};
  #pragma unroll
  for (int ks = 0; ks < 4; ++ks){
    bf16x8 bf[4];
    #pragma unroll
    for (int fc = 0; fc < 4; ++fc){
      int j = (fc < 2) ? (cb + fc * 16 + (l & 15))
                       : (256 + cb + (fc - 2) * 16 + (l & 15));
      bf[fc] = *(const bf16x8*)(WT + (size_t)j * 128 + ks * 32 + lk);
    }
    bf16x8 af[4];
    #pragma unroll
    for (int fr = 0; fr < 4; ++fr){
      int row = fr * 16 + (l & 15);
      int byte = (row * 256 + ks * 64 + (l >> 4) * 16) ^ ((l & 7) << 4);
      af[fr] = *(const bf16x8*)((const char*)Al + byte);
    }
    #pragma unroll
    for (int fr = 0; fr < 4; ++fr)
      #pragma unroll
      for (int fc = 0; fc < 4; ++fc)
        acc[fr][fc] = __builtin_amdgcn_mfma_f32_16x16x32_bf16(bf[fc], af[fr], acc[fr][fc], 0, 0, 0);
  }

  #pragma unroll
  for (int fr = 0; fr < 4; ++fr){
    int row = n0 + fr * 16 + (l & 15);
    bool ok = row < n;
    float nr = nr4[fr];
    #pragma unroll
    for (int fcp = 0; fcp < 2; ++fcp){
      int j0 = cb + fcp * 16 + (l >> 4) * 4;
      f32x4 aP = acc[fr][fcp], aM = acc[fr][fcp + 2];
      float bPe[4] = {bPr[fcp].x, bPr[fcp].y, bPr[fcp].z, bPr[fcp].w};
      float bMe[4] = {bMr[fcp].x, bMr[fcp].y, bMr[fcp].z, bMr[fcp].w};
      ushort4 mgv;
      u16* mgp = (u16*)&mgv;
      float o4[4];
      #pragma unroll
      for (int r = 0; r < 4; ++r){
        float mg = aM[r] + bMe[r];
        float o  = aP[r] + bPe[r] + mg;
        o = (o > 0.f) ? o : 0.f;
        mgp[r] = f2bf(mg);
        o4[r] = nr * o;
      }
      if (ok){
        *(ushort4*)(merge + (size_t)row * C2 + j0) = mgv;
        *(unsigned int*)(outA + (size_t)row * C2 + j0) = pk4fp8(o4[0], o4[1], o4[2], o4[3]);
      }
    }
  }
}

// ---- FUSED prop + conv (MFMA, swapped-D), fp8 state ----
// FINAL=0: dstB = fp8(norm .* relu(conv(P*src) + bc + merge))
// FINAL=1: out  = pair-mean of relu(conv(P*src) + bc + merge), f32
template<int FINAL>
__global__ __launch_bounds__(512) void k_pconv(const u8* __restrict__ src,
    const int* __restrict__ row_start, const int* __restrict__ csr,
    const float* __restrict__ norm,
    const u16* __restrict__ Wc, const float* __restrict__ bc,
    const u16* __restrict__ merge,
    u8* __restrict__ dstB, float* __restrict__ out, int n){
  __shared__ u16 Al[64 * 256];  // bf16 A tile (prop result), swizzled, 32KB
  int t = threadIdx.x;
  int w = t >> 6, l = t & 63;
  int n0 = blockIdx.x * 64;
  int wh = w >> 2;
  int lk = (l >> 4) * 8;
  int half = l >> 5, c = l & 31;

  float nr4[4];
  #pragma unroll
  for (int fr = 0; fr < 4; ++fr){
    int row = n0 + fr * 16 + (l & 15);
    nr4[fr] = (row < n) ? norm[row] : 0.f;
  }
  float4 bCr[2];
  #pragma unroll
  for (int fc = 0; fc < 2; ++fc)
    bCr[fc] = *(const float4*)(bc + w * 32 + fc * 16 + (l >> 4) * 4);

  // ---- PROP phase: wave w computes dst rows [w*8, w*8+8), 2 rows at a time ----
  // lane covers 8 fp8 channels (8B); 32 lanes = 256B row
  const u8* Ac = src + (size_t)c * 8;
  #pragma unroll
  for (int it = 0; it < 4; ++it){
    int rl = w * 8 + it * 2 + half;
    int gw = n0 + rl;
    float a0 = 0.f, a1 = 0.f, a2 = 0.f, a3 = 0.f, a4 = 0.f, a5 = 0.f, a6 = 0.f, a7 = 0.f;
    float nd = 0.f;
    if (gw < n){
      int b = row_start[gw], e = row_start[gw + 1];
      int j = b;
      for (; j + 4 <= e; j += 4){
        int s0 = csr[j], s1 = csr[j + 1], s2 = csr[j + 2], s3 = csr[j + 3];
        uint2 r0 = *(const uint2*)(Ac + (size_t)s0 * C2);
        uint2 r1 = *(const uint2*)(Ac + (size_t)s1 * C2);
        uint2 r2 = *(const uint2*)(Ac + (size_t)s2 * C2);
        uint2 r3 = *(const uint2*)(Ac + (size_t)s3 * C2);
        f32x2 p;
        p = up2<false>(r0.x); a0 += p.x; a1 += p.y; p = up2<true>(r0.x); a2 += p.x; a3 += p.y;
        p = up2<false>(r0.y); a4 += p.x; a5 += p.y; p = up2<true>(r0.y); a6 += p.x; a7 += p.y;
        p = up2<false>(r1.x); a0 += p.x; a1 += p.y; p = up2<true>(r1.x); a2 += p.x; a3 += p.y;
        p = up2<false>(r1.y); a4 += p.x; a5 += p.y; p = up2<true>(r1.y); a6 += p.x; a7 += p.y;
        p = up2<false>(r2.x); a0 += p.x; a1 += p.y; p = up2<true>(r2.x); a2 += p.x; a3 += p.y;
        p = up2<false>(r2.y); a4 += p.x; a5 += p.y; p = up2<true>(r2.y); a6 += p.x; a7 += p.y;
        p = up2<false>(r3.x); a0 += p.x; a1 += p.y; p = up2<true>(r3.x); a2 += p.x; a3 += p.y;
        p = up2<false>(r3.y); a4 += p.x; a5 += p.y; p = up2<true>(r3.y); a6 += p.x; a7 += p.y;
      }
      for (; j < e; ++j){
        int s0 = csr[j];
        uint2 r0 = *(const uint2*)(Ac + (size_t)s0 * C2);
        f32x2 p;
        p = up2<false>(r0.x); a0 += p.x; a1 += p.y; p = up2<true>(r0.x); a2 += p.x; a3 += p.y;
        p = up2<false>(r0.y); a4 += p.x; a5 += p.y; p = up2<true>(r0.y); a6 += p.x; a7 += p.y;
      }
      nd = norm[gw];
    }
    uint4 ov;
    ov.x = pk2(nd * a0, nd * a1);
    ov.y = pk2(nd * a2, nd * a3);
    ov.z = pk2(nd * a4, nd * a5);
    ov.w = pk2(nd * a6, nd * a7);
    int byte = (rl * 512 + c * 16) ^ ((rl & 7) << 4);
    *(uint4*)((char*)Al + byte) = ov;
  }
  __syncthreads();

  // ---- CONV phase ----
  f32x4 acc[4][2] = {};
  #pragma unroll
  for (int ks = 0; ks < 4; ++ks){
    bf16x8 bf[2];
    #pragma unroll
    for (int fc = 0; fc < 2; ++fc){
      int rw = w * 32 + fc * 16 + (l & 15);
      bf[fc] = *(const bf16x8*)(Wc + (size_t)rw * 128 + ks * 32 + lk);
    }
    bf16x8 af[4];
    #pragma unroll
    for (int fr = 0; fr < 4; ++fr){
      int row = fr * 16 + (l & 15);
      int byte = (row * 512 + wh * 256 + ks * 64 + (l >> 4) * 16) ^ ((l & 7) << 4);
      af[fr] = *(const bf16x8*)((const char*)Al + byte);
    }
    #pragma unroll
    for (int fr = 0; fr < 4; ++fr)
      #pragma unroll
      for (int fc = 0; fc < 2; ++fc)
        acc[fr][fc] = __builtin_amdgcn_mfma_f32_16x16x32_bf16(bf[fc], af[fr], acc[fr][fc], 0, 0, 0);
  }

  // epilogue: scattered merge read + direct stores (measured neutral vs coalesced)
  #pragma unroll
  for (int fr = 0; fr < 4; ++fr){
    int row = n0 + fr * 16 + (l & 15);
    bool ok = row < n;
    float nr = nr4[fr];
    #pragma unroll
    for (int fc = 0; fc < 2; ++fc){
      int j0 = w * 32 + fc * 16 + (l >> 4) * 4;
      ushort4 mg4 = ok ? *(const ushort4*)(merge + (size_t)row * C2 + j0)
                       : ushort4{0, 0, 0, 0};
      const u16* mge = (const u16*)&mg4;
      float bCe[4] = {bCr[fc].x, bCr[fc].y, bCr[fc].z, bCr[fc].w};
      float v[4];
      #pragma unroll
      for (int r = 0; r < 4; ++r){
        float o = acc[fr][fc][r] + bCe[r] + bf2f(mge[r]);
        v[r] = (o > 0.f) ? o : 0.f;
      }
      if (ok){
        if (!FINAL){
          *(unsigned int*)(dstB + (size_t)row * C2 + j0) =
              pk4fp8(nr * v[0], nr * v[1], nr * v[2], nr * v[3]);
        } else {
          float2 om;
          om.x = 0.5f * (v[0] + v[1]);
          om.y = 0.5f * (v[2] + v[3]);
          *(float2*)(out + (size_t)row * 128 + (j0 >> 1)) = om;
        }
      }
    }
  }
}

extern "C" void kernel_launch(void* const* d_in, const int* in_sizes, int n_in,
                              void* d_out, int out_size, void* d_ws, size_t ws_size,
                              hipStream_t stream){
  const float* node = (const float*)d_in[0];
  const int*   eidx = (const int*)d_in[1];
  const float* Wpre = (const float*)d_in[2];
  const float* bpre = (const float*)d_in[3];
  const float* Wmrg = (const float*)d_in[4];
  const float* bmrg = (const float*)d_in[5];
  const float* Wcv  = (const float*)d_in[6];
  const float* bcv  = (const float*)d_in[7];
  float* out = (float*)d_out;

  const int n = in_sizes[0] / ICNST;
  const int E = in_sizes[1] / 2;
  const int* srcp = eidx;
  const int* dstp = eidx + E;

  char* ws = (char*)d_ws;
  size_t off = 0;
  auto alloc = [&](size_t bytes) -> char* {
    char* p = ws + off;
    off += bytes;
    off = (off + 255) & ~(size_t)255;
    return p;
  };
  int*   deg       = (int*)  alloc((size_t)n * 4);
  float* norm      = (float*)alloc((size_t)n * 4);
  int*   row_start = (int*)  alloc((size_t)(n + 1) * 4);
  int*   cursor    = (int*)  alloc((size_t)n * 4);
  int*   csr       = (int*)  alloc((size_t)E * 4);
  u16*   merge     = (u16*)  alloc((size_t)n * C2 * 2);
  u8*    bufA      = (u8*)   alloc((size_t)n * C2);
  u8*    bufB      = (u8*)   alloc((size_t)n * C2);
  u16*   WT        = (u16*)  alloc((size_t)512 * 128 * 2);
  u16*   Wcbf      = (u16*)  alloc((size_t)2 * 128 * 128 * 2);
  int*   bsum      = (int*)  alloc((size_t)256 * 4);
  (void)ws_size; (void)n_in; (void)out_size;

  const int nb = (n + 255) / 256;

  k_zero<<<(n + 511) / 512, 512, 0, stream>>>(deg, n);
  k_pre<<<384 + (E + 255) / 256, 256, 0, stream>>>(dstp, deg, Wpre, Wmrg, Wcv, WT, Wcbf, E);
  k_scan1<<<nb, 256, 0, stream>>>(deg, bsum, n);
  k_scan2<<<1, 256, 0, stream>>>(bsum, nb);
  k_scan3<<<nb, 256, 0, stream>>>(deg, bsum, row_start, cursor, norm, n);
  k_scatter<<<(E + 255) / 256, 256, 0, stream>>>(srcp, dstp, cursor, csr, E);

  int gb64 = (n + 63) / 64;
  k_initM<<<gb64, 512, 0, stream>>>(node, WT, bpre, bmrg, norm, merge, bufA, n);

  // iteration 1: fused prop+conv, bufA(fp8) -> bufB(fp8)
  k_pconv<0><<<gb64, 512, 0, stream>>>(bufA, row_start, csr, norm, Wcbf, bcv, merge, bufB, nullptr, n);
  // iteration 2: fused prop+conv + final mean, bufB(fp8) -> out (f32)
  k_pconv<1><<<gb64, 512, 0, stream>>>(bufB, row_start, csr, norm, Wcbf, bcv, merge, nullptr, out, n);
}

// Round 16
// 199.253 us; speedup vs baseline: 4.6622x; 1.0066x over previous
//
#include <hip/hip_runtime.h>

typedef unsigned short u16;
typedef unsigned char u8;
typedef __attribute__((ext_vector_type(8))) short bf16x8;
typedef __attribute__((ext_vector_type(4))) float f32x4;
typedef __attribute__((ext_vector_type(2))) float f32x2;

#define ICNST 128
#define C2 256   // OC*WIDTH

__device__ __forceinline__ float bf2f(u16 u){
  return __uint_as_float(((unsigned int)u) << 16);
}
__device__ __forceinline__ float2 bf2x2(unsigned int u){
  float2 r;
  r.x = __uint_as_float(u << 16);
  r.y = __uint_as_float(u & 0xffff0000u);
  return r;
}
__device__ __forceinline__ u16 f2bf(float f){
  unsigned int u = __float_as_uint(f);
  unsigned int r = (u + 0x7fffu + ((u >> 16) & 1u)) >> 16;
  return (u16)r;
}
__device__ __forceinline__ unsigned int pk2(float a, float b){
  return (unsigned int)f2bf(a) | ((unsigned int)f2bf(b) << 16);
}

// ---- fp8 e4m3 helpers (HW cvt on gfx950; manual fallback) ----
#if defined(__has_builtin)
#if __has_builtin(__builtin_amdgcn_cvt_pk_f32_fp8) && __has_builtin(__builtin_amdgcn_cvt_pk_fp8_f32)
#define HAVE_FP8_BUILTINS 1
#endif
#endif

#ifndef HAVE_FP8_BUILTINS
__device__ __forceinline__ float fp8tof(unsigned int b){
  unsigned int sgn = (b & 0x80u) << 24;
  unsigned int em = b & 0x7fu;
  float mag;
  if (em >= 8u){
    unsigned int e = em >> 3, m = em & 7u;
    mag = __uint_as_float(((e + 120u) << 23) | (m << 20));
  } else {
    mag = (float)em * 0.001953125f; // 2^-9
  }
  return __uint_as_float(__float_as_uint(mag) | sgn);
}
__device__ __forceinline__ unsigned int ftofp8(float f){
  unsigned int u = __float_as_uint(f);
  unsigned int s = (u >> 24) & 0x80u;
  float a = __uint_as_float(u & 0x7fffffffu);
  if (a > 448.f) a = 448.f;
  if (a < 0.015625f){
    int q = (int)(a * 512.f + 0.5f);
    return s | (unsigned int)q;
  }
  int e; float m = frexpf(a, &e);
  int q = (int)(m * 16.f + 0.5f);
  if (q == 16){ q = 8; e += 1; }
  int E = e - 1 + 7;
  if (E > 15){ E = 15; q = 14; }
  return s | (unsigned int)((E << 3) | (q & 7));
}
#endif

template<bool HI>
__device__ __forceinline__ f32x2 up2(unsigned int v){
#ifdef HAVE_FP8_BUILTINS
  return __builtin_amdgcn_cvt_pk_f32_fp8(v, HI);
#else
  f32x2 r;
  constexpr unsigned int sh = HI ? 16u : 0u;
  r.x = fp8tof((v >> sh) & 0xffu);
  r.y = fp8tof((v >> (sh + 8u)) & 0xffu);
  return r;
#endif
}
__device__ __forceinline__ unsigned int pk4fp8(float a, float b, float c, float d){
#ifdef HAVE_FP8_BUILTINS
  unsigned int o = (unsigned int)__builtin_amdgcn_cvt_pk_fp8_f32(a, b, 0, false);
  o = (unsigned int)__builtin_amdgcn_cvt_pk_fp8_f32(c, d, (int)o, true);
  return o;
#else
  return ftofp8(a) | (ftofp8(b) << 8) | (ftofp8(c) << 16) | (ftofp8(d) << 24);
#endif
}

// ---- zero deg ----
__global__ __launch_bounds__(512) void k_zero(int* __restrict__ deg, int n){
  int i = blockIdx.x * 512 + threadIdx.x;
  if (i < n) deg[i] = 0;
}

// ---- fused: weight bf16 conversion (blocks 0..383) + degree count ----
__global__ __launch_bounds__(256) void k_pre(const int* __restrict__ dst,
    int* __restrict__ deg, const float* __restrict__ Wpre,
    const float* __restrict__ Wmrg, const float* __restrict__ Wcv,
    u16* __restrict__ WT, u16* __restrict__ Wc, int E){
  int bid = blockIdx.x;
  if (bid < 384){
    int idx = bid * 256 + threadIdx.x;
    if (idx < 65536){
      int j = idx & 511, k = idx >> 9;
      float v = (j < 256) ? Wpre[k * 256 + j] : Wmrg[k * 256 + (j - 256)];
      WT[j * 128 + k] = f2bf(v);
    } else if (idx < 65536 + 32768){
      int x = idx - 65536;
      Wc[x] = f2bf(Wcv[x]);
    }
  } else {
    int e = (bid - 384) * 256 + threadIdx.x;
    if (e < E) atomicAdd(&deg[dst[e]], 1);
  }
}

// ---- hierarchical scan ----
__global__ __launch_bounds__(256) void k_scan1(const int* __restrict__ deg,
    int* __restrict__ bsum, int n){
  __shared__ int red[256];
  int t = threadIdx.x;
  int i = blockIdx.x * 256 + t;
  red[t] = (i < n) ? deg[i] : 0;
  __syncthreads();
  for (int off = 128; off > 0; off >>= 1){
    if (t < off) red[t] += red[t + off];
    __syncthreads();
  }
  if (t == 0) bsum[blockIdx.x] = red[0];
}

__global__ __launch_bounds__(256) void k_scan2(int* __restrict__ bsum, int nb){
  __shared__ int s[256];
  int t = threadIdx.x;
  int v = (t < nb) ? bsum[t] : 0;
  s[t] = v;
  __syncthreads();
  for (int off = 1; off < 256; off <<= 1){
    int u = (t >= off) ? s[t - off] : 0;
    __syncthreads();
    s[t] += u;
    __syncthreads();
  }
  if (t < nb) bsum[t] = s[t] - v;
}

__global__ __launch_bounds__(256) void k_scan3(const int* __restrict__ deg,
    const int* __restrict__ bsum, int* __restrict__ row_start,
    int* __restrict__ cursor, float* __restrict__ norm, int n){
  __shared__ int s[256];
  int t = threadIdx.x;
  int i = blockIdx.x * 256 + t;
  int v = (i < n) ? deg[i] : 0;
  s[t] = v;
  __syncthreads();
  for (int off = 1; off < 256; off <<= 1){
    int u = (t >= off) ? s[t - off] : 0;
    __syncthreads();
    s[t] += u;
    __syncthreads();
  }
  int ex = s[t] - v + bsum[blockIdx.x];
  if (i < n){
    row_start[i] = ex;
    cursor[i] = ex;
    norm[i] = (v > 0) ? rsqrtf((float)v) : 0.f;
    if (i == n - 1) row_start[n] = ex + v;
  }
}

__global__ void k_scatter(const int* __restrict__ src, const int* __restrict__ dstA,
    int* __restrict__ cursor, int* __restrict__ csr_src, int E){
  int e = blockIdx.x * blockDim.x + threadIdx.x;
  if (e < E){
    int d = dstA[e];
    int pos = atomicAdd(&cursor[d], 1);
    csr_src[pos] = src[e];
  }
}

// ---- init (MFMA, swapped-D): merge = X@Wm + bm (bf16); outA = fp8(norm.*relu(X@Wp+bp+merge))
__global__ __launch_bounds__(512) void k_initM(const float* __restrict__ node,
    const u16* __restrict__ WT, const float* __restrict__ bpre,
    const float* __restrict__ bmrg, const float* __restrict__ norm,
    u16* __restrict__ merge, u8* __restrict__ outA, int n){
  __shared__ u16 Al[64 * 128];  // A tile, swizzled, 16KB
  int t = threadIdx.x;
  int w = t >> 6, l = t & 63;
  int n0 = blockIdx.x * 64;
  int cb = w * 32;
  int lk = (l >> 4) * 8;

  float nr4[4];
  #pragma unroll
  for (int fr = 0; fr < 4; ++fr){
    int row = n0 + fr * 16 + (l & 15);
    nr4[fr] = (row < n) ? norm[row] : 0.f;
  }
  float4 bPr[2], bMr[2];
  #pragma unroll
  for (int fcp = 0; fcp < 2; ++fcp){
    int j0 = cb + fcp * 16 + (l >> 4) * 4;
    bPr[fcp] = *(const float4*)(bpre + j0);
    bMr[fcp] = *(const float4*)(bmrg + j0);
  }

  {
    int row = t >> 3, c0 = (t & 7) * 16;
    const float* src = node + (size_t)(n0 + row) * ICNST + c0;
    bool ok = (n0 + row) < n;
    #pragma unroll
    for (int q = 0; q < 4; ++q){
      float4 v = ok ? *(const float4*)(src + q * 4) : float4{0.f, 0.f, 0.f, 0.f};
      int byte = (row * 256 + c0 * 2 + q * 8) ^ ((row & 7) << 4);
      uint2 pp; pp.x = pk2(v.x, v.y); pp.y = pk2(v.z, v.w);
      *(uint2*)((char*)Al + byte) = pp;
    }
  }
  __syncthreads();

  f32x4 acc[4][4] = {};
  #pragma unroll
  for (int ks = 0; ks < 4; ++ks){
    bf16x8 bf[4];
    #pragma unroll
    for (int fc = 0; fc < 4; ++fc){
      int j = (fc < 2) ? (cb + fc * 16 + (l & 15))
                       : (256 + cb + (fc - 2) * 16 + (l & 15));
      bf[fc] = *(const bf16x8*)(WT + (size_t)j * 128 + ks * 32 + lk);
    }
    bf16x8 af[4];
    #pragma unroll
    for (int fr = 0; fr < 4; ++fr){
      int row = fr * 16 + (l & 15);
      int byte = (row * 256 + ks * 64 + (l >> 4) * 16) ^ ((l & 7) << 4);
      af[fr] = *(const bf16x8*)((const char*)Al + byte);
    }
    #pragma unroll
    for (int fr = 0; fr < 4; ++fr)
      #pragma unroll
      for (int fc = 0; fc < 4; ++fc)
        acc[fr][fc] = __builtin_amdgcn_mfma_f32_16x16x32_bf16(bf[fc], af[fr], acc[fr][fc], 0, 0, 0);
  }

  #pragma unroll
  for (int fr = 0; fr < 4; ++fr){
    int row = n0 + fr * 16 + (l & 15);
    bool ok = row < n;
    float nr = nr4[fr];
    #pragma unroll
    for (int fcp = 0; fcp < 2; ++fcp){
      int j0 = cb + fcp * 16 + (l >> 4) * 4;
      f32x4 aP = acc[fr][fcp], aM = acc[fr][fcp + 2];
      float bPe[4] = {bPr[fcp].x, bPr[fcp].y, bPr[fcp].z, bPr[fcp].w};
      float bMe[4] = {bMr[fcp].x, bMr[fcp].y, bMr[fcp].z, bMr[fcp].w};
      ushort4 mgv;
      u16* mgp = (u16*)&mgv;
      float o4[4];
      #pragma unroll
      for (int r = 0; r < 4; ++r){
        float mg = aM[r] + bMe[r];
        float o  = aP[r] + bPe[r] + mg;
        o = (o > 0.f) ? o : 0.f;
        mgp[r] = f2bf(mg);
        o4[r] = nr * o;
      }
      if (ok){
        *(ushort4*)(merge + (size_t)row * C2 + j0) = mgv;
        *(unsigned int*)(outA + (size_t)row * C2 + j0) = pk4fp8(o4[0], o4[1], o4[2], o4[3]);
      }
    }
  }
}

// ---- FUSED prop + conv (MFMA, swapped-D), fp8 state, 4-rows-in-flight gather ----
// FINAL=0: dstB = fp8(norm .* relu(conv(P*src) + bc + merge))
// FINAL=1: out  = pair-mean of relu(conv(P*src) + bc + merge), f32
template<int FINAL>
__global__ __launch_bounds__(512) void k_pconv(const u8* __restrict__ src,
    const int* __restrict__ row_start, const int* __restrict__ csr,
    const float* __restrict__ norm,
    const u16* __restrict__ Wc, const float* __restrict__ bc,
    const u16* __restrict__ merge,
    u8* __restrict__ dstB, float* __restrict__ out, int n, int Etot){
  __shared__ u16 Al[64 * 256];  // bf16 A tile (prop result), swizzled, 32KB
  int t = threadIdx.x;
  int w = t >> 6, l = t & 63;
  int n0 = blockIdx.x * 64;
  int wh = w >> 2;
  int lk = (l >> 4) * 8;
  int half = l >> 5, c = l & 31;

  float nr4[4];
  #pragma unroll
  for (int fr = 0; fr < 4; ++fr){
    int row = n0 + fr * 16 + (l & 15);
    nr4[fr] = (row < n) ? norm[row] : 0.f;
  }
  float4 bCr[2];
  #pragma unroll
  for (int fc = 0; fc < 2; ++fc)
    bCr[fc] = *(const float4*)(bc + w * 32 + fc * 16 + (l >> 4) * 4);

  // ---- PROP phase: half-wave owns 4 rows IN FLIGHT: rl = w*8 + half*4 + k ----
  const u8* Ac = src + (size_t)c * 8;
  int rbase = w * 8 + half * 4;
  float acc8[4][8];
  int bb[4], ee[4];
  float ndk[4];
  #pragma unroll
  for (int k = 0; k < 4; ++k){
    int gw = n0 + rbase + k;
    bool ok = gw < n;
    bb[k] = ok ? row_start[gw] : 0;
    ee[k] = ok ? row_start[gw + 1] : 0;
    ndk[k] = ok ? norm[gw] : 0.f;
    #pragma unroll
    for (int q = 0; q < 8; ++q) acc8[k][q] = 0.f;
  }
  int Em1 = Etot - 1;
  bool more = (bb[0] < ee[0]) | (bb[1] < ee[1]) | (bb[2] < ee[2]) | (bb[3] < ee[3]);
  while (__any(more)){
    uint2 rr[4];
    float wk[4];
    #pragma unroll
    for (int k = 0; k < 4; ++k){
      bool v = bb[k] < ee[k];
      wk[k] = v ? 1.f : 0.f;
      int idx = (bb[k] < Em1) ? bb[k] : Em1;
      int s0 = csr[idx];
      rr[k] = *(const uint2*)(Ac + (size_t)s0 * C2);
      bb[k] += v ? 1 : 0;
    }
    #pragma unroll
    for (int k = 0; k < 4; ++k){
      f32x2 p;
      p = up2<false>(rr[k].x); acc8[k][0] = fmaf(wk[k], p.x, acc8[k][0]); acc8[k][1] = fmaf(wk[k], p.y, acc8[k][1]);
      p = up2<true >(rr[k].x); acc8[k][2] = fmaf(wk[k], p.x, acc8[k][2]); acc8[k][3] = fmaf(wk[k], p.y, acc8[k][3]);
      p = up2<false>(rr[k].y); acc8[k][4] = fmaf(wk[k], p.x, acc8[k][4]); acc8[k][5] = fmaf(wk[k], p.y, acc8[k][5]);
      p = up2<true >(rr[k].y); acc8[k][6] = fmaf(wk[k], p.x, acc8[k][6]); acc8[k][7] = fmaf(wk[k], p.y, acc8[k][7]);
    }
    more = (bb[0] < ee[0]) | (bb[1] < ee[1]) | (bb[2] < ee[2]) | (bb[3] < ee[3]);
  }
  // write 4 rows to swizzled LDS (bf16)
  #pragma unroll
  for (int k = 0; k < 4; ++k){
    int rl = rbase + k;
    float nd = ndk[k];
    uint4 ov;
    ov.x = pk2(nd * acc8[k][0], nd * acc8[k][1]);
    ov.y = pk2(nd * acc8[k][2], nd * acc8[k][3]);
    ov.z = pk2(nd * acc8[k][4], nd * acc8[k][5]);
    ov.w = pk2(nd * acc8[k][6], nd * acc8[k][7]);
    int byte = (rl * 512 + c * 16) ^ ((rl & 7) << 4);
    *(uint4*)((char*)Al + byte) = ov;
  }
  __syncthreads();

  // ---- CONV phase ----
  f32x4 acc[4][2] = {};
  #pragma unroll
  for (int ks = 0; ks < 4; ++ks){
    bf16x8 bf[2];
    #pragma unroll
    for (int fc = 0; fc < 2; ++fc){
      int rw = w * 32 + fc * 16 + (l & 15);
      bf[fc] = *(const bf16x8*)(Wc + (size_t)rw * 128 + ks * 32 + lk);
    }
    bf16x8 af[4];
    #pragma unroll
    for (int fr = 0; fr < 4; ++fr){
      int row = fr * 16 + (l & 15);
      int byte = (row * 512 + wh * 256 + ks * 64 + (l >> 4) * 16) ^ ((l & 7) << 4);
      af[fr] = *(const bf16x8*)((const char*)Al + byte);
    }
    #pragma unroll
    for (int fr = 0; fr < 4; ++fr)
      #pragma unroll
      for (int fc = 0; fc < 2; ++fc)
        acc[fr][fc] = __builtin_amdgcn_mfma_f32_16x16x32_bf16(bf[fc], af[fr], acc[fr][fc], 0, 0, 0);
  }

  // epilogue
  #pragma unroll
  for (int fr = 0; fr < 4; ++fr){
    int row = n0 + fr * 16 + (l & 15);
    bool ok = row < n;
    float nr = nr4[fr];
    #pragma unroll
    for (int fc = 0; fc < 2; ++fc){
      int j0 = w * 32 + fc * 16 + (l >> 4) * 4;
      ushort4 mg4 = ok ? *(const ushort4*)(merge + (size_t)row * C2 + j0)
                       : ushort4{0, 0, 0, 0};
      const u16* mge = (const u16*)&mg4;
      float bCe[4] = {bCr[fc].x, bCr[fc].y, bCr[fc].z, bCr[fc].w};
      float v[4];
      #pragma unroll
      for (int r = 0; r < 4; ++r){
        float o = acc[fr][fc][r] + bCe[r] + bf2f(mge[r]);
        v[r] = (o > 0.f) ? o : 0.f;
      }
      if (ok){
        if (!FINAL){
          *(unsigned int*)(dstB + (size_t)row * C2 + j0) =
              pk4fp8(nr * v[0], nr * v[1], nr * v[2], nr * v[3]);
        } else {
          float2 om;
          om.x = 0.5f * (v[0] + v[1]);
          om.y = 0.5f * (v[2] + v[3]);
          *(float2*)(out + (size_t)row * 128 + (j0 >> 1)) = om;
        }
      }
    }
  }
}

extern "C" void kernel_launch(void* const* d_in, const int* in_sizes, int n_in,
                              void* d_out, int out_size, void* d_ws, size_t ws_size,
                              hipStream_t stream){
  const float* node = (const float*)d_in[0];
  const int*   eidx = (const int*)d_in[1];
  const float* Wpre = (const float*)d_in[2];
  const float* bpre = (const float*)d_in[3];
  const float* Wmrg = (const float*)d_in[4];
  const float* bmrg = (const float*)d_in[5];
  const float* Wcv  = (const float*)d_in[6];
  const float* bcv  = (const float*)d_in[7];
  float* out = (float*)d_out;

  const int n = in_sizes[0] / ICNST;
  const int E = in_sizes[1] / 2;
  const int* srcp = eidx;
  const int* dstp = eidx + E;

  char* ws = (char*)d_ws;
  size_t off = 0;
  auto alloc = [&](size_t bytes) -> char* {
    char* p = ws + off;
    off += bytes;
    off = (off + 255) & ~(size_t)255;
    return p;
  };
  int*   deg       = (int*)  alloc((size_t)n * 4);
  float* norm      = (float*)alloc((size_t)n * 4);
  int*   row_start = (int*)  alloc((size_t)(n + 1) * 4);
  int*   cursor    = (int*)  alloc((size_t)n * 4);
  int*   csr       = (int*)  alloc((size_t)E * 4);
  u16*   merge     = (u16*)  alloc((size_t)n * C2 * 2);
  u8*    bufA      = (u8*)   alloc((size_t)n * C2);
  u8*    bufB      = (u8*)   alloc((size_t)n * C2);
  u16*   WT        = (u16*)  alloc((size_t)512 * 128 * 2);
  u16*   Wcbf      = (u16*)  alloc((size_t)2 * 128 * 128 * 2);
  int*   bsum      = (int*)  alloc((size_t)256 * 4);
  (void)ws_size; (void)n_in; (void)out_size;

  const int nb = (n + 255) / 256;

  k_zero<<<(n + 511) / 512, 512, 0, stream>>>(deg, n);
  k_pre<<<384 + (E + 255) / 256, 256, 0, stream>>>(dstp, deg, Wpre, Wmrg, Wcv, WT, Wcbf, E);
  k_scan1<<<nb, 256, 0, stream>>>(deg, bsum, n);
  k_scan2<<<1, 256, 0, stream>>>(bsum, nb);
  k_scan3<<<nb, 256, 0, stream>>>(deg, bsum, row_start, cursor, norm, n);
  k_scatter<<<(E + 255) / 256, 256, 0, stream>>>(srcp, dstp, cursor, csr, E);

  int gb64 = (n + 63) / 64;
  k_initM<<<gb64, 512, 0, stream>>>(node, WT, bpre, bmrg, norm, merge, bufA, n);

  // iteration 1: fused prop+conv, bufA(fp8) -> bufB(fp8)
  k_pconv<0><<<gb64, 512, 0, stream>>>(bufA, row_start, csr, norm, Wcbf, bcv, merge, bufB, nullptr, n, E);
  // iteration 2: fused prop+conv + final mean, bufB(fp8) -> out (f32)
  k_pconv<1><<<gb64, 512, 0, stream>>>(bufB, row_start, csr, norm, Wcbf, bcv, merge, nullptr, out, n, E);
}